// Round 10
// baseline (4807.528 us; speedup 1.0000x reference)
//
#include <hip/hip_runtime.h>
#include <math.h>

#define CB 4
#define CT 1024
#define CD 768
#define CH 12
#define CK 64
#define CBH (CB*CH)
#define NB 64

typedef __attribute__((ext_vector_type(8))) short sh8;
typedef __attribute__((ext_vector_type(8))) unsigned short ush8;
typedef __attribute__((ext_vector_type(4))) unsigned short ush4;
typedef __attribute__((ext_vector_type(4))) float fl4;

__device__ __forceinline__ unsigned short f2bf(float f){
    unsigned u = __builtin_bit_cast(unsigned, f);
    unsigned r = (u + 0x7fff + ((u >> 16) & 1)) >> 16;
    return (unsigned short)r;
}
__device__ __forceinline__ float bf2f(unsigned short u){
    return __builtin_bit_cast(float, (unsigned)u << 16);
}
#define MFMA3(acc, ah, al, bh_, bl_) { \
    acc = __builtin_amdgcn_mfma_f32_16x16x32_bf16(al, bh_, acc, 0, 0, 0); \
    acc = __builtin_amdgcn_mfma_f32_16x16x32_bf16(ah, bl_, acc, 0, 0, 0); \
    acc = __builtin_amdgcn_mfma_f32_16x16x32_bf16(ah, bh_, acc, 0, 0, 0); }

// cooperative 64x64 tile load: global (row-major, given stride) -> LDS [64][65]
#define LOAD_TILE(dst, src, stride) { \
    _Pragma("unroll") \
    for (int i_ = 0; i_ < 4; i_++){ \
        int rr_ = (tid>>4) + i_*16, cc_ = (tid&15)*4; \
        float4 v_ = *(const float4*)((src) + (size_t)rr_*(stride) + cc_); \
        dst[rr_][cc_+0]=v_.x; dst[rr_][cc_+1]=v_.y; dst[rr_][cc_+2]=v_.z; dst[rr_][cc_+3]=v_.w; \
    } }

// ---------------- elementwise: token shift + xxx ----------------
__global__ void k_shift(const float* __restrict__ x, const float* __restrict__ tmx,
                        float* __restrict__ dxprev, float* __restrict__ xxx){
    int idx = blockIdx.x*256 + threadIdx.x;
    if (idx >= CB*CT*CD) return;
    int d = idx % CD;
    int bt = idx / CD;
    int t = bt % CT;
    float xc = x[idx];
    float xl = (t > 0)      ? x[idx - CD] : 0.f;
    float xr = (t < CT-1)   ? x[idx + CD] : 0.f;
    float dx = 0.5f*(xl + xr) - xc;
    dxprev[idx] = dx;
    xxx[idx] = xc + dx * tmx[d];
}

// ---------------- generic tiled fp32 GEMM (maa_w1 only) ----------------
template<int MODE>
__global__ void k_gemm(const float* __restrict__ A, const float* __restrict__ Bm,
                       const float* __restrict__ bias, float* __restrict__ C,
                       int M, int N, int Kd){
    __shared__ float As[16][128];
    __shared__ float Bs[16][64];
    int tid = threadIdx.x;
    int m0 = blockIdx.y * 128, n0 = blockIdx.x * 64;
    int tn = (tid & 15) * 4;
    int tm = (tid >> 4) * 8;
    float acc[8][4] = {};
    for (int k0 = 0; k0 < Kd; k0 += 16){
        #pragma unroll
        for (int i = 0; i < 8; i++){
            int e = tid + i*256;
            int r = e >> 4, c = e & 15;
            As[c][r] = A[(size_t)(m0+r)*Kd + k0 + c];
        }
        #pragma unroll
        for (int i = 0; i < 4; i++){
            int e = tid + i*256;
            int r = e >> 6, c = e & 63;
            float bv = 0.f;
            if (n0 + c < N) bv = Bm[(size_t)(k0+r)*N + n0 + c];
            Bs[r][c] = bv;
        }
        __syncthreads();
        #pragma unroll
        for (int kk = 0; kk < 16; kk++){
            float a0[8], b0[4];
            #pragma unroll
            for (int i = 0; i < 8; i++) a0[i] = As[kk][tm+i];
            #pragma unroll
            for (int j = 0; j < 4; j++) b0[j] = Bs[kk][tn+j];
            #pragma unroll
            for (int i = 0; i < 8; i++)
                #pragma unroll
                for (int j = 0; j < 4; j++) acc[i][j] += a0[i]*b0[j];
        }
        __syncthreads();
    }
    #pragma unroll
    for (int i = 0; i < 8; i++)
        #pragma unroll
        for (int j = 0; j < 4; j++){
            int mm = m0 + tm + i, nn = n0 + tn + j;
            if (nn < N){
                float v = acc[i][j];
                if (MODE == 1) v = tanhf(v);
                else if (MODE == 2) v = v / (1.f + expf(-v));
                else if (MODE == 3) v += bias[nn];
                C[(size_t)mm*N + nn] = v;
            }
        }
}

// ---------------- weight transpose + split: B[K][N] -> Bt{Hi,Lo}[N][K] ----------------
__global__ void k_splitT(const float* __restrict__ B, unsigned short* __restrict__ hi,
                         unsigned short* __restrict__ lo, int Kd, int N){
    __shared__ float ts[64][65];
    int tid = threadIdx.x;
    int n0 = blockIdx.x*64, k0 = blockIdx.y*64;
    #pragma unroll
    for (int i = 0; i < 4; i++){
        int rr = (tid>>4) + i*16, cc = (tid&15)*4;
        float4 v = *(const float4*)(B + (size_t)(k0+rr)*N + n0 + cc);
        ts[rr][cc+0]=v.x; ts[rr][cc+1]=v.y; ts[rr][cc+2]=v.z; ts[rr][cc+3]=v.w;
    }
    __syncthreads();
    #pragma unroll
    for (int i = 0; i < 4; i++){
        int nl = (tid>>4) + i*16, k4 = (tid&15)*4;
        ush4 vh, vl;
        #pragma unroll
        for (int j = 0; j < 4; j++){
            float f = ts[k4+j][nl];
            unsigned short h = f2bf(f);
            vh[j] = h;
            vl[j] = f2bf(f - bf2f(h));
        }
        size_t o = (size_t)(n0+nl)*Kd + k0 + k4;
        *reinterpret_cast<ush4*>(hi + o) = vh;
        *reinterpret_cast<ush4*>(lo + o) = vl;
    }
}

// ---------------- MFMA split-bf16 GEMM: C[M,N] = A[M,K] @ Bt[N,K]^T ----------------
// MODE 0 plain, 1 tanh, 2 silu, 3 +bias[n]
template<int MODE>
__global__ __launch_bounds__(256) void k_mgemm(const float* __restrict__ A,
        const unsigned short* __restrict__ BtHi, const unsigned short* __restrict__ BtLo,
        const float* __restrict__ bias, float* __restrict__ C, int M, int N, int Kd){
    __shared__ unsigned short AHI[2048], ALO[2048], BHI[2048], BLO[2048];
    int tid = threadIdx.x;
    int n0 = blockIdx.x*64, m0 = blockIdx.y*64;
    int w = tid >> 6, lane = tid & 63;
    int wm = w >> 1, wn = w & 1;
    fl4 acc[2][2];
    #pragma unroll
    for (int mi = 0; mi < 2; mi++)
        #pragma unroll
        for (int ni = 0; ni < 2; ni++) acc[mi][ni] = (fl4){0.f, 0.f, 0.f, 0.f};
    int sm = tid >> 2;
    int sk = (tid & 3) * 8;
    int slane = (sm & 15) + ((tid & 3) << 4);
    int sidx = (((sm >> 4)*64) + slane) * 8;
    const int nsteps = Kd >> 5;
    for (int ks = 0; ks < nsteps; ks++){
        int k0 = ks << 5;
        __syncthreads();
        {
            const float* ap = A + (size_t)(m0+sm)*Kd + k0 + sk;
            float4 a0 = *(const float4*)ap, a1 = *(const float4*)(ap+4);
            float av[8] = {a0.x,a0.y,a0.z,a0.w,a1.x,a1.y,a1.z,a1.w};
            ush8 vh, vl;
            #pragma unroll
            for (int i = 0; i < 8; i++){
                unsigned short h = f2bf(av[i]);
                vh[i] = h;
                vl[i] = f2bf(av[i] - bf2f(h));
            }
            *reinterpret_cast<ush8*>(&AHI[sidx]) = vh;
            *reinterpret_cast<ush8*>(&ALO[sidx]) = vl;
            size_t bo = (size_t)(n0+sm)*Kd + k0 + sk;
            *reinterpret_cast<ush8*>(&BHI[sidx]) = *reinterpret_cast<const ush8*>(BtHi + bo);
            *reinterpret_cast<ush8*>(&BLO[sidx]) = *reinterpret_cast<const ush8*>(BtLo + bo);
        }
        __syncthreads();
        sh8 ah[2], al[2], bh[2], bl[2];
        #pragma unroll
        for (int mi = 0; mi < 2; mi++){
            int gm = wm*2 + mi;
            ah[mi] = *reinterpret_cast<sh8*>(&AHI[(gm*64 + lane)*8]);
            al[mi] = *reinterpret_cast<sh8*>(&ALO[(gm*64 + lane)*8]);
        }
        #pragma unroll
        for (int ni = 0; ni < 2; ni++){
            int gn = wn*2 + ni;
            bh[ni] = *reinterpret_cast<sh8*>(&BHI[(gn*64 + lane)*8]);
            bl[ni] = *reinterpret_cast<sh8*>(&BLO[(gn*64 + lane)*8]);
        }
        #pragma unroll
        for (int mi = 0; mi < 2; mi++)
            #pragma unroll
            for (int ni = 0; ni < 2; ni++)
                MFMA3(acc[mi][ni], ah[mi], al[mi], bh[ni], bl[ni]);
    }
    #pragma unroll
    for (int mi = 0; mi < 2; mi++)
        #pragma unroll
        for (int ni = 0; ni < 2; ni++){
            int cc = n0 + wn*32 + ni*16 + (lane & 15);
            int rb = m0 + wm*32 + mi*16 + ((lane >> 4) << 2);
            #pragma unroll
            for (int j = 0; j < 4; j++){
                float v = acc[mi][ni][j];
                if (MODE == 1) v = tanhf(v);
                else if (MODE == 2) v = v / (1.f + expf(-v));
                else if (MODE == 3) v += bias[cc];
                C[(size_t)(rb+j)*N + cc] = v;
            }
        }
}

// ---------------- 5-way low-rank mix ----------------
__global__ void k_mix5(const float* __restrict__ x, const float* __restrict__ dxprev,
                       const float* __restrict__ m,
                       const float* __restrict__ tmw, const float* __restrict__ tmk,
                       const float* __restrict__ tmv, const float* __restrict__ tmr,
                       const float* __restrict__ tmg, const float* __restrict__ w2,
                       float* __restrict__ xw, float* __restrict__ xk, float* __restrict__ xv,
                       float* __restrict__ xr, float* __restrict__ xg){
    __shared__ float ms[160];
    int i = blockIdx.y;
    int j = blockIdx.x*256 + threadIdx.x;
    if (threadIdx.x < 160) ms[threadIdx.x] = m[(size_t)i*160 + threadIdx.x];
    __syncthreads();
    float xc = x[(size_t)i*CD + j], dx = dxprev[(size_t)i*CD + j];
    const float* tms[5] = {tmw, tmk, tmv, tmr, tmg};
    float* outs[5] = {xw, xk, xv, xr, xg};
    #pragma unroll
    for (int c = 0; c < 5; c++){
        float s = tms[c][j];
        const float* w2c = w2 + (size_t)c*32*CD + j;
        #pragma unroll
        for (int dm = 0; dm < 32; dm++) s += ms[c*32+dm] * w2c[(size_t)dm*CD];
        outs[c][(size_t)i*CD + j] = xc + dx*s;
    }
}

// ---------------- normalize k, stage v into X (head layout) ----------------
__global__ void k_knvx(const float* __restrict__ k, const float* __restrict__ v,
                       float* __restrict__ kn, float* __restrict__ X){
    int gw = (blockIdx.x*256 + threadIdx.x) >> 6;
    int lane = threadIdx.x & 63;
    if (gw >= CB*CH*CT) return;
    int t = gw % CT; int bh = gw / CT; int h = bh % CH; int b = bh / CH;
    size_t src = ((size_t)(b*CT + t))*CD + h*64 + lane;
    float kv = k[src];
    float ss = kv*kv;
    #pragma unroll
    for (int off = 32; off; off >>= 1) ss += __shfl_xor(ss, off);
    float nrm = fmaxf(sqrtf(ss), 1e-12f);
    size_t dst = ((size_t)bh*CT + t)*64 + lane;
    kn[dst] = kv / nrm;
    X[dst]  = v[src];
}

// ---------------- decay scan, fully coalesced ----------------
__global__ __launch_bounds__(256) void k_scan2(const float* __restrict__ r, const float* __restrict__ k,
                        const float* __restrict__ w,
                        float* __restrict__ rf, float* __restrict__ kf,
                        float* __restrict__ rb, float* __restrict__ kb){
    __shared__ float parts[16][4][64];
    __shared__ float carr[16][64];
    __shared__ float refs[2][64];
    int bh = blockIdx.x; int h = bh % CH; int b = bh / CH;
    int tid = threadIdx.x; int wid = tid >> 6; int ch = tid & 63;
    const float* wb = w + (size_t)b*CT*CD + h*64;
    for (int tc = 0; tc < 16; tc++){
        float sum = 0.f;
        int tb = tc*64 + wid*16;
        for (int s = 0; s < 16; s++)
            sum -= expf(wb[(size_t)(tb+s)*CD + ch]);
        parts[tc][wid][ch] = sum;
    }
    __syncthreads();
    if (tid < 64){
        float run = 0.f;
        for (int tc = 0; tc < 16; tc++){
            carr[tc][tid] = run;
            run += parts[tc][0][tid] + parts[tc][1][tid] + parts[tc][2][tid] + parts[tc][3][tid];
        }
        float wv512 = -expf(wb[(size_t)512*CD + tid]);
        refs[0][tid] = carr[8][tid] + wv512;
        refs[1][tid] = carr[8][tid];
    }
    __syncthreads();
    const float* rbp = r + (size_t)b*CT*CD + h*64;
    const float* kbp = k + (size_t)b*CT*CD + h*64;
    size_t ob = (size_t)bh*CT*64;
    float ref_f = refs[0][ch], ref_b = refs[1][ch];
    for (int tc = 0; tc < 16; tc++){
        float run = carr[tc][ch];
        if (wid > 0) run += parts[tc][0][ch];
        if (wid > 1) run += parts[tc][1][ch];
        if (wid > 2) run += parts[tc][2][ch];
        int tb = tc*64 + wid*16;
        for (int s = 0; s < 16; s++){
            int t = tb + s;
            float wv = -expf(wb[(size_t)t*CD + ch]);
            run += wv;
            float csf = fminf(fmaxf(run - ref_f, -60.f), 60.f);
            float csb = fminf(fmaxf((run - wv) - ref_b, -60.f), 60.f);
            float rv = rbp[(size_t)t*CD + ch], kv = kbp[(size_t)t*CD + ch];
            rf[ob + (size_t)t*64 + ch] = rv * expf(csf);
            kf[ob + (size_t)t*64 + ch] = kv * expf(-csf);
            rb[ob + (size_t)t*64 + ch] = rv * expf(-csb);
            kb[ob + (size_t)t*64 + ch] = kv * expf(csb);
        }
    }
}

// ---------------- P(lower) = I + exp(clip(temp * kn knT)) ----------------
__global__ void k_gram(const float* __restrict__ kn, const float* __restrict__ lucid_temp,
                       float* __restrict__ P, int bh0){
    int t0 = blockIdx.y*64, s0 = blockIdx.x*64;
    if (t0 < s0) return;
    __shared__ float tA[64][65];
    __shared__ float tB[64][65];
    int lbh = blockIdx.z; int gbh = bh0 + lbh; int h = gbh % CH;
    int tid = threadIdx.x;
    LOAD_TILE(tA, kn + ((size_t)gbh*CT + t0)*64, 64);
    LOAD_TILE(tB, kn + ((size_t)gbh*CT + s0)*64, 64);
    __syncthreads();
    float tv = lucid_temp[h];
    tv = (tv > 20.f) ? tv : log1pf(expf(tv));
    int ty = (tid >> 4)*4, tx = (tid & 15)*4;
    float acc[4][4] = {};
    #pragma unroll
    for (int kk = 0; kk < 64; kk++){
        float a0[4], b0[4];
        #pragma unroll
        for (int i = 0; i < 4; i++){ a0[i] = tA[ty+i][kk]; b0[i] = tB[tx+i][kk]; }
        #pragma unroll
        for (int i = 0; i < 4; i++)
            #pragma unroll
            for (int j = 0; j < 4; j++) acc[i][j] += a0[i]*b0[j];
    }
    size_t pbase = (size_t)lbh*CT*CT;
    #pragma unroll
    for (int i = 0; i < 4; i++){
        int tt = t0+ty+i;
        float4 v;
        float g0 = fminf(fmaxf(tv*acc[i][0], -20.f), 20.f);
        float g1 = fminf(fmaxf(tv*acc[i][1], -20.f), 20.f);
        float g2 = fminf(fmaxf(tv*acc[i][2], -20.f), 20.f);
        float g3 = fminf(fmaxf(tv*acc[i][3], -20.f), 20.f);
        v.x = expf(g0) + ((tt == s0+tx+0) ? 1.f : 0.f);
        v.y = expf(g1) + ((tt == s0+tx+1) ? 1.f : 0.f);
        v.z = expf(g2) + ((tt == s0+tx+2) ? 1.f : 0.f);
        v.w = expf(g3) + ((tt == s0+tx+3) ? 1.f : 0.f);
        *(float4*)(P + pbase + (size_t)tt*CT + s0 + tx) = v;
    }
}

// ---------------- in-LDS 64x64 Cholesky + triangular inverse ----------------
__device__ __forceinline__ void potrf_inv(float (&s)[64][65], float (&inv)[64][65], int tid){
    for (int j = 0; j < 63; j++){
        __syncthreads();
        float invd = 1.f / fmaxf(s[j][j], 1e-20f);
        int n = 63 - j;
        for (int e = tid; e < n*n; e += 256){
            int ii = j+1 + e / n, cc = j+1 + e % n;
            s[ii][cc] -= s[ii][j]*s[cc][j]*invd;
        }
    }
    __syncthreads();
    for (int e = tid; e < 64*64; e += 256){
        int i2 = e >> 6, j2 = e & 63;
        if (i2 > j2) s[i2][j2] *= rsqrtf(fmaxf(s[j2][j2], 1e-20f));
    }
    __syncthreads();
    if (tid < 64) s[tid][tid] = sqrtf(fmaxf(s[tid][tid], 1e-20f));
    __syncthreads();
    if (tid < 64){
        int c = tid;
        for (int j = 0; j < c; j++) inv[j][c] = 0.f;
        for (int j = c; j < 64; j++){
            float sum = (j == c) ? 1.f : 0.f;
            for (int kk = c; kk < j; kk++) sum -= s[j][kk]*inv[kk][c];
            inv[j][c] = sum / s[j][j];
        }
    }
    __syncthreads();
}

__device__ __forceinline__ void potrf_writeout(float (&s)[64][65], float (&inv)[64][65], int tid,
                                               float* __restrict__ Pd, float* __restrict__ invp){
    for (int e = tid; e < 4096; e += 256){
        int r2 = e >> 6, c2 = e & 63;
        if (c2 <= r2) Pd[(size_t)r2*CT + c2] = s[r2][c2];
    }
    #pragma unroll
    for (int i_ = 0; i_ < 4; i_++){
        int rr_ = (tid>>4) + i_*16, cc_ = (tid&15)*4;
        float4 v_ = make_float4(inv[rr_][cc_], inv[rr_][cc_+1], inv[rr_][cc_+2], inv[rr_][cc_+3]);
        *(float4*)(invp + rr_*64 + cc_) = v_;
    }
}

__global__ void k_potrf0(float* __restrict__ P, float* __restrict__ invL){
    __shared__ float s[64][65], inv[64][65];
    int bh = blockIdx.x; int tid = threadIdx.x;
    size_t base = (size_t)bh*CT*CT;
    LOAD_TILE(s, P + base, CT);
    __syncthreads();
    potrf_inv(s, inv, tid);
    potrf_writeout(s, inv, tid, P + base, invL + (size_t)bh*16*4096);
}

// ---------------- TRSM: panel = A21 @ invL11^T ----------------
__global__ void k_trsm(float* __restrict__ P, const float* __restrict__ invL, int jb){
    __shared__ float a[64][65];
    __shared__ float iv[64][65];
    int bh = blockIdx.y;
    int r0 = (jb+1)*NB + blockIdx.x*64;
    int j0 = jb*NB;
    size_t base = (size_t)bh*CT*CT;
    int tid = threadIdx.x;
    const float* invp = invL + ((size_t)bh*16 + jb)*4096;
    LOAD_TILE(a, P + base + (size_t)r0*CT + j0, CT);
    LOAD_TILE(iv, invp, 64);
    __syncthreads();
    int ty = (tid >> 4)*4, tx = (tid & 15)*4;
    float acc[4][4] = {};
    #pragma unroll
    for (int kk = 0; kk < 64; kk++){
        float a0[4], b0[4];
        #pragma unroll
        for (int i = 0; i < 4; i++){ a0[i] = a[ty+i][kk]; b0[i] = iv[tx+i][kk]; }
        #pragma unroll
        for (int i = 0; i < 4; i++)
            #pragma unroll
            for (int j = 0; j < 4; j++) acc[i][j] += a0[i]*b0[j];
    }
    #pragma unroll
    for (int i = 0; i < 4; i++)
        *(float4*)(P + base + (size_t)(r0+ty+i)*CT + j0 + tx) =
            make_float4(acc[i][0], acc[i][1], acc[i][2], acc[i][3]);
}

// ---------------- fused SYRK + inline next-potrf + forward-solve column ----------------
// grid (nt+1, nt, Gc): tj<=ti -> syrk tile; tj==nt -> fwd solve for ib=jb+1+ti
__global__ void k_syrkf(float* __restrict__ P, float* __restrict__ invL,
                        float* __restrict__ X, float* __restrict__ Yb, int bh0, int jb){
    __shared__ float sA[64][65], sB[64][65], sC[64][65];
    int tj = blockIdx.x, ti = blockIdx.y, lbh = blockIdx.z;
    int tid = threadIdx.x;
    int ty = (tid >> 4)*4, tx = (tid & 15)*4;
    size_t base = (size_t)lbh*CT*CT;
    if (tj == gridDim.x - 1){
        // forward-solve role: Y = invL[jb] @ X[jb]; X[ib] -= L[ib][jb] @ Y
        int ib = jb + 1 + ti;
        const float* invp = invL + ((size_t)lbh*16 + jb)*4096;
        const float* Xj = X + ((size_t)(bh0+lbh)*CT + jb*64)*64;
        LOAD_TILE(sA, invp, 64);
        LOAD_TILE(sB, Xj, 64);
        __syncthreads();
        float c4[4][4] = {};
        #pragma unroll
        for (int kk = 0; kk < 64; kk++){
            float a0[4], b0[4];
            #pragma unroll
            for (int i = 0; i < 4; i++){ a0[i] = sA[ty+i][kk]; b0[i] = sB[kk][tx+i]; }
            #pragma unroll
            for (int i = 0; i < 4; i++)
                #pragma unroll
                for (int j = 0; j < 4; j++) c4[i][j] += a0[i]*b0[j];
        }
        if (ti == 0){
            float* yd = Yb + ((size_t)(bh0+lbh)*CT + jb*64)*64;
            #pragma unroll
            for (int i = 0; i < 4; i++)
                *(float4*)(yd + (size_t)(ty+i)*64 + tx) =
                    make_float4(c4[i][0], c4[i][1], c4[i][2], c4[i][3]);
        }
        #pragma unroll
        for (int i = 0; i < 4; i++)
            #pragma unroll
            for (int j = 0; j < 4; j++) sC[ty+i][tx+j] = c4[i][j];
        __syncthreads();
        LOAD_TILE(sA, P + base + (size_t)(ib*64)*CT + jb*64, CT);
        __syncthreads();
        float u4[4][4] = {};
        #pragma unroll
        for (int kk = 0; kk < 64; kk++){
            float a0[4], b0[4];
            #pragma unroll
            for (int i = 0; i < 4; i++){ a0[i] = sA[ty+i][kk]; b0[i] = sC[kk][tx+i]; }
            #pragma unroll
            for (int i = 0; i < 4; i++)
                #pragma unroll
                for (int j = 0; j < 4; j++) u4[i][j] += a0[i]*b0[j];
        }
        float* dst = X + ((size_t)(bh0+lbh)*CT + ib*64)*64;
        #pragma unroll
        for (int i = 0; i < 4; i++){
            float4* p4 = (float4*)(dst + (size_t)(ty+i)*64 + tx);
            float4 v = *p4;
            v.x -= u4[i][0]; v.y -= u4[i][1]; v.z -= u4[i][2]; v.w -= u4[i][3];
            *p4 = v;
        }
        return;
    }
    if (tj > ti) return;
    // SYRK role
    int off = (jb+1)*NB;
    int r0 = off + ti*64, c0 = off + tj*64, j0 = jb*NB;
    LOAD_TILE(sA, P + base + (size_t)r0*CT + j0, CT);
    LOAD_TILE(sB, P + base + (size_t)c0*CT + j0, CT);
    __syncthreads();
    float acc[4][4] = {};
    #pragma unroll
    for (int kk = 0; kk < 64; kk++){
        float a0[4], b0[4];
        #pragma unroll
        for (int i = 0; i < 4; i++){ a0[i] = sA[ty+i][kk]; b0[i] = sB[tx+i][kk]; }
        #pragma unroll
        for (int i = 0; i < 4; i++)
            #pragma unroll
            for (int j = 0; j < 4; j++) acc[i][j] += a0[i]*b0[j];
    }
    if (!(ti == 0 && tj == 0)){
        #pragma unroll
        for (int i = 0; i < 4; i++){
            float4* p4 = (float4*)(P + base + (size_t)(r0+ty+i)*CT + c0 + tx);
            float4 v = *p4;
            v.x -= acc[i][0]; v.y -= acc[i][1]; v.z -= acc[i][2]; v.w -= acc[i][3];
            *p4 = v;
        }
    } else {
        __syncthreads();
        #pragma unroll
        for (int i = 0; i < 4; i++){
            float4 v = *(const float4*)(P + base + (size_t)(r0+ty+i)*CT + c0 + tx);
            sA[ty+i][tx+0] = v.x - acc[i][0];
            sA[ty+i][tx+1] = v.y - acc[i][1];
            sA[ty+i][tx+2] = v.z - acc[i][2];
            sA[ty+i][tx+3] = v.w - acc[i][3];
        }
        __syncthreads();
        potrf_inv(sA, sB, tid);
        potrf_writeout(sA, sB, tid, P + base + (size_t)off*CT + off,
                       invL + ((size_t)lbh*16 + jb+1)*4096);
    }
}

// ---------------- fused block substitution (fwd tail + backward sweep) ----------------
template<int TRANS>
__global__ void k_solve(const float* __restrict__ P, const float* __restrict__ invL,
                        float* __restrict__ Xc, float* __restrict__ Yb, int bh0, int jb){
    __shared__ float A[64][65], B[64][65], C[64][65];
    int bh = blockIdx.y, tid = threadIdx.x;
    int ib = TRANS ? blockIdx.x : (jb + blockIdx.x);
    const float* invp = invL + ((size_t)bh*16 + jb)*4096;
    const float* src = (TRANS ? Yb : Xc) + ((size_t)(bh0+bh)*CT + jb*64)*64;
    LOAD_TILE(A, invp, 64);
    LOAD_TILE(B, src, 64);
    __syncthreads();
    int ty = (tid >> 4)*4, tx = (tid & 15)*4;
    float c4[4][4] = {};
    #pragma unroll
    for (int kk = 0; kk < 64; kk++){
        float a0[4], b0[4];
        #pragma unroll
        for (int i = 0; i < 4; i++){
            a0[i] = TRANS ? A[kk][ty+i] : A[ty+i][kk];
            b0[i] = B[kk][tx+i];
        }
        #pragma unroll
        for (int i = 0; i < 4; i++)
            #pragma unroll
            for (int j = 0; j < 4; j++) c4[i][j] += a0[i]*b0[j];
    }
    if (ib == jb){
        float* dst = (TRANS ? Xc : Yb) + ((size_t)(bh0+bh)*CT + jb*64)*64;
        #pragma unroll
        for (int i = 0; i < 4; i++)
            *(float4*)(dst + (size_t)(ty+i)*64 + tx) =
                make_float4(c4[i][0], c4[i][1], c4[i][2], c4[i][3]);
        return;
    }
    #pragma unroll
    for (int i = 0; i < 4; i++)
        #pragma unroll
        for (int j = 0; j < 4; j++) C[ty+i][tx+j] = c4[i][j];
    __syncthreads();
    const float* Lp = P + (size_t)bh*CT*CT + (TRANS ? ((size_t)(jb*64)*CT + ib*64)
                                                    : ((size_t)(ib*64)*CT + jb*64));
    LOAD_TILE(A, Lp, CT);
    __syncthreads();
    float u4[4][4] = {};
    #pragma unroll
    for (int kk = 0; kk < 64; kk++){
        float a0[4], b0[4];
        #pragma unroll
        for (int i = 0; i < 4; i++){
            a0[i] = TRANS ? A[kk][ty+i] : A[ty+i][kk];
            b0[i] = C[kk][tx+i];
        }
        #pragma unroll
        for (int i = 0; i < 4; i++)
            #pragma unroll
            for (int j = 0; j < 4; j++) u4[i][j] += a0[i]*b0[j];
    }
    float* dst = (TRANS ? Yb : Xc) + ((size_t)(bh0+bh)*CT + ib*64)*64;
    #pragma unroll
    for (int i = 0; i < 4; i++){
        float4* p4 = (float4*)(dst + (size_t)(ty+i)*64 + tx);
        float4 v = *p4;
        v.x -= u4[i][0]; v.y -= u4[i][1]; v.z -= u4[i][2]; v.w -= u4[i][3];
        *p4 = v;
    }
}

// ---------------- per-chunk outer products ----------------
__global__ void k_outer(const float* __restrict__ kf, const float* __restrict__ kb,
                        const float* __restrict__ X,
                        float* __restrict__ Sf, float* __restrict__ Sb){
    __shared__ float kfs[64][65], kbs[64][65], pvs[64][65];
    int c = blockIdx.x, bh = blockIdx.y, tid = threadIdx.x;
    size_t hb = (size_t)bh*CT*64 + (size_t)c*64*64;
    LOAD_TILE(kfs, kf + hb, 64);
    LOAD_TILE(kbs, kb + hb, 64);
    LOAD_TILE(pvs, X + hb, 64);
    __syncthreads();
    int ty = (tid >> 4)*4, tx = (tid & 15)*4;
    float af[4][4] = {}, ab[4][4] = {};
    #pragma unroll
    for (int kk = 0; kk < 64; kk++){
        float f0[4], g0[4], b0[4];
        #pragma unroll
        for (int i = 0; i < 4; i++){
            f0[i] = kfs[kk][ty+i];
            g0[i] = kbs[kk][ty+i];
            b0[i] = pvs[kk][tx+i];
        }
        #pragma unroll
        for (int i = 0; i < 4; i++)
            #pragma unroll
            for (int j = 0; j < 4; j++){
                af[i][j] += f0[i]*b0[j];
                ab[i][j] += g0[i]*b0[j];
            }
    }
    size_t sb = ((size_t)bh*16 + c)*4096;
    #pragma unroll
    for (int i = 0; i < 4; i++){
        *(float4*)(Sf + sb + (size_t)(ty+i)*64 + tx) = make_float4(af[i][0], af[i][1], af[i][2], af[i][3]);
        *(float4*)(Sb + sb + (size_t)(ty+i)*64 + tx) = make_float4(ab[i][0], ab[i][1], ab[i][2], ab[i][3]);
    }
}

// ---------------- in-place chunk-state cumsum ----------------
__global__ void k_cumsum(float* __restrict__ Sf, float* __restrict__ Sb){
    int bh = blockIdx.x, tid = threadIdx.x;
    size_t base = (size_t)bh*16*4096;
    #pragma unroll
    for (int i = 0; i < 16; i++){
        int e = tid + i*256;
        float run = 0.f;
        for (int c = 0; c < 16; c++){
            float* p = Sf + base + (size_t)c*4096 + e;
            float t = *p; *p = run; run += t;
        }
        run = 0.f;
        for (int c = 15; c >= 0; c--){
            float* p = Sb + base + (size_t)c*4096 + e;
            float t = *p; *p = run; run += t;
        }
    }
}

// ---------------- per-chunk y: masked diag + state GEMMs ----------------
__global__ void k_apv2(const float* __restrict__ rf, const float* __restrict__ kf,
                       const float* __restrict__ rb, const float* __restrict__ kb,
                       const float* __restrict__ X,
                       const float* __restrict__ Sf, const float* __restrict__ Sb,
                       float* __restrict__ y){
    __shared__ float rs[64][65], ks[64][65], at[64][65];
    int c = blockIdx.x, bh = blockIdx.y, tid = threadIdx.x;
    size_t hb = (size_t)bh*CT*64 + (size_t)c*64*64;
    size_t sb = ((size_t)bh*16 + c)*4096;
    int ty = (tid >> 4)*4, tx = (tid & 15)*4;
    LOAD_TILE(rs, rf + hb, 64);
    LOAD_TILE(ks, kf + hb, 64);
    __syncthreads();
    float a4[4][4] = {};
    #pragma unroll
    for (int kk = 0; kk < 64; kk++){
        float a0[4], b0[4];
        #pragma unroll
        for (int i = 0; i < 4; i++){ a0[i] = rs[ty+i][kk]; b0[i] = ks[tx+i][kk]; }
        #pragma unroll
        for (int i = 0; i < 4; i++)
            #pragma unroll
            for (int j = 0; j < 4; j++) a4[i][j] += a0[i]*b0[j];
    }
    __syncthreads();
    LOAD_TILE(rs, rb + hb, 64);
    LOAD_TILE(ks, kb + hb, 64);
    __syncthreads();
    float b4[4][4] = {};
    #pragma unroll
    for (int kk = 0; kk < 64; kk++){
        float a0[4], b0[4];
        #pragma unroll
        for (int i = 0; i < 4; i++){ a0[i] = rs[ty+i][kk]; b0[i] = ks[tx+i][kk]; }
        #pragma unroll
        for (int i = 0; i < 4; i++)
            #pragma unroll
            for (int j = 0; j < 4; j++) b4[i][j] += a0[i]*b0[j];
    }
    #pragma unroll
    for (int i = 0; i < 4; i++)
        #pragma unroll
        for (int j = 0; j < 4; j++)
            at[ty+i][tx+j] = ((ty+i) >= (tx+j)) ? a4[i][j] : b4[i][j];
    __syncthreads();
    LOAD_TILE(rs, X + hb, 64);
    __syncthreads();
    float yacc[4][4] = {};
    #pragma unroll 8
    for (int s = 0; s < 64; s++){
        float a0[4], b0[4];
        #pragma unroll
        for (int i = 0; i < 4; i++){ a0[i] = at[ty+i][s]; b0[i] = rs[s][tx+i]; }
        #pragma unroll
        for (int i = 0; i < 4; i++)
            #pragma unroll
            for (int j = 0; j < 4; j++) yacc[i][j] += a0[i]*b0[j];
    }
    __syncthreads();
    LOAD_TILE(rs, Sf + sb, 64);
    LOAD_TILE(ks, rf + hb, 64);
    __syncthreads();
    #pragma unroll 8
    for (int kk = 0; kk < 64; kk++){
        float a0[4], b0[4];
        #pragma unroll
        for (int i = 0; i < 4; i++){ a0[i] = ks[ty+i][kk]; b0[i] = rs[kk][tx+i]; }
        #pragma unroll
        for (int i = 0; i < 4; i++)
            #pragma unroll
            for (int j = 0; j < 4; j++) yacc[i][j] += a0[i]*b0[j];
    }
    __syncthreads();
    LOAD_TILE(rs, Sb + sb, 64);
    LOAD_TILE(ks, rb + hb, 64);
    __syncthreads();
    #pragma unroll 8
    for (int kk = 0; kk < 64; kk++){
        float a0[4], b0[4];
        #pragma unroll
        for (int i = 0; i < 4; i++){ a0[i] = ks[ty+i][kk]; b0[i] = rs[kk][tx+i]; }
        #pragma unroll
        for (int i = 0; i < 4; i++)
            #pragma unroll
            for (int j = 0; j < 4; j++) yacc[i][j] += a0[i]*b0[j];
    }
    #pragma unroll
    for (int i = 0; i < 4; i++)
        *(float4*)(y + hb + (size_t)(ty+i)*64 + tx) =
            make_float4(yacc[i][0], yacc[i][1], yacc[i][2], yacc[i][3]);
}

// ---------------- GroupNorm + gate ----------------
__global__ void k_gn(const float* __restrict__ y, const float* __restrict__ g,
                     const float* __restrict__ lnw, const float* __restrict__ lnb,
                     float* __restrict__ z){
    int gw = (blockIdx.x*256 + threadIdx.x) >> 6;
    int lane = threadIdx.x & 63;
    if (gw >= CB*CT*CH) return;
    int h = gw % CH; int bt = gw / CH;
    int b = bt / CT, t = bt % CT;
    int bh = b*CH + h;
    float yv = y[((size_t)bh*CT + t)*64 + lane];
    float s1 = yv, s2 = yv*yv;
    #pragma unroll
    for (int off = 32; off; off >>= 1){ s1 += __shfl_xor(s1, off); s2 += __shfl_xor(s2, off); }
    float mu = s1 * (1.f/64.f);
    float var = s2 * (1.f/64.f) - mu*mu;
    float inv = rsqrtf(var + 6.4e-4f);
    int d = h*64 + lane;
    float yn = (yv - mu)*inv*lnw[d] + lnb[d];
    z[(size_t)bt*CD + d] = yn * g[(size_t)bt*CD + d];
}

extern "C" void kernel_launch(void* const* d_in, const int* in_sizes, int n_in,
                              void* d_out, int out_size, void* d_ws, size_t ws_size,
                              hipStream_t stream){
    const float* x          = (const float*)d_in[0];
    const float* tmx        = (const float*)d_in[1];
    const float* tmw        = (const float*)d_in[2];
    const float* tmk        = (const float*)d_in[3];
    const float* tmv        = (const float*)d_in[4];
    const float* tmr        = (const float*)d_in[5];
    const float* tmg        = (const float*)d_in[6];
    const float* maa_w1     = (const float*)d_in[7];
    const float* maa_w2     = (const float*)d_in[8];
    const float* time_decay = (const float*)d_in[9];
    const float* decay_w1   = (const float*)d_in[10];
    const float* decay_w2   = (const float*)d_in[11];
    const float* lucid_temp = (const float*)d_in[12];
    const float* Wr         = (const float*)d_in[13];
    const float* Wk         = (const float*)d_in[14];
    const float* Wv         = (const float*)d_in[15];
    const float* Wg         = (const float*)d_in[16];
    const float* Wo         = (const float*)d_in[17];
    const float* lnw        = (const float*)d_in[18];
    const float* lnb        = (const float*)d_in[19];
    float* out = (float*)d_out;
    float* ws  = (float*)d_ws;

    const size_t S = (size_t)CB*CT*CD;
    float* b0 = ws;          // dxprev -> wbuf -> Yb -> Sb
    float* b1 = ws + 1*S;    // xxx -> xw -> rf
    float* b2 = ws + 2*S;    // xk -> kf
    float* b3 = ws + 3*S;    // xv -> rb
    float* b4 = ws + 4*S;    // xr -> kn -> Sf
    float* b5 = ws + 5*S;    // xg -> X (v -> Pv)
    float* b6 = ws + 6*S;    // rbuf -> y
    float* b7 = ws + 7*S;    // kbuf -> z
    float* b8 = ws + 8*S;    // vbuf -> kb
    float* b9 = ws + 9*S;    // gbuf
    float* mbuf = ws + 10*S;
    const size_t MB_F = 4096*160;
    size_t base_f = 10*S + MB_F;

    const size_t per_bh = (size_t)CT*CT + 16*NB*NB;
    size_t avail = ws_size / sizeof(float);
    int G = 1;
    if (avail > base_f + per_bh){
        size_t g = (avail - base_f) / per_bh;
        G = (g >= CBH) ? CBH : (int)g;
        if (G < 1) G = 1;
    }
    float* P    = ws + base_f;
    float* invL = P + (size_t)G*CT*CT;

    // weight split scratch lives in the P region (dead until k_gram)
    unsigned short* BtHi = (unsigned short*)P;
    unsigned short* BtLo = BtHi + (size_t)CD*CD;

    float* dxprev = b0; float* xxx = b1;
    float* xw = b1; float* xk = b2; float* xv = b3; float* xr = b4; float* xg = b5;
    float* rbuf = b6; float* kbuf = b7; float* vbuf = b8; float* gbuf = b9; float* wbuf = b0;
    float* kn = b4; float* X = b5;
    float* rf = b1; float* kf = b2; float* rb = b3; float* kb = b8;
    float* Yb = b0;
    float* Sf = b4; float* Sb = b0;
    float* ybuf = b6; float* zbuf = b7;

    dim3 mg(CD/64, (CB*CT)/64);
    dim3 tg(CD/64, CD/64);

    k_shift<<<dim3((CB*CT*CD + 255)/256), 256, 0, stream>>>(x, tmx, dxprev, xxx);
    k_gemm<1><<<dim3(3, 32), 256, 0, stream>>>(xxx, maa_w1, nullptr, mbuf, 4096, 160, 768);
    k_mix5<<<dim3(3, 4096), 256, 0, stream>>>(x, dxprev, mbuf, tmw, tmk, tmv, tmr, tmg,
                                              maa_w2, xw, xk, xv, xr, xg);
    k_splitT<<<tg, 256, 0, stream>>>(Wr, BtHi, BtLo, CD, CD);
    k_mgemm<0><<<mg, 256, 0, stream>>>(xr, BtHi, BtLo, nullptr, rbuf, 4096, CD, CD);
    k_splitT<<<tg, 256, 0, stream>>>(Wk, BtHi, BtLo, CD, CD);
    k_mgemm<0><<<mg, 256, 0, stream>>>(xk, BtHi, BtLo, nullptr, kbuf, 4096, CD, CD);
    k_splitT<<<tg, 256, 0, stream>>>(Wv, BtHi, BtLo, CD, CD);
    k_mgemm<0><<<mg, 256, 0, stream>>>(xv, BtHi, BtLo, nullptr, vbuf, 4096, CD, CD);
    k_splitT<<<tg, 256, 0, stream>>>(Wg, BtHi, BtLo, CD, CD);
    k_mgemm<2><<<mg, 256, 0, stream>>>(xg, BtHi, BtLo, nullptr, gbuf, 4096, CD, CD);
    // decay: mbuf = tanh(xw @ decay_w1); wbuf = mbuf @ decay_w2 + time_decay
    k_splitT<<<dim3(1, 12), 256, 0, stream>>>(decay_w1, BtHi, BtLo, CD, 64);
    k_mgemm<1><<<dim3(1, 64), 256, 0, stream>>>(xw, BtHi, BtLo, nullptr, mbuf, 4096, 64, CD);
    k_splitT<<<dim3(12, 1), 256, 0, stream>>>(decay_w2, BtHi, BtLo, 64, CD);
    k_mgemm<3><<<dim3(12, 64), 256, 0, stream>>>(mbuf, BtHi, BtLo, time_decay, wbuf, 4096, CD, 64);

    k_knvx<<<dim3((CB*CH*CT*64)/256), 256, 0, stream>>>(kbuf, vbuf, kn, X);
    k_scan2<<<dim3(CBH), 256, 0, stream>>>(rbuf, kbuf, wbuf, rf, kf, rb, kb);

    for (int bh0 = 0; bh0 < CBH; bh0 += G){
        int Gc = (CBH - bh0 < G) ? (CBH - bh0) : G;
        k_gram<<<dim3(16, 16, Gc), 256, 0, stream>>>(kn, lucid_temp, P, bh0);
        k_potrf0<<<dim3(Gc), 256, 0, stream>>>(P, invL);
        for (int jb = 0; jb < 15; jb++){
            int nt = 15 - jb;
            k_trsm<<<dim3(nt, Gc), 256, 0, stream>>>(P, invL, jb);
            k_syrkf<<<dim3(nt+1, nt, Gc), 256, 0, stream>>>(P, invL, X, Yb, bh0, jb);
        }
        k_solve<0><<<dim3(1, Gc), 256, 0, stream>>>(P, invL, X, Yb, bh0, 15);  // fwd tail (diag 15)
        for (int jb = 15; jb >= 0; jb--)
            k_solve<1><<<dim3(jb+1, Gc), 256, 0, stream>>>(P, invL, X, Yb, bh0, jb);
    }

    k_outer<<<dim3(16, CBH), 256, 0, stream>>>(kf, kb, X, Sf, Sb);
    k_cumsum<<<dim3(CBH), 256, 0, stream>>>(Sf, Sb);
    k_apv2<<<dim3(16, CBH), 256, 0, stream>>>(rf, kf, rb, kb, X, Sf, Sb, ybuf);
    k_gn<<<dim3((CB*CT*CH*64)/256), 256, 0, stream>>>(ybuf, gbuf, lnw, lnb, zbuf);
    k_splitT<<<tg, 256, 0, stream>>>(Wo, BtHi, BtLo, CD, CD);
    k_mgemm<0><<<mg, 256, 0, stream>>>(zbuf, BtHi, BtLo, nullptr, out, 4096, CD, CD);
}

// Round 11
// 4807.491 us; speedup vs baseline: 1.0000x; 1.0000x over previous
//
#include <hip/hip_runtime.h>
#include <math.h>

#define CB 4
#define CT 1024
#define CD 768
#define CH 12
#define CK 64
#define CBH (CB*CH)
#define NB 64

typedef __attribute__((ext_vector_type(8))) short sh8;
typedef __attribute__((ext_vector_type(8))) unsigned short ush8;
typedef __attribute__((ext_vector_type(4))) unsigned short ush4;
typedef __attribute__((ext_vector_type(4))) float fl4;

__device__ __forceinline__ unsigned short f2bf(float f){
    unsigned u = __builtin_bit_cast(unsigned, f);
    unsigned r = (u + 0x7fff + ((u >> 16) & 1)) >> 16;
    return (unsigned short)r;
}
__device__ __forceinline__ float bf2f(unsigned short u){
    return __builtin_bit_cast(float, (unsigned)u << 16);
}
#define MFMA3(acc, ah, al, bh_, bl_) { \
    acc = __builtin_amdgcn_mfma_f32_16x16x32_bf16(al, bh_, acc, 0, 0, 0); \
    acc = __builtin_amdgcn_mfma_f32_16x16x32_bf16(ah, bl_, acc, 0, 0, 0); \
    acc = __builtin_amdgcn_mfma_f32_16x16x32_bf16(ah, bh_, acc, 0, 0, 0); }

// cooperative 64x64 tile load: global (row-major, given stride) -> LDS [64][65]
#define LOAD_TILE(dst, src, stride) { \
    _Pragma("unroll") \
    for (int i_ = 0; i_ < 4; i_++){ \
        int rr_ = (tid>>4) + i_*16, cc_ = (tid&15)*4; \
        float4 v_ = *(const float4*)((src) + (size_t)rr_*(stride) + cc_); \
        dst[rr_][cc_+0]=v_.x; dst[rr_][cc_+1]=v_.y; dst[rr_][cc_+2]=v_.z; dst[rr_][cc_+3]=v_.w; \
    } }

// ---------------- elementwise: token shift + xxx ----------------
__global__ void k_shift(const float* __restrict__ x, const float* __restrict__ tmx,
                        float* __restrict__ dxprev, float* __restrict__ xxx){
    int idx = blockIdx.x*256 + threadIdx.x;
    if (idx >= CB*CT*CD) return;
    int d = idx % CD;
    int bt = idx / CD;
    int t = bt % CT;
    float xc = x[idx];
    float xl = (t > 0)      ? x[idx - CD] : 0.f;
    float xr = (t < CT-1)   ? x[idx + CD] : 0.f;
    float dx = 0.5f*(xl + xr) - xc;
    dxprev[idx] = dx;
    xxx[idx] = xc + dx * tmx[d];
}

// ---------------- generic tiled fp32 GEMM (maa_w1 only) ----------------
template<int MODE>
__global__ void k_gemm(const float* __restrict__ A, const float* __restrict__ Bm,
                       const float* __restrict__ bias, float* __restrict__ C,
                       int M, int N, int Kd){
    __shared__ float As[16][128];
    __shared__ float Bs[16][64];
    int tid = threadIdx.x;
    int m0 = blockIdx.y * 128, n0 = blockIdx.x * 64;
    int tn = (tid & 15) * 4;
    int tm = (tid >> 4) * 8;
    float acc[8][4] = {};
    for (int k0 = 0; k0 < Kd; k0 += 16){
        #pragma unroll
        for (int i = 0; i < 8; i++){
            int e = tid + i*256;
            int r = e >> 4, c = e & 15;
            As[c][r] = A[(size_t)(m0+r)*Kd + k0 + c];
        }
        #pragma unroll
        for (int i = 0; i < 4; i++){
            int e = tid + i*256;
            int r = e >> 6, c = e & 63;
            float bv = 0.f;
            if (n0 + c < N) bv = Bm[(size_t)(k0+r)*N + n0 + c];
            Bs[r][c] = bv;
        }
        __syncthreads();
        #pragma unroll
        for (int kk = 0; kk < 16; kk++){
            float a0[8], b0[4];
            #pragma unroll
            for (int i = 0; i < 8; i++) a0[i] = As[kk][tm+i];
            #pragma unroll
            for (int j = 0; j < 4; j++) b0[j] = Bs[kk][tn+j];
            #pragma unroll
            for (int i = 0; i < 8; i++)
                #pragma unroll
                for (int j = 0; j < 4; j++) acc[i][j] += a0[i]*b0[j];
        }
        __syncthreads();
    }
    #pragma unroll
    for (int i = 0; i < 8; i++)
        #pragma unroll
        for (int j = 0; j < 4; j++){
            int mm = m0 + tm + i, nn = n0 + tn + j;
            if (nn < N){
                float v = acc[i][j];
                if (MODE == 1) v = tanhf(v);
                else if (MODE == 2) v = v / (1.f + expf(-v));
                else if (MODE == 3) v += bias[nn];
                C[(size_t)mm*N + nn] = v;
            }
        }
}

// ---------------- weight transpose + split: B[K][N] -> Bt{Hi,Lo}[N][K] ----------------
__global__ void k_splitT(const float* __restrict__ B, unsigned short* __restrict__ hi,
                         unsigned short* __restrict__ lo, int Kd, int N){
    __shared__ float ts[64][65];
    int tid = threadIdx.x;
    int n0 = blockIdx.x*64, k0 = blockIdx.y*64;
    #pragma unroll
    for (int i = 0; i < 4; i++){
        int rr = (tid>>4) + i*16, cc = (tid&15)*4;
        float4 v = *(const float4*)(B + (size_t)(k0+rr)*N + n0 + cc);
        ts[rr][cc+0]=v.x; ts[rr][cc+1]=v.y; ts[rr][cc+2]=v.z; ts[rr][cc+3]=v.w;
    }
    __syncthreads();
    #pragma unroll
    for (int i = 0; i < 4; i++){
        int nl = (tid>>4) + i*16, k4 = (tid&15)*4;
        ush4 vh, vl;
        #pragma unroll
        for (int j = 0; j < 4; j++){
            float f = ts[k4+j][nl];
            unsigned short h = f2bf(f);
            vh[j] = h;
            vl[j] = f2bf(f - bf2f(h));
        }
        size_t o = (size_t)(n0+nl)*Kd + k0 + k4;
        *reinterpret_cast<ush4*>(hi + o) = vh;
        *reinterpret_cast<ush4*>(lo + o) = vl;
    }
}

// ---------------- MFMA split-bf16 GEMM: C[M,N] = A[M,K] @ Bt[N,K]^T ----------------
// MODE 0 plain, 1 tanh, 2 silu, 3 +bias[n]
template<int MODE>
__global__ __launch_bounds__(256) void k_mgemm(const float* __restrict__ A,
        const unsigned short* __restrict__ BtHi, const unsigned short* __restrict__ BtLo,
        const float* __restrict__ bias, float* __restrict__ C, int M, int N, int Kd){
    __shared__ unsigned short AHI[2048], ALO[2048], BHI[2048], BLO[2048];
    int tid = threadIdx.x;
    int n0 = blockIdx.x*64, m0 = blockIdx.y*64;
    int w = tid >> 6, lane = tid & 63;
    int wm = w >> 1, wn = w & 1;
    fl4 acc[2][2];
    #pragma unroll
    for (int mi = 0; mi < 2; mi++)
        #pragma unroll
        for (int ni = 0; ni < 2; ni++) acc[mi][ni] = (fl4){0.f, 0.f, 0.f, 0.f};
    int sm = tid >> 2;
    int sk = (tid & 3) * 8;
    int slane = (sm & 15) + ((tid & 3) << 4);
    int sidx = (((sm >> 4)*64) + slane) * 8;
    const int nsteps = Kd >> 5;
    for (int ks = 0; ks < nsteps; ks++){
        int k0 = ks << 5;
        __syncthreads();
        {
            const float* ap = A + (size_t)(m0+sm)*Kd + k0 + sk;
            float4 a0 = *(const float4*)ap, a1 = *(const float4*)(ap+4);
            float av[8] = {a0.x,a0.y,a0.z,a0.w,a1.x,a1.y,a1.z,a1.w};
            ush8 vh, vl;
            #pragma unroll
            for (int i = 0; i < 8; i++){
                unsigned short h = f2bf(av[i]);
                vh[i] = h;
                vl[i] = f2bf(av[i] - bf2f(h));
            }
            *reinterpret_cast<ush8*>(&AHI[sidx]) = vh;
            *reinterpret_cast<ush8*>(&ALO[sidx]) = vl;
            size_t bo = (size_t)(n0+sm)*Kd + k0 + sk;
            *reinterpret_cast<ush8*>(&BHI[sidx]) = *reinterpret_cast<const ush8*>(BtHi + bo);
            *reinterpret_cast<ush8*>(&BLO[sidx]) = *reinterpret_cast<const ush8*>(BtLo + bo);
        }
        __syncthreads();
        sh8 ah[2], al[2], bh[2], bl[2];
        #pragma unroll
        for (int mi = 0; mi < 2; mi++){
            int gm = wm*2 + mi;
            ah[mi] = *reinterpret_cast<sh8*>(&AHI[(gm*64 + lane)*8]);
            al[mi] = *reinterpret_cast<sh8*>(&ALO[(gm*64 + lane)*8]);
        }
        #pragma unroll
        for (int ni = 0; ni < 2; ni++){
            int gn = wn*2 + ni;
            bh[ni] = *reinterpret_cast<sh8*>(&BHI[(gn*64 + lane)*8]);
            bl[ni] = *reinterpret_cast<sh8*>(&BLO[(gn*64 + lane)*8]);
        }
        #pragma unroll
        for (int mi = 0; mi < 2; mi++)
            #pragma unroll
            for (int ni = 0; ni < 2; ni++)
                MFMA3(acc[mi][ni], ah[mi], al[mi], bh[ni], bl[ni]);
    }
    #pragma unroll
    for (int mi = 0; mi < 2; mi++)
        #pragma unroll
        for (int ni = 0; ni < 2; ni++){
            int cc = n0 + wn*32 + ni*16 + (lane & 15);
            int rb = m0 + wm*32 + mi*16 + ((lane >> 4) << 2);
            #pragma unroll
            for (int j = 0; j < 4; j++){
                float v = acc[mi][ni][j];
                if (MODE == 1) v = tanhf(v);
                else if (MODE == 2) v = v / (1.f + expf(-v));
                else if (MODE == 3) v += bias[cc];
                C[(size_t)(rb+j)*N + cc] = v;
            }
        }
}

// ---------------- 5-way low-rank mix ----------------
__global__ void k_mix5(const float* __restrict__ x, const float* __restrict__ dxprev,
                       const float* __restrict__ m,
                       const float* __restrict__ tmw, const float* __restrict__ tmk,
                       const float* __restrict__ tmv, const float* __restrict__ tmr,
                       const float* __restrict__ tmg, const float* __restrict__ w2,
                       float* __restrict__ xw, float* __restrict__ xk, float* __restrict__ xv,
                       float* __restrict__ xr, float* __restrict__ xg){
    __shared__ float ms[160];
    int i = blockIdx.y;
    int j = blockIdx.x*256 + threadIdx.x;
    if (threadIdx.x < 160) ms[threadIdx.x] = m[(size_t)i*160 + threadIdx.x];
    __syncthreads();
    float xc = x[(size_t)i*CD + j], dx = dxprev[(size_t)i*CD + j];
    const float* tms[5] = {tmw, tmk, tmv, tmr, tmg};
    float* outs[5] = {xw, xk, xv, xr, xg};
    #pragma unroll
    for (int c = 0; c < 5; c++){
        float s = tms[c][j];
        const float* w2c = w2 + (size_t)c*32*CD + j;
        #pragma unroll
        for (int dm = 0; dm < 32; dm++) s += ms[c*32+dm] * w2c[(size_t)dm*CD];
        outs[c][(size_t)i*CD + j] = xc + dx*s;
    }
}

// ---------------- normalize k, stage v into X (head layout) ----------------
__global__ void k_knvx(const float* __restrict__ k, const float* __restrict__ v,
                       float* __restrict__ kn, float* __restrict__ X){
    int gw = (blockIdx.x*256 + threadIdx.x) >> 6;
    int lane = threadIdx.x & 63;
    if (gw >= CB*CH*CT) return;
    int t = gw % CT; int bh = gw / CT; int h = bh % CH; int b = bh / CH;
    size_t src = ((size_t)(b*CT + t))*CD + h*64 + lane;
    float kv = k[src];
    float ss = kv*kv;
    #pragma unroll
    for (int off = 32; off; off >>= 1) ss += __shfl_xor(ss, off);
    float nrm = fmaxf(sqrtf(ss), 1e-12f);
    size_t dst = ((size_t)bh*CT + t)*64 + lane;
    kn[dst] = kv / nrm;
    X[dst]  = v[src];
}

// ---------------- decay scan, fully coalesced ----------------
__global__ __launch_bounds__(256) void k_scan2(const float* __restrict__ r, const float* __restrict__ k,
                        const float* __restrict__ w,
                        float* __restrict__ rf, float* __restrict__ kf,
                        float* __restrict__ rb, float* __restrict__ kb){
    __shared__ float parts[16][4][64];
    __shared__ float carr[16][64];
    __shared__ float refs[2][64];
    int bh = blockIdx.x; int h = bh % CH; int b = bh / CH;
    int tid = threadIdx.x; int wid = tid >> 6; int ch = tid & 63;
    const float* wb = w + (size_t)b*CT*CD + h*64;
    for (int tc = 0; tc < 16; tc++){
        float sum = 0.f;
        int tb = tc*64 + wid*16;
        for (int s = 0; s < 16; s++)
            sum -= expf(wb[(size_t)(tb+s)*CD + ch]);
        parts[tc][wid][ch] = sum;
    }
    __syncthreads();
    if (tid < 64){
        float run = 0.f;
        for (int tc = 0; tc < 16; tc++){
            carr[tc][tid] = run;
            run += parts[tc][0][tid] + parts[tc][1][tid] + parts[tc][2][tid] + parts[tc][3][tid];
        }
        float wv512 = -expf(wb[(size_t)512*CD + tid]);
        refs[0][tid] = carr[8][tid] + wv512;
        refs[1][tid] = carr[8][tid];
    }
    __syncthreads();
    const float* rbp = r + (size_t)b*CT*CD + h*64;
    const float* kbp = k + (size_t)b*CT*CD + h*64;
    size_t ob = (size_t)bh*CT*64;
    float ref_f = refs[0][ch], ref_b = refs[1][ch];
    for (int tc = 0; tc < 16; tc++){
        float run = carr[tc][ch];
        if (wid > 0) run += parts[tc][0][ch];
        if (wid > 1) run += parts[tc][1][ch];
        if (wid > 2) run += parts[tc][2][ch];
        int tb = tc*64 + wid*16;
        for (int s = 0; s < 16; s++){
            int t = tb + s;
            float wv = -expf(wb[(size_t)t*CD + ch]);
            run += wv;
            float csf = fminf(fmaxf(run - ref_f, -60.f), 60.f);
            float csb = fminf(fmaxf((run - wv) - ref_b, -60.f), 60.f);
            float rv = rbp[(size_t)t*CD + ch], kv = kbp[(size_t)t*CD + ch];
            rf[ob + (size_t)t*64 + ch] = rv * expf(csf);
            kf[ob + (size_t)t*64 + ch] = kv * expf(-csf);
            rb[ob + (size_t)t*64 + ch] = rv * expf(-csb);
            kb[ob + (size_t)t*64 + ch] = kv * expf(csb);
        }
    }
}

// ---------------- P(lower) = I + exp(clip(temp * kn knT)) ----------------
__global__ void k_gram(const float* __restrict__ kn, const float* __restrict__ lucid_temp,
                       float* __restrict__ P, int bh0){
    int t0 = blockIdx.y*64, s0 = blockIdx.x*64;
    if (t0 < s0) return;
    __shared__ float tA[64][65];
    __shared__ float tB[64][65];
    int lbh = blockIdx.z; int gbh = bh0 + lbh; int h = gbh % CH;
    int tid = threadIdx.x;
    LOAD_TILE(tA, kn + ((size_t)gbh*CT + t0)*64, 64);
    LOAD_TILE(tB, kn + ((size_t)gbh*CT + s0)*64, 64);
    __syncthreads();
    float tv = lucid_temp[h];
    tv = (tv > 20.f) ? tv : log1pf(expf(tv));
    int ty = (tid >> 4)*4, tx = (tid & 15)*4;
    float acc[4][4] = {};
    #pragma unroll
    for (int kk = 0; kk < 64; kk++){
        float a0[4], b0[4];
        #pragma unroll
        for (int i = 0; i < 4; i++){ a0[i] = tA[ty+i][kk]; b0[i] = tB[tx+i][kk]; }
        #pragma unroll
        for (int i = 0; i < 4; i++)
            #pragma unroll
            for (int j = 0; j < 4; j++) acc[i][j] += a0[i]*b0[j];
    }
    size_t pbase = (size_t)lbh*CT*CT;
    #pragma unroll
    for (int i = 0; i < 4; i++){
        int tt = t0+ty+i;
        float4 v;
        float g0 = fminf(fmaxf(tv*acc[i][0], -20.f), 20.f);
        float g1 = fminf(fmaxf(tv*acc[i][1], -20.f), 20.f);
        float g2 = fminf(fmaxf(tv*acc[i][2], -20.f), 20.f);
        float g3 = fminf(fmaxf(tv*acc[i][3], -20.f), 20.f);
        v.x = expf(g0) + ((tt == s0+tx+0) ? 1.f : 0.f);
        v.y = expf(g1) + ((tt == s0+tx+1) ? 1.f : 0.f);
        v.z = expf(g2) + ((tt == s0+tx+2) ? 1.f : 0.f);
        v.w = expf(g3) + ((tt == s0+tx+3) ? 1.f : 0.f);
        *(float4*)(P + pbase + (size_t)tt*CT + s0 + tx) = v;
    }
}

// ---------------- in-LDS 64x64 Cholesky + triangular inverse ----------------
__device__ __forceinline__ void potrf_inv(float (&s)[64][65], float (&inv)[64][65], int tid){
    for (int j = 0; j < 63; j++){
        __syncthreads();
        float invd = 1.f / fmaxf(s[j][j], 1e-20f);
        int n = 63 - j;
        for (int e = tid; e < n*n; e += 256){
            int ii = j+1 + e / n, cc = j+1 + e % n;
            s[ii][cc] -= s[ii][j]*s[cc][j]*invd;
        }
    }
    __syncthreads();
    for (int e = tid; e < 64*64; e += 256){
        int i2 = e >> 6, j2 = e & 63;
        if (i2 > j2) s[i2][j2] *= rsqrtf(fmaxf(s[j2][j2], 1e-20f));
    }
    __syncthreads();
    if (tid < 64) s[tid][tid] = sqrtf(fmaxf(s[tid][tid], 1e-20f));
    __syncthreads();
    if (tid < 64){
        int c = tid;
        for (int j = 0; j < c; j++) inv[j][c] = 0.f;
        for (int j = c; j < 64; j++){
            float sum = (j == c) ? 1.f : 0.f;
            for (int kk = c; kk < j; kk++) sum -= s[j][kk]*inv[kk][c];
            inv[j][c] = sum / s[j][j];
        }
    }
    __syncthreads();
}

__device__ __forceinline__ void potrf_writeout(float (&s)[64][65], float (&inv)[64][65], int tid,
                                               float* __restrict__ Pd, float* __restrict__ invp){
    for (int e = tid; e < 4096; e += 256){
        int r2 = e >> 6, c2 = e & 63;
        if (c2 <= r2) Pd[(size_t)r2*CT + c2] = s[r2][c2];
    }
    #pragma unroll
    for (int i_ = 0; i_ < 4; i_++){
        int rr_ = (tid>>4) + i_*16, cc_ = (tid&15)*4;
        float4 v_ = make_float4(inv[rr_][cc_], inv[rr_][cc_+1], inv[rr_][cc_+2], inv[rr_][cc_+3]);
        *(float4*)(invp + rr_*64 + cc_) = v_;
    }
}

__global__ void k_potrf0(float* __restrict__ P, float* __restrict__ invL){
    __shared__ float s[64][65], inv[64][65];
    int bh = blockIdx.x; int tid = threadIdx.x;
    size_t base = (size_t)bh*CT*CT;
    LOAD_TILE(s, P + base, CT);
    __syncthreads();
    potrf_inv(s, inv, tid);
    potrf_writeout(s, inv, tid, P + base, invL + (size_t)bh*16*4096);
}

// ---------------- TRSM: panel = A21 @ invL11^T ----------------
__global__ void k_trsm(float* __restrict__ P, const float* __restrict__ invL, int jb){
    __shared__ float a[64][65];
    __shared__ float iv[64][65];
    int bh = blockIdx.y;
    int r0 = (jb+1)*NB + blockIdx.x*64;
    int j0 = jb*NB;
    size_t base = (size_t)bh*CT*CT;
    int tid = threadIdx.x;
    const float* invp = invL + ((size_t)bh*16 + jb)*4096;
    LOAD_TILE(a, P + base + (size_t)r0*CT + j0, CT);
    LOAD_TILE(iv, invp, 64);
    __syncthreads();
    int ty = (tid >> 4)*4, tx = (tid & 15)*4;
    float acc[4][4] = {};
    #pragma unroll
    for (int kk = 0; kk < 64; kk++){
        float a0[4], b0[4];
        #pragma unroll
        for (int i = 0; i < 4; i++){ a0[i] = a[ty+i][kk]; b0[i] = iv[tx+i][kk]; }
        #pragma unroll
        for (int i = 0; i < 4; i++)
            #pragma unroll
            for (int j = 0; j < 4; j++) acc[i][j] += a0[i]*b0[j];
    }
    #pragma unroll
    for (int i = 0; i < 4; i++)
        *(float4*)(P + base + (size_t)(r0+ty+i)*CT + j0 + tx) =
            make_float4(acc[i][0], acc[i][1], acc[i][2], acc[i][3]);
}

// ---------------- fused SYRK + inline next-potrf + forward-solve column ----------------
// grid (nt+1, nt, Gc): tj<=ti -> syrk tile; tj==nt -> fwd solve for ib=jb+1+ti
__global__ void k_syrkf(float* __restrict__ P, float* __restrict__ invL,
                        float* __restrict__ X, float* __restrict__ Yb, int bh0, int jb){
    __shared__ float sA[64][65], sB[64][65], sC[64][65];
    int tj = blockIdx.x, ti = blockIdx.y, lbh = blockIdx.z;
    int tid = threadIdx.x;
    int ty = (tid >> 4)*4, tx = (tid & 15)*4;
    size_t base = (size_t)lbh*CT*CT;
    if (tj == gridDim.x - 1){
        // forward-solve role: Y = invL[jb] @ X[jb]; X[ib] -= L[ib][jb] @ Y
        int ib = jb + 1 + ti;
        const float* invp = invL + ((size_t)lbh*16 + jb)*4096;
        const float* Xj = X + ((size_t)(bh0+lbh)*CT + jb*64)*64;
        LOAD_TILE(sA, invp, 64);
        LOAD_TILE(sB, Xj, 64);
        __syncthreads();
        float c4[4][4] = {};
        #pragma unroll
        for (int kk = 0; kk < 64; kk++){
            float a0[4], b0[4];
            #pragma unroll
            for (int i = 0; i < 4; i++){ a0[i] = sA[ty+i][kk]; b0[i] = sB[kk][tx+i]; }
            #pragma unroll
            for (int i = 0; i < 4; i++)
                #pragma unroll
                for (int j = 0; j < 4; j++) c4[i][j] += a0[i]*b0[j];
        }
        if (ti == 0){
            float* yd = Yb + ((size_t)(bh0+lbh)*CT + jb*64)*64;
            #pragma unroll
            for (int i = 0; i < 4; i++)
                *(float4*)(yd + (size_t)(ty+i)*64 + tx) =
                    make_float4(c4[i][0], c4[i][1], c4[i][2], c4[i][3]);
        }
        #pragma unroll
        for (int i = 0; i < 4; i++)
            #pragma unroll
            for (int j = 0; j < 4; j++) sC[ty+i][tx+j] = c4[i][j];
        __syncthreads();
        LOAD_TILE(sA, P + base + (size_t)(ib*64)*CT + jb*64, CT);
        __syncthreads();
        float u4[4][4] = {};
        #pragma unroll
        for (int kk = 0; kk < 64; kk++){
            float a0[4], b0[4];
            #pragma unroll
            for (int i = 0; i < 4; i++){ a0[i] = sA[ty+i][kk]; b0[i] = sC[kk][tx+i]; }
            #pragma unroll
            for (int i = 0; i < 4; i++)
                #pragma unroll
                for (int j = 0; j < 4; j++) u4[i][j] += a0[i]*b0[j];
        }
        float* dst = X + ((size_t)(bh0+lbh)*CT + ib*64)*64;
        #pragma unroll
        for (int i = 0; i < 4; i++){
            float4* p4 = (float4*)(dst + (size_t)(ty+i)*64 + tx);
            float4 v = *p4;
            v.x -= u4[i][0]; v.y -= u4[i][1]; v.z -= u4[i][2]; v.w -= u4[i][3];
            *p4 = v;
        }
        return;
    }
    if (tj > ti) return;
    // SYRK role
    int off = (jb+1)*NB;
    int r0 = off + ti*64, c0 = off + tj*64, j0 = jb*NB;
    LOAD_TILE(sA, P + base + (size_t)r0*CT + j0, CT);
    LOAD_TILE(sB, P + base + (size_t)c0*CT + j0, CT);
    __syncthreads();
    float acc[4][4] = {};
    #pragma unroll
    for (int kk = 0; kk < 64; kk++){
        float a0[4], b0[4];
        #pragma unroll
        for (int i = 0; i < 4; i++){ a0[i] = sA[ty+i][kk]; b0[i] = sB[tx+i][kk]; }
        #pragma unroll
        for (int i = 0; i < 4; i++)
            #pragma unroll
            for (int j = 0; j < 4; j++) acc[i][j] += a0[i]*b0[j];
    }
    if (!(ti == 0 && tj == 0)){
        #pragma unroll
        for (int i = 0; i < 4; i++){
            float4* p4 = (float4*)(P + base + (size_t)(r0+ty+i)*CT + c0 + tx);
            float4 v = *p4;
            v.x -= acc[i][0]; v.y -= acc[i][1]; v.z -= acc[i][2]; v.w -= acc[i][3];
            *p4 = v;
        }
    } else {
        __syncthreads();
        #pragma unroll
        for (int i = 0; i < 4; i++){
            float4 v = *(const float4*)(P + base + (size_t)(r0+ty+i)*CT + c0 + tx);
            sA[ty+i][tx+0] = v.x - acc[i][0];
            sA[ty+i][tx+1] = v.y - acc[i][1];
            sA[ty+i][tx+2] = v.z - acc[i][2];
            sA[ty+i][tx+3] = v.w - acc[i][3];
        }
        __syncthreads();
        potrf_inv(sA, sB, tid);
        potrf_writeout(sA, sB, tid, P + base + (size_t)off*CT + off,
                       invL + ((size_t)lbh*16 + jb+1)*4096);
    }
}

// ---------------- fused block substitution (fwd tail + backward sweep) ----------------
template<int TRANS>
__global__ void k_solve(const float* __restrict__ P, const float* __restrict__ invL,
                        float* __restrict__ Xc, float* __restrict__ Yb, int bh0, int jb){
    __shared__ float A[64][65], B[64][65], C[64][65];
    int bh = blockIdx.y, tid = threadIdx.x;
    int ib = TRANS ? blockIdx.x : (jb + blockIdx.x);
    const float* invp = invL + ((size_t)bh*16 + jb)*4096;
    const float* src = (TRANS ? Yb : Xc) + ((size_t)(bh0+bh)*CT + jb*64)*64;
    LOAD_TILE(A, invp, 64);
    LOAD_TILE(B, src, 64);
    __syncthreads();
    int ty = (tid >> 4)*4, tx = (tid & 15)*4;
    float c4[4][4] = {};
    #pragma unroll
    for (int kk = 0; kk < 64; kk++){
        float a0[4], b0[4];
        #pragma unroll
        for (int i = 0; i < 4; i++){
            a0[i] = TRANS ? A[kk][ty+i] : A[ty+i][kk];
            b0[i] = B[kk][tx+i];
        }
        #pragma unroll
        for (int i = 0; i < 4; i++)
            #pragma unroll
            for (int j = 0; j < 4; j++) c4[i][j] += a0[i]*b0[j];
    }
    if (ib == jb){
        float* dst = (TRANS ? Xc : Yb) + ((size_t)(bh0+bh)*CT + jb*64)*64;
        #pragma unroll
        for (int i = 0; i < 4; i++)
            *(float4*)(dst + (size_t)(ty+i)*64 + tx) =
                make_float4(c4[i][0], c4[i][1], c4[i][2], c4[i][3]);
        return;
    }
    #pragma unroll
    for (int i = 0; i < 4; i++)
        #pragma unroll
        for (int j = 0; j < 4; j++) C[ty+i][tx+j] = c4[i][j];
    __syncthreads();
    const float* Lp = P + (size_t)bh*CT*CT + (TRANS ? ((size_t)(jb*64)*CT + ib*64)
                                                    : ((size_t)(ib*64)*CT + jb*64));
    LOAD_TILE(A, Lp, CT);
    __syncthreads();
    float u4[4][4] = {};
    #pragma unroll
    for (int kk = 0; kk < 64; kk++){
        float a0[4], b0[4];
        #pragma unroll
        for (int i = 0; i < 4; i++){
            a0[i] = TRANS ? A[kk][ty+i] : A[ty+i][kk];
            b0[i] = C[kk][tx+i];
        }
        #pragma unroll
        for (int i = 0; i < 4; i++)
            #pragma unroll
            for (int j = 0; j < 4; j++) u4[i][j] += a0[i]*b0[j];
    }
    float* dst = (TRANS ? Yb : Xc) + ((size_t)(bh0+bh)*CT + ib*64)*64;
    #pragma unroll
    for (int i = 0; i < 4; i++){
        float4* p4 = (float4*)(dst + (size_t)(ty+i)*64 + tx);
        float4 v = *p4;
        v.x -= u4[i][0]; v.y -= u4[i][1]; v.z -= u4[i][2]; v.w -= u4[i][3];
        *p4 = v;
    }
}

// ---------------- per-chunk outer products ----------------
__global__ void k_outer(const float* __restrict__ kf, const float* __restrict__ kb,
                        const float* __restrict__ X,
                        float* __restrict__ Sf, float* __restrict__ Sb){
    __shared__ float kfs[64][65], kbs[64][65], pvs[64][65];
    int c = blockIdx.x, bh = blockIdx.y, tid = threadIdx.x;
    size_t hb = (size_t)bh*CT*64 + (size_t)c*64*64;
    LOAD_TILE(kfs, kf + hb, 64);
    LOAD_TILE(kbs, kb + hb, 64);
    LOAD_TILE(pvs, X + hb, 64);
    __syncthreads();
    int ty = (tid >> 4)*4, tx = (tid & 15)*4;
    float af[4][4] = {}, ab[4][4] = {};
    #pragma unroll
    for (int kk = 0; kk < 64; kk++){
        float f0[4], g0[4], b0[4];
        #pragma unroll
        for (int i = 0; i < 4; i++){
            f0[i] = kfs[kk][ty+i];
            g0[i] = kbs[kk][ty+i];
            b0[i] = pvs[kk][tx+i];
        }
        #pragma unroll
        for (int i = 0; i < 4; i++)
            #pragma unroll
            for (int j = 0; j < 4; j++){
                af[i][j] += f0[i]*b0[j];
                ab[i][j] += g0[i]*b0[j];
            }
    }
    size_t sb = ((size_t)bh*16 + c)*4096;
    #pragma unroll
    for (int i = 0; i < 4; i++){
        *(float4*)(Sf + sb + (size_t)(ty+i)*64 + tx) = make_float4(af[i][0], af[i][1], af[i][2], af[i][3]);
        *(float4*)(Sb + sb + (size_t)(ty+i)*64 + tx) = make_float4(ab[i][0], ab[i][1], ab[i][2], ab[i][3]);
    }
}

// ---------------- in-place chunk-state cumsum ----------------
__global__ void k_cumsum(float* __restrict__ Sf, float* __restrict__ Sb){
    int bh = blockIdx.x, tid = threadIdx.x;
    size_t base = (size_t)bh*16*4096;
    #pragma unroll
    for (int i = 0; i < 16; i++){
        int e = tid + i*256;
        float run = 0.f;
        for (int c = 0; c < 16; c++){
            float* p = Sf + base + (size_t)c*4096 + e;
            float t = *p; *p = run; run += t;
        }
        run = 0.f;
        for (int c = 15; c >= 0; c--){
            float* p = Sb + base + (size_t)c*4096 + e;
            float t = *p; *p = run; run += t;
        }
    }
}

// ---------------- per-chunk y: masked diag + state GEMMs ----------------
__global__ void k_apv2(const float* __restrict__ rf, const float* __restrict__ kf,
                       const float* __restrict__ rb, const float* __restrict__ kb,
                       const float* __restrict__ X,
                       const float* __restrict__ Sf, const float* __restrict__ Sb,
                       float* __restrict__ y){
    __shared__ float rs[64][65], ks[64][65], at[64][65];
    int c = blockIdx.x, bh = blockIdx.y, tid = threadIdx.x;
    size_t hb = (size_t)bh*CT*64 + (size_t)c*64*64;
    size_t sb = ((size_t)bh*16 + c)*4096;
    int ty = (tid >> 4)*4, tx = (tid & 15)*4;
    LOAD_TILE(rs, rf + hb, 64);
    LOAD_TILE(ks, kf + hb, 64);
    __syncthreads();
    float a4[4][4] = {};
    #pragma unroll
    for (int kk = 0; kk < 64; kk++){
        float a0[4], b0[4];
        #pragma unroll
        for (int i = 0; i < 4; i++){ a0[i] = rs[ty+i][kk]; b0[i] = ks[tx+i][kk]; }
        #pragma unroll
        for (int i = 0; i < 4; i++)
            #pragma unroll
            for (int j = 0; j < 4; j++) a4[i][j] += a0[i]*b0[j];
    }
    __syncthreads();
    LOAD_TILE(rs, rb + hb, 64);
    LOAD_TILE(ks, kb + hb, 64);
    __syncthreads();
    float b4[4][4] = {};
    #pragma unroll
    for (int kk = 0; kk < 64; kk++){
        float a0[4], b0[4];
        #pragma unroll
        for (int i = 0; i < 4; i++){ a0[i] = rs[ty+i][kk]; b0[i] = ks[tx+i][kk]; }
        #pragma unroll
        for (int i = 0; i < 4; i++)
            #pragma unroll
            for (int j = 0; j < 4; j++) b4[i][j] += a0[i]*b0[j];
    }
    #pragma unroll
    for (int i = 0; i < 4; i++)
        #pragma unroll
        for (int j = 0; j < 4; j++)
            at[ty+i][tx+j] = ((ty+i) >= (tx+j)) ? a4[i][j] : b4[i][j];
    __syncthreads();
    LOAD_TILE(rs, X + hb, 64);
    __syncthreads();
    float yacc[4][4] = {};
    #pragma unroll 8
    for (int s = 0; s < 64; s++){
        float a0[4], b0[4];
        #pragma unroll
        for (int i = 0; i < 4; i++){ a0[i] = at[ty+i][s]; b0[i] = rs[s][tx+i]; }
        #pragma unroll
        for (int i = 0; i < 4; i++)
            #pragma unroll
            for (int j = 0; j < 4; j++) yacc[i][j] += a0[i]*b0[j];
    }
    __syncthreads();
    LOAD_TILE(rs, Sf + sb, 64);
    LOAD_TILE(ks, rf + hb, 64);
    __syncthreads();
    #pragma unroll 8
    for (int kk = 0; kk < 64; kk++){
        float a0[4], b0[4];
        #pragma unroll
        for (int i = 0; i < 4; i++){ a0[i] = ks[ty+i][kk]; b0[i] = rs[kk][tx+i]; }
        #pragma unroll
        for (int i = 0; i < 4; i++)
            #pragma unroll
            for (int j = 0; j < 4; j++) yacc[i][j] += a0[i]*b0[j];
    }
    __syncthreads();
    LOAD_TILE(rs, Sb + sb, 64);
    LOAD_TILE(ks, rb + hb, 64);
    __syncthreads();
    #pragma unroll 8
    for (int kk = 0; kk < 64; kk++){
        float a0[4], b0[4];
        #pragma unroll
        for (int i = 0; i < 4; i++){ a0[i] = ks[ty+i][kk]; b0[i] = rs[kk][tx+i]; }
        #pragma unroll
        for (int i = 0; i < 4; i++)
            #pragma unroll
            for (int j = 0; j < 4; j++) yacc[i][j] += a0[i]*b0[j];
    }
    #pragma unroll
    for (int i = 0; i < 4; i++)
        *(float4*)(y + hb + (size_t)(ty+i)*64 + tx) =
            make_float4(yacc[i][0], yacc[i][1], yacc[i][2], yacc[i][3]);
}

// ---------------- GroupNorm + gate ----------------
__global__ void k_gn(const float* __restrict__ y, const float* __restrict__ g,
                     const float* __restrict__ lnw, const float* __restrict__ lnb,
                     float* __restrict__ z){
    int gw = (blockIdx.x*256 + threadIdx.x) >> 6;
    int lane = threadIdx.x & 63;
    if (gw >= CB*CT*CH) return;
    int h = gw % CH; int bt = gw / CH;
    int b = bt / CT, t = bt % CT;
    int bh = b*CH + h;
    float yv = y[((size_t)bh*CT + t)*64 + lane];
    float s1 = yv, s2 = yv*yv;
    #pragma unroll
    for (int off = 32; off; off >>= 1){ s1 += __shfl_xor(s1, off); s2 += __shfl_xor(s2, off); }
    float mu = s1 * (1.f/64.f);
    float var = s2 * (1.f/64.f) - mu*mu;
    float inv = rsqrtf(var + 6.4e-4f);
    int d = h*64 + lane;
    float yn = (yv - mu)*inv*lnw[d] + lnb[d];
    z[(size_t)bt*CD + d] = yn * g[(size_t)bt*CD + d];
}

extern "C" void kernel_launch(void* const* d_in, const int* in_sizes, int n_in,
                              void* d_out, int out_size, void* d_ws, size_t ws_size,
                              hipStream_t stream){
    const float* x          = (const float*)d_in[0];
    const float* tmx        = (const float*)d_in[1];
    const float* tmw        = (const float*)d_in[2];
    const float* tmk        = (const float*)d_in[3];
    const float* tmv        = (const float*)d_in[4];
    const float* tmr        = (const float*)d_in[5];
    const float* tmg        = (const float*)d_in[6];
    const float* maa_w1     = (const float*)d_in[7];
    const float* maa_w2     = (const float*)d_in[8];
    const float* time_decay = (const float*)d_in[9];
    const float* decay_w1   = (const float*)d_in[10];
    const float* decay_w2   = (const float*)d_in[11];
    const float* lucid_temp = (const float*)d_in[12];
    const float* Wr         = (const float*)d_in[13];
    const float* Wk         = (const float*)d_in[14];
    const float* Wv         = (const float*)d_in[15];
    const float* Wg         = (const float*)d_in[16];
    const float* Wo         = (const float*)d_in[17];
    const float* lnw        = (const float*)d_in[18];
    const float* lnb        = (const float*)d_in[19];
    float* out = (float*)d_out;
    float* ws  = (float*)d_ws;

    const size_t S = (size_t)CB*CT*CD;
    float* b0 = ws;          // dxprev -> wbuf -> Yb -> Sb
    float* b1 = ws + 1*S;    // xxx -> xw -> rf
    float* b2 = ws + 2*S;    // xk -> kf
    float* b3 = ws + 3*S;    // xv -> rb
    float* b4 = ws + 4*S;    // xr -> kn -> Sf
    float* b5 = ws + 5*S;    // xg -> X (v -> Pv)
    float* b6 = ws + 6*S;    // rbuf -> y
    float* b7 = ws + 7*S;    // kbuf -> z
    float* b8 = ws + 8*S;    // vbuf -> kb
    float* b9 = ws + 9*S;    // gbuf
    float* mbuf = ws + 10*S;
    const size_t MB_F = 4096*160;
    size_t base_f = 10*S + MB_F;

    const size_t per_bh = (size_t)CT*CT + 16*NB*NB;
    size_t avail = ws_size / sizeof(float);
    int G = 1;
    if (avail > base_f + per_bh){
        size_t g = (avail - base_f) / per_bh;
        G = (g >= CBH) ? CBH : (int)g;
        if (G < 1) G = 1;
    }
    float* P    = ws + base_f;
    float* invL = P + (size_t)G*CT*CT;

    // weight split scratch lives in the P region (dead until k_gram)
    unsigned short* BtHi = (unsigned short*)P;
    unsigned short* BtLo = BtHi + (size_t)CD*CD;

    float* dxprev = b0; float* xxx = b1;
    float* xw = b1; float* xk = b2; float* xv = b3; float* xr = b4; float* xg = b5;
    float* rbuf = b6; float* kbuf = b7; float* vbuf = b8; float* gbuf = b9; float* wbuf = b0;
    float* kn = b4; float* X = b5;
    float* rf = b1; float* kf = b2; float* rb = b3; float* kb = b8;
    float* Yb = b0;
    float* Sf = b4; float* Sb = b0;
    float* ybuf = b6; float* zbuf = b7;

    dim3 mg(CD/64, (CB*CT)/64);
    dim3 tg(CD/64, CD/64);

    k_shift<<<dim3((CB*CT*CD + 255)/256), 256, 0, stream>>>(x, tmx, dxprev, xxx);
    k_gemm<1><<<dim3(3, 32), 256, 0, stream>>>(xxx, maa_w1, nullptr, mbuf, 4096, 160, 768);
    k_mix5<<<dim3(3, 4096), 256, 0, stream>>>(x, dxprev, mbuf, tmw, tmk, tmv, tmr, tmg,
                                              maa_w2, xw, xk, xv, xr, xg);
    k_splitT<<<tg, 256, 0, stream>>>(Wr, BtHi, BtLo, CD, CD);
    k_mgemm<0><<<mg, 256, 0, stream>>>(xr, BtHi, BtLo, nullptr, rbuf, 4096, CD, CD);
    k_splitT<<<tg, 256, 0, stream>>>(Wk, BtHi, BtLo, CD, CD);
    k_mgemm<0><<<mg, 256, 0, stream>>>(xk, BtHi, BtLo, nullptr, kbuf, 4096, CD, CD);
    k_splitT<<<tg, 256, 0, stream>>>(Wv, BtHi, BtLo, CD, CD);
    k_mgemm<0><<<mg, 256, 0, stream>>>(xv, BtHi, BtLo, nullptr, vbuf, 4096, CD, CD);
    k_splitT<<<tg, 256, 0, stream>>>(Wg, BtHi, BtLo, CD, CD);
    k_mgemm<2><<<mg, 256, 0, stream>>>(xg, BtHi, BtLo, nullptr, gbuf, 4096, CD, CD);
    // decay: mbuf = tanh(xw @ decay_w1); wbuf = mbuf @ decay_w2 + time_decay
    k_splitT<<<dim3(1, 12), 256, 0, stream>>>(decay_w1, BtHi, BtLo, CD, 64);
    k_mgemm<1><<<dim3(1, 64), 256, 0, stream>>>(xw, BtHi, BtLo, nullptr, mbuf, 4096, 64, CD);
    k_splitT<<<dim3(12, 1), 256, 0, stream>>>(decay_w2, BtHi, BtLo, 64, CD);
    k_mgemm<3><<<dim3(12, 64), 256, 0, stream>>>(mbuf, BtHi, BtLo, time_decay, wbuf, 4096, CD, 64);

    k_knvx<<<dim3((CB*CH*CT*64)/256), 256, 0, stream>>>(kbuf, vbuf, kn, X);
    k_scan2<<<dim3(CBH), 256, 0, stream>>>(rbuf, kbuf, wbuf, rf, kf, rb, kb);

    for (int bh0 = 0; bh0 < CBH; bh0 += G){
        int Gc = (CBH - bh0 < G) ? (CBH - bh0) : G;
        k_gram<<<dim3(16, 16, Gc), 256, 0, stream>>>(kn, lucid_temp, P, bh0);
        k_potrf0<<<dim3(Gc), 256, 0, stream>>>(P, invL);
        for (int jb = 0; jb < 15; jb++){
            int nt = 15 - jb;
            k_trsm<<<dim3(nt, Gc), 256, 0, stream>>>(P, invL, jb);
            k_syrkf<<<dim3(nt+1, nt, Gc), 256, 0, stream>>>(P, invL, X, Yb, bh0, jb);
        }
        k_solve<0><<<dim3(1, Gc), 256, 0, stream>>>(P, invL, X, Yb, bh0, 15);  // fwd tail (diag 15)
        for (int jb = 15; jb >= 0; jb--)
            k_solve<1><<<dim3(jb+1, Gc), 256, 0, stream>>>(P, invL, X, Yb, bh0, jb);
    }

    k_outer<<<dim3(16, CBH), 256, 0, stream>>>(kf, kb, X, Sf, Sb);
    k_cumsum<<<dim3(CBH), 256, 0, stream>>>(Sf, Sb);
    k_apv2<<<dim3(16, CBH), 256, 0, stream>>>(rf, kf, rb, kb, X, Sf, Sb, ybuf);
    k_gn<<<dim3((CB*CT*CH*64)/256), 256, 0, stream>>>(ybuf, gbuf, lnw, lnb, zbuf);
    k_splitT<<<tg, 256, 0, stream>>>(Wo, BtHi, BtLo, CD, CD);
    k_mgemm<0><<<mg, 256, 0, stream>>>(zbuf, BtHi, BtLo, nullptr, out, 4096, CD, CD);
}

// Round 12
// 4804.338 us; speedup vs baseline: 1.0007x; 1.0007x over previous
//
#include <hip/hip_runtime.h>
#include <math.h>

#define CB 4
#define CT 1024
#define CD 768
#define CH 12
#define CK 64
#define CBH (CB*CH)
#define NB 64

typedef __attribute__((ext_vector_type(8))) short sh8;
typedef __attribute__((ext_vector_type(8))) unsigned short ush8;
typedef __attribute__((ext_vector_type(4))) unsigned short ush4;
typedef __attribute__((ext_vector_type(4))) float fl4;

__device__ __forceinline__ unsigned short f2bf(float f){
    unsigned u = __builtin_bit_cast(unsigned, f);
    unsigned r = (u + 0x7fff + ((u >> 16) & 1)) >> 16;
    return (unsigned short)r;
}
__device__ __forceinline__ float bf2f(unsigned short u){
    return __builtin_bit_cast(float, (unsigned)u << 16);
}
#define MFMA3(acc, ah, al, bh_, bl_) { \
    acc = __builtin_amdgcn_mfma_f32_16x16x32_bf16(al, bh_, acc, 0, 0, 0); \
    acc = __builtin_amdgcn_mfma_f32_16x16x32_bf16(ah, bl_, acc, 0, 0, 0); \
    acc = __builtin_amdgcn_mfma_f32_16x16x32_bf16(ah, bh_, acc, 0, 0, 0); }

// cooperative 64x64 tile load: global (row-major, given stride) -> LDS [64][65]
#define LOAD_TILE(dst, src, stride) { \
    _Pragma("unroll") \
    for (int i_ = 0; i_ < 4; i_++){ \
        int rr_ = (tid>>4) + i_*16, cc_ = (tid&15)*4; \
        float4 v_ = *(const float4*)((src) + (size_t)rr_*(stride) + cc_); \
        dst[rr_][cc_+0]=v_.x; dst[rr_][cc_+1]=v_.y; dst[rr_][cc_+2]=v_.z; dst[rr_][cc_+3]=v_.w; \
    } }

// ---------------- elementwise: token shift + xxx ----------------
__global__ void k_shift(const float* __restrict__ x, const float* __restrict__ tmx,
                        float* __restrict__ dxprev, float* __restrict__ xxx){
    int idx = blockIdx.x*256 + threadIdx.x;
    if (idx >= CB*CT*CD) return;
    int d = idx % CD;
    int bt = idx / CD;
    int t = bt % CT;
    float xc = x[idx];
    float xl = (t > 0)      ? x[idx - CD] : 0.f;
    float xr = (t < CT-1)   ? x[idx + CD] : 0.f;
    float dx = 0.5f*(xl + xr) - xc;
    dxprev[idx] = dx;
    xxx[idx] = xc + dx * tmx[d];
}

// ---------------- generic tiled fp32 GEMM (maa_w1 only) ----------------
template<int MODE>
__global__ void k_gemm(const float* __restrict__ A, const float* __restrict__ Bm,
                       const float* __restrict__ bias, float* __restrict__ C,
                       int M, int N, int Kd){
    __shared__ float As[16][128];
    __shared__ float Bs[16][64];
    int tid = threadIdx.x;
    int m0 = blockIdx.y * 128, n0 = blockIdx.x * 64;
    int tn = (tid & 15) * 4;
    int tm = (tid >> 4) * 8;
    float acc[8][4] = {};
    for (int k0 = 0; k0 < Kd; k0 += 16){
        #pragma unroll
        for (int i = 0; i < 8; i++){
            int e = tid + i*256;
            int r = e >> 4, c = e & 15;
            As[c][r] = A[(size_t)(m0+r)*Kd + k0 + c];
        }
        #pragma unroll
        for (int i = 0; i < 4; i++){
            int e = tid + i*256;
            int r = e >> 6, c = e & 63;
            float bv = 0.f;
            if (n0 + c < N) bv = Bm[(size_t)(k0+r)*N + n0 + c];
            Bs[r][c] = bv;
        }
        __syncthreads();
        #pragma unroll
        for (int kk = 0; kk < 16; kk++){
            float a0[8], b0[4];
            #pragma unroll
            for (int i = 0; i < 8; i++) a0[i] = As[kk][tm+i];
            #pragma unroll
            for (int j = 0; j < 4; j++) b0[j] = Bs[kk][tn+j];
            #pragma unroll
            for (int i = 0; i < 8; i++)
                #pragma unroll
                for (int j = 0; j < 4; j++) acc[i][j] += a0[i]*b0[j];
        }
        __syncthreads();
    }
    #pragma unroll
    for (int i = 0; i < 8; i++)
        #pragma unroll
        for (int j = 0; j < 4; j++){
            int mm = m0 + tm + i, nn = n0 + tn + j;
            if (nn < N){
                float v = acc[i][j];
                if (MODE == 1) v = tanhf(v);
                else if (MODE == 2) v = v / (1.f + expf(-v));
                else if (MODE == 3) v += bias[nn];
                C[(size_t)mm*N + nn] = v;
            }
        }
}

// ---------------- weight transpose + split: B[K][N] -> Bt{Hi,Lo}[N][K] ----------------
__global__ void k_splitT(const float* __restrict__ B, unsigned short* __restrict__ hi,
                         unsigned short* __restrict__ lo, int Kd, int N){
    __shared__ float ts[64][65];
    int tid = threadIdx.x;
    int n0 = blockIdx.x*64, k0 = blockIdx.y*64;
    #pragma unroll
    for (int i = 0; i < 4; i++){
        int rr = (tid>>4) + i*16, cc = (tid&15)*4;
        float4 v = *(const float4*)(B + (size_t)(k0+rr)*N + n0 + cc);
        ts[rr][cc+0]=v.x; ts[rr][cc+1]=v.y; ts[rr][cc+2]=v.z; ts[rr][cc+3]=v.w;
    }
    __syncthreads();
    #pragma unroll
    for (int i = 0; i < 4; i++){
        int nl = (tid>>4) + i*16, k4 = (tid&15)*4;
        ush4 vh, vl;
        #pragma unroll
        for (int j = 0; j < 4; j++){
            float f = ts[k4+j][nl];
            unsigned short h = f2bf(f);
            vh[j] = h;
            vl[j] = f2bf(f - bf2f(h));
        }
        size_t o = (size_t)(n0+nl)*Kd + k0 + k4;
        *reinterpret_cast<ush4*>(hi + o) = vh;
        *reinterpret_cast<ush4*>(lo + o) = vl;
    }
}

// ---------------- MFMA split-bf16 GEMM: C[M,N] = A[M,K] @ Bt[N,K]^T ----------------
// MODE 0 plain, 1 tanh, 2 silu, 3 +bias[n]
template<int MODE>
__global__ __launch_bounds__(256) void k_mgemm(const float* __restrict__ A,
        const unsigned short* __restrict__ BtHi, const unsigned short* __restrict__ BtLo,
        const float* __restrict__ bias, float* __restrict__ C, int M, int N, int Kd){
    __shared__ unsigned short AHI[2048], ALO[2048], BHI[2048], BLO[2048];
    int tid = threadIdx.x;
    int n0 = blockIdx.x*64, m0 = blockIdx.y*64;
    int w = tid >> 6, lane = tid & 63;
    int wm = w >> 1, wn = w & 1;
    fl4 acc[2][2];
    #pragma unroll
    for (int mi = 0; mi < 2; mi++)
        #pragma unroll
        for (int ni = 0; ni < 2; ni++) acc[mi][ni] = (fl4){0.f, 0.f, 0.f, 0.f};
    int sm = tid >> 2;
    int sk = (tid & 3) * 8;
    int slane = (sm & 15) + ((tid & 3) << 4);
    int sidx = (((sm >> 4)*64) + slane) * 8;
    const int nsteps = Kd >> 5;
    for (int ks = 0; ks < nsteps; ks++){
        int k0 = ks << 5;
        __syncthreads();
        {
            const float* ap = A + (size_t)(m0+sm)*Kd + k0 + sk;
            float4 a0 = *(const float4*)ap, a1 = *(const float4*)(ap+4);
            float av[8] = {a0.x,a0.y,a0.z,a0.w,a1.x,a1.y,a1.z,a1.w};
            ush8 vh, vl;
            #pragma unroll
            for (int i = 0; i < 8; i++){
                unsigned short h = f2bf(av[i]);
                vh[i] = h;
                vl[i] = f2bf(av[i] - bf2f(h));
            }
            *reinterpret_cast<ush8*>(&AHI[sidx]) = vh;
            *reinterpret_cast<ush8*>(&ALO[sidx]) = vl;
            size_t bo = (size_t)(n0+sm)*Kd + k0 + sk;
            *reinterpret_cast<ush8*>(&BHI[sidx]) = *reinterpret_cast<const ush8*>(BtHi + bo);
            *reinterpret_cast<ush8*>(&BLO[sidx]) = *reinterpret_cast<const ush8*>(BtLo + bo);
        }
        __syncthreads();
        sh8 ah[2], al[2], bh[2], bl[2];
        #pragma unroll
        for (int mi = 0; mi < 2; mi++){
            int gm = wm*2 + mi;
            ah[mi] = *reinterpret_cast<sh8*>(&AHI[(gm*64 + lane)*8]);
            al[mi] = *reinterpret_cast<sh8*>(&ALO[(gm*64 + lane)*8]);
        }
        #pragma unroll
        for (int ni = 0; ni < 2; ni++){
            int gn = wn*2 + ni;
            bh[ni] = *reinterpret_cast<sh8*>(&BHI[(gn*64 + lane)*8]);
            bl[ni] = *reinterpret_cast<sh8*>(&BLO[(gn*64 + lane)*8]);
        }
        #pragma unroll
        for (int mi = 0; mi < 2; mi++)
            #pragma unroll
            for (int ni = 0; ni < 2; ni++)
                MFMA3(acc[mi][ni], ah[mi], al[mi], bh[ni], bl[ni]);
    }
    #pragma unroll
    for (int mi = 0; mi < 2; mi++)
        #pragma unroll
        for (int ni = 0; ni < 2; ni++){
            int cc = n0 + wn*32 + ni*16 + (lane & 15);
            int rb = m0 + wm*32 + mi*16 + ((lane >> 4) << 2);
            #pragma unroll
            for (int j = 0; j < 4; j++){
                float v = acc[mi][ni][j];
                if (MODE == 1) v = tanhf(v);
                else if (MODE == 2) v = v / (1.f + expf(-v));
                else if (MODE == 3) v += bias[cc];
                C[(size_t)(rb+j)*N + cc] = v;
            }
        }
}

// ---------------- 5-way low-rank mix ----------------
__global__ void k_mix5(const float* __restrict__ x, const float* __restrict__ dxprev,
                       const float* __restrict__ m,
                       const float* __restrict__ tmw, const float* __restrict__ tmk,
                       const float* __restrict__ tmv, const float* __restrict__ tmr,
                       const float* __restrict__ tmg, const float* __restrict__ w2,
                       float* __restrict__ xw, float* __restrict__ xk, float* __restrict__ xv,
                       float* __restrict__ xr, float* __restrict__ xg){
    __shared__ float ms[160];
    int i = blockIdx.y;
    int j = blockIdx.x*256 + threadIdx.x;
    if (threadIdx.x < 160) ms[threadIdx.x] = m[(size_t)i*160 + threadIdx.x];
    __syncthreads();
    float xc = x[(size_t)i*CD + j], dx = dxprev[(size_t)i*CD + j];
    const float* tms[5] = {tmw, tmk, tmv, tmr, tmg};
    float* outs[5] = {xw, xk, xv, xr, xg};
    #pragma unroll
    for (int c = 0; c < 5; c++){
        float s = tms[c][j];
        const float* w2c = w2 + (size_t)c*32*CD + j;
        #pragma unroll
        for (int dm = 0; dm < 32; dm++) s += ms[c*32+dm] * w2c[(size_t)dm*CD];
        outs[c][(size_t)i*CD + j] = xc + dx*s;
    }
}

// ---------------- normalize k, stage v into X (head layout) ----------------
__global__ void k_knvx(const float* __restrict__ k, const float* __restrict__ v,
                       float* __restrict__ kn, float* __restrict__ X){
    int gw = (blockIdx.x*256 + threadIdx.x) >> 6;
    int lane = threadIdx.x & 63;
    if (gw >= CB*CH*CT) return;
    int t = gw % CT; int bh = gw / CT; int h = bh % CH; int b = bh / CH;
    size_t src = ((size_t)(b*CT + t))*CD + h*64 + lane;
    float kv = k[src];
    float ss = kv*kv;
    #pragma unroll
    for (int off = 32; off; off >>= 1) ss += __shfl_xor(ss, off);
    float nrm = fmaxf(sqrtf(ss), 1e-12f);
    size_t dst = ((size_t)bh*CT + t)*64 + lane;
    kn[dst] = kv / nrm;
    X[dst]  = v[src];
}

// ---------------- decay scan, fully coalesced ----------------
__global__ __launch_bounds__(256) void k_scan2(const float* __restrict__ r, const float* __restrict__ k,
                        const float* __restrict__ w,
                        float* __restrict__ rf, float* __restrict__ kf,
                        float* __restrict__ rb, float* __restrict__ kb){
    __shared__ float parts[16][4][64];
    __shared__ float carr[16][64];
    __shared__ float refs[2][64];
    int bh = blockIdx.x; int h = bh % CH; int b = bh / CH;
    int tid = threadIdx.x; int wid = tid >> 6; int ch = tid & 63;
    const float* wb = w + (size_t)b*CT*CD + h*64;
    for (int tc = 0; tc < 16; tc++){
        float sum = 0.f;
        int tb = tc*64 + wid*16;
        for (int s = 0; s < 16; s++)
            sum -= expf(wb[(size_t)(tb+s)*CD + ch]);
        parts[tc][wid][ch] = sum;
    }
    __syncthreads();
    if (tid < 64){
        float run = 0.f;
        for (int tc = 0; tc < 16; tc++){
            carr[tc][tid] = run;
            run += parts[tc][0][tid] + parts[tc][1][tid] + parts[tc][2][tid] + parts[tc][3][tid];
        }
        float wv512 = -expf(wb[(size_t)512*CD + tid]);
        refs[0][tid] = carr[8][tid] + wv512;
        refs[1][tid] = carr[8][tid];
    }
    __syncthreads();
    const float* rbp = r + (size_t)b*CT*CD + h*64;
    const float* kbp = k + (size_t)b*CT*CD + h*64;
    size_t ob = (size_t)bh*CT*64;
    float ref_f = refs[0][ch], ref_b = refs[1][ch];
    for (int tc = 0; tc < 16; tc++){
        float run = carr[tc][ch];
        if (wid > 0) run += parts[tc][0][ch];
        if (wid > 1) run += parts[tc][1][ch];
        if (wid > 2) run += parts[tc][2][ch];
        int tb = tc*64 + wid*16;
        for (int s = 0; s < 16; s++){
            int t = tb + s;
            float wv = -expf(wb[(size_t)t*CD + ch]);
            run += wv;
            float csf = fminf(fmaxf(run - ref_f, -60.f), 60.f);
            float csb = fminf(fmaxf((run - wv) - ref_b, -60.f), 60.f);
            float rv = rbp[(size_t)t*CD + ch], kv = kbp[(size_t)t*CD + ch];
            rf[ob + (size_t)t*64 + ch] = rv * expf(csf);
            kf[ob + (size_t)t*64 + ch] = kv * expf(-csf);
            rb[ob + (size_t)t*64 + ch] = rv * expf(-csb);
            kb[ob + (size_t)t*64 + ch] = kv * expf(csb);
        }
    }
}

// ---------------- P(lower) = I + exp(clip(temp * kn knT)) ----------------
__global__ void k_gram(const float* __restrict__ kn, const float* __restrict__ lucid_temp,
                       float* __restrict__ P, int bh0){
    int t0 = blockIdx.y*64, s0 = blockIdx.x*64;
    if (t0 < s0) return;
    __shared__ float tA[64][65];
    __shared__ float tB[64][65];
    int lbh = blockIdx.z; int gbh = bh0 + lbh; int h = gbh % CH;
    int tid = threadIdx.x;
    LOAD_TILE(tA, kn + ((size_t)gbh*CT + t0)*64, 64);
    LOAD_TILE(tB, kn + ((size_t)gbh*CT + s0)*64, 64);
    __syncthreads();
    float tv = lucid_temp[h];
    tv = (tv > 20.f) ? tv : log1pf(expf(tv));
    int ty = (tid >> 4)*4, tx = (tid & 15)*4;
    float acc[4][4] = {};
    #pragma unroll
    for (int kk = 0; kk < 64; kk++){
        float a0[4], b0[4];
        #pragma unroll
        for (int i = 0; i < 4; i++){ a0[i] = tA[ty+i][kk]; b0[i] = tB[tx+i][kk]; }
        #pragma unroll
        for (int i = 0; i < 4; i++)
            #pragma unroll
            for (int j = 0; j < 4; j++) acc[i][j] += a0[i]*b0[j];
    }
    size_t pbase = (size_t)lbh*CT*CT;
    #pragma unroll
    for (int i = 0; i < 4; i++){
        int tt = t0+ty+i;
        float4 v;
        float g0 = fminf(fmaxf(tv*acc[i][0], -20.f), 20.f);
        float g1 = fminf(fmaxf(tv*acc[i][1], -20.f), 20.f);
        float g2 = fminf(fmaxf(tv*acc[i][2], -20.f), 20.f);
        float g3 = fminf(fmaxf(tv*acc[i][3], -20.f), 20.f);
        v.x = expf(g0) + ((tt == s0+tx+0) ? 1.f : 0.f);
        v.y = expf(g1) + ((tt == s0+tx+1) ? 1.f : 0.f);
        v.z = expf(g2) + ((tt == s0+tx+2) ? 1.f : 0.f);
        v.w = expf(g3) + ((tt == s0+tx+3) ? 1.f : 0.f);
        *(float4*)(P + pbase + (size_t)tt*CT + s0 + tx) = v;
    }
}

// ---------------- in-LDS 64x64 Cholesky + triangular inverse ----------------
__device__ __forceinline__ void potrf_inv(float (&s)[64][65], float (&inv)[64][65], int tid){
    for (int j = 0; j < 63; j++){
        __syncthreads();
        float invd = 1.f / fmaxf(s[j][j], 1e-20f);
        int n = 63 - j;
        for (int e = tid; e < n*n; e += 256){
            int ii = j+1 + e / n, cc = j+1 + e % n;
            s[ii][cc] -= s[ii][j]*s[cc][j]*invd;
        }
    }
    __syncthreads();
    for (int e = tid; e < 64*64; e += 256){
        int i2 = e >> 6, j2 = e & 63;
        if (i2 > j2) s[i2][j2] *= rsqrtf(fmaxf(s[j2][j2], 1e-20f));
    }
    __syncthreads();
    if (tid < 64) s[tid][tid] = sqrtf(fmaxf(s[tid][tid], 1e-20f));
    __syncthreads();
    if (tid < 64){
        int c = tid;
        for (int j = 0; j < c; j++) inv[j][c] = 0.f;
        for (int j = c; j < 64; j++){
            float sum = (j == c) ? 1.f : 0.f;
            for (int kk = c; kk < j; kk++) sum -= s[j][kk]*inv[kk][c];
            inv[j][c] = sum / s[j][j];
        }
    }
    __syncthreads();
}

__device__ __forceinline__ void potrf_writeout(float (&s)[64][65], float (&inv)[64][65], int tid,
                                               float* __restrict__ Pd, float* __restrict__ invp){
    for (int e = tid; e < 4096; e += 256){
        int r2 = e >> 6, c2 = e & 63;
        if (c2 <= r2) Pd[(size_t)r2*CT + c2] = s[r2][c2];
    }
    #pragma unroll
    for (int i_ = 0; i_ < 4; i_++){
        int rr_ = (tid>>4) + i_*16, cc_ = (tid&15)*4;
        float4 v_ = make_float4(inv[rr_][cc_], inv[rr_][cc_+1], inv[rr_][cc_+2], inv[rr_][cc_+3]);
        *(float4*)(invp + rr_*64 + cc_) = v_;
    }
}

__global__ void k_potrf0(float* __restrict__ P, float* __restrict__ invL){
    __shared__ float s[64][65], inv[64][65];
    int bh = blockIdx.x; int tid = threadIdx.x;
    size_t base = (size_t)bh*CT*CT;
    LOAD_TILE(s, P + base, CT);
    __syncthreads();
    potrf_inv(s, inv, tid);
    potrf_writeout(s, inv, tid, P + base, invL + (size_t)bh*16*4096);
}

// ---------------- TRSM: panel = A21 @ invL11^T ----------------
__global__ void k_trsm(float* __restrict__ P, const float* __restrict__ invL, int jb){
    __shared__ float a[64][65];
    __shared__ float iv[64][65];
    int bh = blockIdx.y;
    int r0 = (jb+1)*NB + blockIdx.x*64;
    int j0 = jb*NB;
    size_t base = (size_t)bh*CT*CT;
    int tid = threadIdx.x;
    const float* invp = invL + ((size_t)bh*16 + jb)*4096;
    LOAD_TILE(a, P + base + (size_t)r0*CT + j0, CT);
    LOAD_TILE(iv, invp, 64);
    __syncthreads();
    int ty = (tid >> 4)*4, tx = (tid & 15)*4;
    float acc[4][4] = {};
    #pragma unroll
    for (int kk = 0; kk < 64; kk++){
        float a0[4], b0[4];
        #pragma unroll
        for (int i = 0; i < 4; i++){ a0[i] = a[ty+i][kk]; b0[i] = iv[tx+i][kk]; }
        #pragma unroll
        for (int i = 0; i < 4; i++)
            #pragma unroll
            for (int j = 0; j < 4; j++) acc[i][j] += a0[i]*b0[j];
    }
    #pragma unroll
    for (int i = 0; i < 4; i++)
        *(float4*)(P + base + (size_t)(r0+ty+i)*CT + j0 + tx) =
            make_float4(acc[i][0], acc[i][1], acc[i][2], acc[i][3]);
}

// ---------------- fused SYRK + inline next-potrf + forward-solve column ----------------
// grid (nt+1, nt, Gc): tj<=ti -> syrk tile; tj==nt -> fwd solve for ib=jb+1+ti
__global__ void k_syrkf(float* __restrict__ P, float* __restrict__ invL,
                        float* __restrict__ X, float* __restrict__ Yb, int bh0, int jb){
    __shared__ float sA[64][65], sB[64][65], sC[64][65];
    int tj = blockIdx.x, ti = blockIdx.y, lbh = blockIdx.z;
    int tid = threadIdx.x;
    int ty = (tid >> 4)*4, tx = (tid & 15)*4;
    size_t base = (size_t)lbh*CT*CT;
    if (tj == gridDim.x - 1){
        // forward-solve role: Y = invL[jb] @ X[jb]; X[ib] -= L[ib][jb] @ Y
        int ib = jb + 1 + ti;
        const float* invp = invL + ((size_t)lbh*16 + jb)*4096;
        const float* Xj = X + ((size_t)(bh0+lbh)*CT + jb*64)*64;
        LOAD_TILE(sA, invp, 64);
        LOAD_TILE(sB, Xj, 64);
        __syncthreads();
        float c4[4][4] = {};
        #pragma unroll
        for (int kk = 0; kk < 64; kk++){
            float a0[4], b0[4];
            #pragma unroll
            for (int i = 0; i < 4; i++){ a0[i] = sA[ty+i][kk]; b0[i] = sB[kk][tx+i]; }
            #pragma unroll
            for (int i = 0; i < 4; i++)
                #pragma unroll
                for (int j = 0; j < 4; j++) c4[i][j] += a0[i]*b0[j];
        }
        if (ti == 0){
            float* yd = Yb + ((size_t)(bh0+lbh)*CT + jb*64)*64;
            #pragma unroll
            for (int i = 0; i < 4; i++)
                *(float4*)(yd + (size_t)(ty+i)*64 + tx) =
                    make_float4(c4[i][0], c4[i][1], c4[i][2], c4[i][3]);
        }
        #pragma unroll
        for (int i = 0; i < 4; i++)
            #pragma unroll
            for (int j = 0; j < 4; j++) sC[ty+i][tx+j] = c4[i][j];
        __syncthreads();
        LOAD_TILE(sA, P + base + (size_t)(ib*64)*CT + jb*64, CT);
        __syncthreads();
        float u4[4][4] = {};
        #pragma unroll
        for (int kk = 0; kk < 64; kk++){
            float a0[4], b0[4];
            #pragma unroll
            for (int i = 0; i < 4; i++){ a0[i] = sA[ty+i][kk]; b0[i] = sC[kk][tx+i]; }
            #pragma unroll
            for (int i = 0; i < 4; i++)
                #pragma unroll
                for (int j = 0; j < 4; j++) u4[i][j] += a0[i]*b0[j];
        }
        float* dst = X + ((size_t)(bh0+lbh)*CT + ib*64)*64;
        #pragma unroll
        for (int i = 0; i < 4; i++){
            float4* p4 = (float4*)(dst + (size_t)(ty+i)*64 + tx);
            float4 v = *p4;
            v.x -= u4[i][0]; v.y -= u4[i][1]; v.z -= u4[i][2]; v.w -= u4[i][3];
            *p4 = v;
        }
        return;
    }
    if (tj > ti) return;
    // SYRK role
    int off = (jb+1)*NB;
    int r0 = off + ti*64, c0 = off + tj*64, j0 = jb*NB;
    LOAD_TILE(sA, P + base + (size_t)r0*CT + j0, CT);
    LOAD_TILE(sB, P + base + (size_t)c0*CT + j0, CT);
    __syncthreads();
    float acc[4][4] = {};
    #pragma unroll
    for (int kk = 0; kk < 64; kk++){
        float a0[4], b0[4];
        #pragma unroll
        for (int i = 0; i < 4; i++){ a0[i] = sA[ty+i][kk]; b0[i] = sB[tx+i][kk]; }
        #pragma unroll
        for (int i = 0; i < 4; i++)
            #pragma unroll
            for (int j = 0; j < 4; j++) acc[i][j] += a0[i]*b0[j];
    }
    if (!(ti == 0 && tj == 0)){
        #pragma unroll
        for (int i = 0; i < 4; i++){
            float4* p4 = (float4*)(P + base + (size_t)(r0+ty+i)*CT + c0 + tx);
            float4 v = *p4;
            v.x -= acc[i][0]; v.y -= acc[i][1]; v.z -= acc[i][2]; v.w -= acc[i][3];
            *p4 = v;
        }
    } else {
        __syncthreads();
        #pragma unroll
        for (int i = 0; i < 4; i++){
            float4 v = *(const float4*)(P + base + (size_t)(r0+ty+i)*CT + c0 + tx);
            sA[ty+i][tx+0] = v.x - acc[i][0];
            sA[ty+i][tx+1] = v.y - acc[i][1];
            sA[ty+i][tx+2] = v.z - acc[i][2];
            sA[ty+i][tx+3] = v.w - acc[i][3];
        }
        __syncthreads();
        potrf_inv(sA, sB, tid);
        potrf_writeout(sA, sB, tid, P + base + (size_t)off*CT + off,
                       invL + ((size_t)lbh*16 + jb+1)*4096);
    }
}

// ---------------- fused block substitution (fwd tail + backward sweep) ----------------
template<int TRANS>
__global__ void k_solve(const float* __restrict__ P, const float* __restrict__ invL,
                        float* __restrict__ Xc, float* __restrict__ Yb, int bh0, int jb){
    __shared__ float A[64][65], B[64][65], C[64][65];
    int bh = blockIdx.y, tid = threadIdx.x;
    int ib = TRANS ? blockIdx.x : (jb + blockIdx.x);
    const float* invp = invL + ((size_t)bh*16 + jb)*4096;
    const float* src = (TRANS ? Yb : Xc) + ((size_t)(bh0+bh)*CT + jb*64)*64;
    LOAD_TILE(A, invp, 64);
    LOAD_TILE(B, src, 64);
    __syncthreads();
    int ty = (tid >> 4)*4, tx = (tid & 15)*4;
    float c4[4][4] = {};
    #pragma unroll
    for (int kk = 0; kk < 64; kk++){
        float a0[4], b0[4];
        #pragma unroll
        for (int i = 0; i < 4; i++){
            a0[i] = TRANS ? A[kk][ty+i] : A[ty+i][kk];
            b0[i] = B[kk][tx+i];
        }
        #pragma unroll
        for (int i = 0; i < 4; i++)
            #pragma unroll
            for (int j = 0; j < 4; j++) c4[i][j] += a0[i]*b0[j];
    }
    if (ib == jb){
        float* dst = (TRANS ? Xc : Yb) + ((size_t)(bh0+bh)*CT + jb*64)*64;
        #pragma unroll
        for (int i = 0; i < 4; i++)
            *(float4*)(dst + (size_t)(ty+i)*64 + tx) =
                make_float4(c4[i][0], c4[i][1], c4[i][2], c4[i][3]);
        return;
    }
    #pragma unroll
    for (int i = 0; i < 4; i++)
        #pragma unroll
        for (int j = 0; j < 4; j++) C[ty+i][tx+j] = c4[i][j];
    __syncthreads();
    const float* Lp = P + (size_t)bh*CT*CT + (TRANS ? ((size_t)(jb*64)*CT + ib*64)
                                                    : ((size_t)(ib*64)*CT + jb*64));
    LOAD_TILE(A, Lp, CT);
    __syncthreads();
    float u4[4][4] = {};
    #pragma unroll
    for (int kk = 0; kk < 64; kk++){
        float a0[4], b0[4];
        #pragma unroll
        for (int i = 0; i < 4; i++){
            a0[i] = TRANS ? A[kk][ty+i] : A[ty+i][kk];
            b0[i] = C[kk][tx+i];
        }
        #pragma unroll
        for (int i = 0; i < 4; i++)
            #pragma unroll
            for (int j = 0; j < 4; j++) u4[i][j] += a0[i]*b0[j];
    }
    float* dst = (TRANS ? Yb : Xc) + ((size_t)(bh0+bh)*CT + ib*64)*64;
    #pragma unroll
    for (int i = 0; i < 4; i++){
        float4* p4 = (float4*)(dst + (size_t)(ty+i)*64 + tx);
        float4 v = *p4;
        v.x -= u4[i][0]; v.y -= u4[i][1]; v.z -= u4[i][2]; v.w -= u4[i][3];
        *p4 = v;
    }
}

// ---------------- per-chunk outer products ----------------
__global__ void k_outer(const float* __restrict__ kf, const float* __restrict__ kb,
                        const float* __restrict__ X,
                        float* __restrict__ Sf, float* __restrict__ Sb){
    __shared__ float kfs[64][65], kbs[64][65], pvs[64][65];
    int c = blockIdx.x, bh = blockIdx.y, tid = threadIdx.x;
    size_t hb = (size_t)bh*CT*64 + (size_t)c*64*64;
    LOAD_TILE(kfs, kf + hb, 64);
    LOAD_TILE(kbs, kb + hb, 64);
    LOAD_TILE(pvs, X + hb, 64);
    __syncthreads();
    int ty = (tid >> 4)*4, tx = (tid & 15)*4;
    float af[4][4] = {}, ab[4][4] = {};
    #pragma unroll
    for (int kk = 0; kk < 64; kk++){
        float f0[4], g0[4], b0[4];
        #pragma unroll
        for (int i = 0; i < 4; i++){
            f0[i] = kfs[kk][ty+i];
            g0[i] = kbs[kk][ty+i];
            b0[i] = pvs[kk][tx+i];
        }
        #pragma unroll
        for (int i = 0; i < 4; i++)
            #pragma unroll
            for (int j = 0; j < 4; j++){
                af[i][j] += f0[i]*b0[j];
                ab[i][j] += g0[i]*b0[j];
            }
    }
    size_t sb = ((size_t)bh*16 + c)*4096;
    #pragma unroll
    for (int i = 0; i < 4; i++){
        *(float4*)(Sf + sb + (size_t)(ty+i)*64 + tx) = make_float4(af[i][0], af[i][1], af[i][2], af[i][3]);
        *(float4*)(Sb + sb + (size_t)(ty+i)*64 + tx) = make_float4(ab[i][0], ab[i][1], ab[i][2], ab[i][3]);
    }
}

// ---------------- in-place chunk-state cumsum ----------------
__global__ void k_cumsum(float* __restrict__ Sf, float* __restrict__ Sb){
    int bh = blockIdx.x, tid = threadIdx.x;
    size_t base = (size_t)bh*16*4096;
    #pragma unroll
    for (int i = 0; i < 16; i++){
        int e = tid + i*256;
        float run = 0.f;
        for (int c = 0; c < 16; c++){
            float* p = Sf + base + (size_t)c*4096 + e;
            float t = *p; *p = run; run += t;
        }
        run = 0.f;
        for (int c = 15; c >= 0; c--){
            float* p = Sb + base + (size_t)c*4096 + e;
            float t = *p; *p = run; run += t;
        }
    }
}

// ---------------- per-chunk y: masked diag + state GEMMs ----------------
__global__ void k_apv2(const float* __restrict__ rf, const float* __restrict__ kf,
                       const float* __restrict__ rb, const float* __restrict__ kb,
                       const float* __restrict__ X,
                       const float* __restrict__ Sf, const float* __restrict__ Sb,
                       float* __restrict__ y){
    __shared__ float rs[64][65], ks[64][65], at[64][65];
    int c = blockIdx.x, bh = blockIdx.y, tid = threadIdx.x;
    size_t hb = (size_t)bh*CT*64 + (size_t)c*64*64;
    size_t sb = ((size_t)bh*16 + c)*4096;
    int ty = (tid >> 4)*4, tx = (tid & 15)*4;
    LOAD_TILE(rs, rf + hb, 64);
    LOAD_TILE(ks, kf + hb, 64);
    __syncthreads();
    float a4[4][4] = {};
    #pragma unroll
    for (int kk = 0; kk < 64; kk++){
        float a0[4], b0[4];
        #pragma unroll
        for (int i = 0; i < 4; i++){ a0[i] = rs[ty+i][kk]; b0[i] = ks[tx+i][kk]; }
        #pragma unroll
        for (int i = 0; i < 4; i++)
            #pragma unroll
            for (int j = 0; j < 4; j++) a4[i][j] += a0[i]*b0[j];
    }
    __syncthreads();
    LOAD_TILE(rs, rb + hb, 64);
    LOAD_TILE(ks, kb + hb, 64);
    __syncthreads();
    float b4[4][4] = {};
    #pragma unroll
    for (int kk = 0; kk < 64; kk++){
        float a0[4], b0[4];
        #pragma unroll
        for (int i = 0; i < 4; i++){ a0[i] = rs[ty+i][kk]; b0[i] = ks[tx+i][kk]; }
        #pragma unroll
        for (int i = 0; i < 4; i++)
            #pragma unroll
            for (int j = 0; j < 4; j++) b4[i][j] += a0[i]*b0[j];
    }
    #pragma unroll
    for (int i = 0; i < 4; i++)
        #pragma unroll
        for (int j = 0; j < 4; j++)
            at[ty+i][tx+j] = ((ty+i) >= (tx+j)) ? a4[i][j] : b4[i][j];
    __syncthreads();
    LOAD_TILE(rs, X + hb, 64);
    __syncthreads();
    float yacc[4][4] = {};
    #pragma unroll 8
    for (int s = 0; s < 64; s++){
        float a0[4], b0[4];
        #pragma unroll
        for (int i = 0; i < 4; i++){ a0[i] = at[ty+i][s]; b0[i] = rs[s][tx+i]; }
        #pragma unroll
        for (int i = 0; i < 4; i++)
            #pragma unroll
            for (int j = 0; j < 4; j++) yacc[i][j] += a0[i]*b0[j];
    }
    __syncthreads();
    LOAD_TILE(rs, Sf + sb, 64);
    LOAD_TILE(ks, rf + hb, 64);
    __syncthreads();
    #pragma unroll 8
    for (int kk = 0; kk < 64; kk++){
        float a0[4], b0[4];
        #pragma unroll
        for (int i = 0; i < 4; i++){ a0[i] = ks[ty+i][kk]; b0[i] = rs[kk][tx+i]; }
        #pragma unroll
        for (int i = 0; i < 4; i++)
            #pragma unroll
            for (int j = 0; j < 4; j++) yacc[i][j] += a0[i]*b0[j];
    }
    __syncthreads();
    LOAD_TILE(rs, Sb + sb, 64);
    LOAD_TILE(ks, rb + hb, 64);
    __syncthreads();
    #pragma unroll 8
    for (int kk = 0; kk < 64; kk++){
        float a0[4], b0[4];
        #pragma unroll
        for (int i = 0; i < 4; i++){ a0[i] = ks[ty+i][kk]; b0[i] = rs[kk][tx+i]; }
        #pragma unroll
        for (int i = 0; i < 4; i++)
            #pragma unroll
            for (int j = 0; j < 4; j++) yacc[i][j] += a0[i]*b0[j];
    }
    #pragma unroll
    for (int i = 0; i < 4; i++)
        *(float4*)(y + hb + (size_t)(ty+i)*64 + tx) =
            make_float4(yacc[i][0], yacc[i][1], yacc[i][2], yacc[i][3]);
}

// ---------------- GroupNorm + gate ----------------
__global__ void k_gn(const float* __restrict__ y, const float* __restrict__ g,
                     const float* __restrict__ lnw, const float* __restrict__ lnb,
                     float* __restrict__ z){
    int gw = (blockIdx.x*256 + threadIdx.x) >> 6;
    int lane = threadIdx.x & 63;
    if (gw >= CB*CT*CH) return;
    int h = gw % CH; int bt = gw / CH;
    int b = bt / CT, t = bt % CT;
    int bh = b*CH + h;
    float yv = y[((size_t)bh*CT + t)*64 + lane];
    float s1 = yv, s2 = yv*yv;
    #pragma unroll
    for (int off = 32; off; off >>= 1){ s1 += __shfl_xor(s1, off); s2 += __shfl_xor(s2, off); }
    float mu = s1 * (1.f/64.f);
    float var = s2 * (1.f/64.f) - mu*mu;
    float inv = rsqrtf(var + 6.4e-4f);
    int d = h*64 + lane;
    float yn = (yv - mu)*inv*lnw[d] + lnb[d];
    z[(size_t)bt*CD + d] = yn * g[(size_t)bt*CD + d];
}

extern "C" void kernel_launch(void* const* d_in, const int* in_sizes, int n_in,
                              void* d_out, int out_size, void* d_ws, size_t ws_size,
                              hipStream_t stream){
    const float* x          = (const float*)d_in[0];
    const float* tmx        = (const float*)d_in[1];
    const float* tmw        = (const float*)d_in[2];
    const float* tmk        = (const float*)d_in[3];
    const float* tmv        = (const float*)d_in[4];
    const float* tmr        = (const float*)d_in[5];
    const float* tmg        = (const float*)d_in[6];
    const float* maa_w1     = (const float*)d_in[7];
    const float* maa_w2     = (const float*)d_in[8];
    const float* time_decay = (const float*)d_in[9];
    const float* decay_w1   = (const float*)d_in[10];
    const float* decay_w2   = (const float*)d_in[11];
    const float* lucid_temp = (const float*)d_in[12];
    const float* Wr         = (const float*)d_in[13];
    const float* Wk         = (const float*)d_in[14];
    const float* Wv         = (const float*)d_in[15];
    const float* Wg         = (const float*)d_in[16];
    const float* Wo         = (const float*)d_in[17];
    const float* lnw        = (const float*)d_in[18];
    const float* lnb        = (const float*)d_in[19];
    float* out = (float*)d_out;
    float* ws  = (float*)d_ws;

    const size_t S = (size_t)CB*CT*CD;
    float* b0 = ws;          // dxprev -> wbuf -> Yb -> Sb
    float* b1 = ws + 1*S;    // xxx -> xw -> rf
    float* b2 = ws + 2*S;    // xk -> kf
    float* b3 = ws + 3*S;    // xv -> rb
    float* b4 = ws + 4*S;    // xr -> kn -> Sf
    float* b5 = ws + 5*S;    // xg -> X (v -> Pv)
    float* b6 = ws + 6*S;    // rbuf -> y
    float* b7 = ws + 7*S;    // kbuf -> z
    float* b8 = ws + 8*S;    // vbuf -> kb
    float* b9 = ws + 9*S;    // gbuf
    float* mbuf = ws + 10*S;
    const size_t MB_F = 4096*160;
    size_t base_f = 10*S + MB_F;

    const size_t per_bh = (size_t)CT*CT + 16*NB*NB;
    size_t avail = ws_size / sizeof(float);
    int G = 1;
    if (avail > base_f + per_bh){
        size_t g = (avail - base_f) / per_bh;
        G = (g >= CBH) ? CBH : (int)g;
        if (G < 1) G = 1;
    }
    float* P    = ws + base_f;
    float* invL = P + (size_t)G*CT*CT;

    // weight split scratch lives in the P region (dead until k_gram)
    unsigned short* BtHi = (unsigned short*)P;
    unsigned short* BtLo = BtHi + (size_t)CD*CD;

    float* dxprev = b0; float* xxx = b1;
    float* xw = b1; float* xk = b2; float* xv = b3; float* xr = b4; float* xg = b5;
    float* rbuf = b6; float* kbuf = b7; float* vbuf = b8; float* gbuf = b9; float* wbuf = b0;
    float* kn = b4; float* X = b5;
    float* rf = b1; float* kf = b2; float* rb = b3; float* kb = b8;
    float* Yb = b0;
    float* Sf = b4; float* Sb = b0;
    float* ybuf = b6; float* zbuf = b7;

    dim3 mg(CD/64, (CB*CT)/64);
    dim3 tg(CD/64, CD/64);

    k_shift<<<dim3((CB*CT*CD + 255)/256), 256, 0, stream>>>(x, tmx, dxprev, xxx);
    k_gemm<1><<<dim3(3, 32), 256, 0, stream>>>(xxx, maa_w1, nullptr, mbuf, 4096, 160, 768);
    k_mix5<<<dim3(3, 4096), 256, 0, stream>>>(x, dxprev, mbuf, tmw, tmk, tmv, tmr, tmg,
                                              maa_w2, xw, xk, xv, xr, xg);
    k_splitT<<<tg, 256, 0, stream>>>(Wr, BtHi, BtLo, CD, CD);
    k_mgemm<0><<<mg, 256, 0, stream>>>(xr, BtHi, BtLo, nullptr, rbuf, 4096, CD, CD);
    k_splitT<<<tg, 256, 0, stream>>>(Wk, BtHi, BtLo, CD, CD);
    k_mgemm<0><<<mg, 256, 0, stream>>>(xk, BtHi, BtLo, nullptr, kbuf, 4096, CD, CD);
    k_splitT<<<tg, 256, 0, stream>>>(Wv, BtHi, BtLo, CD, CD);
    k_mgemm<0><<<mg, 256, 0, stream>>>(xv, BtHi, BtLo, nullptr, vbuf, 4096, CD, CD);
    k_splitT<<<tg, 256, 0, stream>>>(Wg, BtHi, BtLo, CD, CD);
    k_mgemm<2><<<mg, 256, 0, stream>>>(xg, BtHi, BtLo, nullptr, gbuf, 4096, CD, CD);
    // decay: mbuf = tanh(xw @ decay_w1); wbuf = mbuf @ decay_w2 + time_decay
    k_splitT<<<dim3(1, 12), 256, 0, stream>>>(decay_w1, BtHi, BtLo, CD, 64);
    k_mgemm<1><<<dim3(1, 64), 256, 0, stream>>>(xw, BtHi, BtLo, nullptr, mbuf, 4096, 64, CD);
    k_splitT<<<dim3(12, 1), 256, 0, stream>>>(decay_w2, BtHi, BtLo, 64, CD);
    k_mgemm<3><<<dim3(12, 64), 256, 0, stream>>>(mbuf, BtHi, BtLo, time_decay, wbuf, 4096, CD, 64);

    k_knvx<<<dim3((CB*CH*CT*64)/256), 256, 0, stream>>>(kbuf, vbuf, kn, X);
    k_scan2<<<dim3(CBH), 256, 0, stream>>>(rbuf, kbuf, wbuf, rf, kf, rb, kb);

    for (int bh0 = 0; bh0 < CBH; bh0 += G){
        int Gc = (CBH - bh0 < G) ? (CBH - bh0) : G;
        k_gram<<<dim3(16, 16, Gc), 256, 0, stream>>>(kn, lucid_temp, P, bh0);
        k_potrf0<<<dim3(Gc), 256, 0, stream>>>(P, invL);
        for (int jb = 0; jb < 15; jb++){
            int nt = 15 - jb;
            k_trsm<<<dim3(nt, Gc), 256, 0, stream>>>(P, invL, jb);
            k_syrkf<<<dim3(nt+1, nt, Gc), 256, 0, stream>>>(P, invL, X, Yb, bh0, jb);
        }
        k_solve<0><<<dim3(1, Gc), 256, 0, stream>>>(P, invL, X, Yb, bh0, 15);  // fwd tail (diag 15)
        for (int jb = 15; jb >= 0; jb--)
            k_solve<1><<<dim3(jb+1, Gc), 256, 0, stream>>>(P, invL, X, Yb, bh0, jb);
    }

    k_outer<<<dim3(16, CBH), 256, 0, stream>>>(kf, kb, X, Sf, Sb);
    k_cumsum<<<dim3(CBH), 256, 0, stream>>>(Sf, Sb);
    k_apv2<<<dim3(16, CBH), 256, 0, stream>>>(rf, kf, rb, kb, X, Sf, Sb, ybuf);
    k_gn<<<dim3((CB*CT*CH*64)/256), 256, 0, stream>>>(ybuf, gbuf, lnw, lnb, zbuf);
    k_splitT<<<tg, 256, 0, stream>>>(Wo, BtHi, BtLo, CD, CD);
    k_mgemm<0><<<mg, 256, 0, stream>>>(zbuf, BtHi, BtLo, nullptr, out, 4096, CD, CD);
}

// Round 13
// 3330.036 us; speedup vs baseline: 1.4437x; 1.4427x over previous
//
#include <hip/hip_runtime.h>
#include <math.h>

#define CB 4
#define CT 1024
#define CD 768
#define CH 12
#define CK 64
#define CBH (CB*CH)
#define NB 64

// packed lower-triangular tile storage for P: tile (i,j), i>=j, dense 64x64 row-major
#define PTILE(i,j) ((size_t)(((i)*((i)+1))/2 + (j))*4096)
#define PBF ((size_t)136*4096)   // floats per (b,h): 136 tiles

typedef __attribute__((ext_vector_type(8))) short sh8;
typedef __attribute__((ext_vector_type(8))) unsigned short ush8;
typedef __attribute__((ext_vector_type(4))) unsigned short ush4;
typedef __attribute__((ext_vector_type(4))) float fl4;

__device__ __forceinline__ unsigned short f2bf(float f){
    unsigned u = __builtin_bit_cast(unsigned, f);
    unsigned r = (u + 0x7fff + ((u >> 16) & 1)) >> 16;
    return (unsigned short)r;
}
__device__ __forceinline__ float bf2f(unsigned short u){
    return __builtin_bit_cast(float, (unsigned)u << 16);
}
#define MFMA3(acc, ah, al, bh_, bl_) { \
    acc = __builtin_amdgcn_mfma_f32_16x16x32_bf16(al, bh_, acc, 0, 0, 0); \
    acc = __builtin_amdgcn_mfma_f32_16x16x32_bf16(ah, bl_, acc, 0, 0, 0); \
    acc = __builtin_amdgcn_mfma_f32_16x16x32_bf16(ah, bh_, acc, 0, 0, 0); }

// cooperative 64x64 tile load: global (row-major, given stride) -> LDS [64][65]
#define LOAD_TILE(dst, src, stride) { \
    _Pragma("unroll") \
    for (int i_ = 0; i_ < 4; i_++){ \
        int rr_ = (tid>>4) + i_*16, cc_ = (tid&15)*4; \
        float4 v_ = *(const float4*)((src) + (size_t)rr_*(stride) + cc_); \
        dst[rr_][cc_+0]=v_.x; dst[rr_][cc_+1]=v_.y; dst[rr_][cc_+2]=v_.z; dst[rr_][cc_+3]=v_.w; \
    } }

// ---------------- elementwise: token shift + xxx ----------------
__global__ void k_shift(const float* __restrict__ x, const float* __restrict__ tmx,
                        float* __restrict__ dxprev, float* __restrict__ xxx){
    int idx = blockIdx.x*256 + threadIdx.x;
    if (idx >= CB*CT*CD) return;
    int d = idx % CD;
    int bt = idx / CD;
    int t = bt % CT;
    float xc = x[idx];
    float xl = (t > 0)      ? x[idx - CD] : 0.f;
    float xr = (t < CT-1)   ? x[idx + CD] : 0.f;
    float dx = 0.5f*(xl + xr) - xc;
    dxprev[idx] = dx;
    xxx[idx] = xc + dx * tmx[d];
}

// ---------------- generic tiled fp32 GEMM (maa_w1 only) ----------------
template<int MODE>
__global__ void k_gemm(const float* __restrict__ A, const float* __restrict__ Bm,
                       const float* __restrict__ bias, float* __restrict__ C,
                       int M, int N, int Kd){
    __shared__ float As[16][128];
    __shared__ float Bs[16][64];
    int tid = threadIdx.x;
    int m0 = blockIdx.y * 128, n0 = blockIdx.x * 64;
    int tn = (tid & 15) * 4;
    int tm = (tid >> 4) * 8;
    float acc[8][4] = {};
    for (int k0 = 0; k0 < Kd; k0 += 16){
        #pragma unroll
        for (int i = 0; i < 8; i++){
            int e = tid + i*256;
            int r = e >> 4, c = e & 15;
            As[c][r] = A[(size_t)(m0+r)*Kd + k0 + c];
        }
        #pragma unroll
        for (int i = 0; i < 4; i++){
            int e = tid + i*256;
            int r = e >> 6, c = e & 63;
            float bv = 0.f;
            if (n0 + c < N) bv = Bm[(size_t)(k0+r)*N + n0 + c];
            Bs[r][c] = bv;
        }
        __syncthreads();
        #pragma unroll
        for (int kk = 0; kk < 16; kk++){
            float a0[8], b0[4];
            #pragma unroll
            for (int i = 0; i < 8; i++) a0[i] = As[kk][tm+i];
            #pragma unroll
            for (int j = 0; j < 4; j++) b0[j] = Bs[kk][tn+j];
            #pragma unroll
            for (int i = 0; i < 8; i++)
                #pragma unroll
                for (int j = 0; j < 4; j++) acc[i][j] += a0[i]*b0[j];
        }
        __syncthreads();
    }
    #pragma unroll
    for (int i = 0; i < 8; i++)
        #pragma unroll
        for (int j = 0; j < 4; j++){
            int mm = m0 + tm + i, nn = n0 + tn + j;
            if (nn < N){
                float v = acc[i][j];
                if (MODE == 1) v = tanhf(v);
                else if (MODE == 2) v = v / (1.f + expf(-v));
                else if (MODE == 3) v += bias[nn];
                C[(size_t)mm*N + nn] = v;
            }
        }
}

// ---------------- weight transpose + split: B[K][N] -> Bt{Hi,Lo}[N][K] ----------------
__global__ void k_splitT(const float* __restrict__ B, unsigned short* __restrict__ hi,
                         unsigned short* __restrict__ lo, int Kd, int N){
    __shared__ float ts[64][65];
    int tid = threadIdx.x;
    int n0 = blockIdx.x*64, k0 = blockIdx.y*64;
    #pragma unroll
    for (int i = 0; i < 4; i++){
        int rr = (tid>>4) + i*16, cc = (tid&15)*4;
        float4 v = *(const float4*)(B + (size_t)(k0+rr)*N + n0 + cc);
        ts[rr][cc+0]=v.x; ts[rr][cc+1]=v.y; ts[rr][cc+2]=v.z; ts[rr][cc+3]=v.w;
    }
    __syncthreads();
    #pragma unroll
    for (int i = 0; i < 4; i++){
        int nl = (tid>>4) + i*16, k4 = (tid&15)*4;
        ush4 vh, vl;
        #pragma unroll
        for (int j = 0; j < 4; j++){
            float f = ts[k4+j][nl];
            unsigned short h = f2bf(f);
            vh[j] = h;
            vl[j] = f2bf(f - bf2f(h));
        }
        size_t o = (size_t)(n0+nl)*Kd + k0 + k4;
        *reinterpret_cast<ush4*>(hi + o) = vh;
        *reinterpret_cast<ush4*>(lo + o) = vl;
    }
}

// ---------------- MFMA split-bf16 GEMM: C[M,N] = A[M,K] @ Bt[N,K]^T ----------------
// MODE 0 plain, 1 tanh, 2 silu, 3 +bias[n]
template<int MODE>
__global__ __launch_bounds__(256) void k_mgemm(const float* __restrict__ A,
        const unsigned short* __restrict__ BtHi, const unsigned short* __restrict__ BtLo,
        const float* __restrict__ bias, float* __restrict__ C, int M, int N, int Kd){
    __shared__ unsigned short AHI[2048], ALO[2048], BHI[2048], BLO[2048];
    int tid = threadIdx.x;
    int n0 = blockIdx.x*64, m0 = blockIdx.y*64;
    int w = tid >> 6, lane = tid & 63;
    int wm = w >> 1, wn = w & 1;
    fl4 acc[2][2];
    #pragma unroll
    for (int mi = 0; mi < 2; mi++)
        #pragma unroll
        for (int ni = 0; ni < 2; ni++) acc[mi][ni] = (fl4){0.f, 0.f, 0.f, 0.f};
    int sm = tid >> 2;
    int sk = (tid & 3) * 8;
    int slane = (sm & 15) + ((tid & 3) << 4);
    int sidx = (((sm >> 4)*64) + slane) * 8;
    const int nsteps = Kd >> 5;
    for (int ks = 0; ks < nsteps; ks++){
        int k0 = ks << 5;
        __syncthreads();
        {
            const float* ap = A + (size_t)(m0+sm)*Kd + k0 + sk;
            float4 a0 = *(const float4*)ap, a1 = *(const float4*)(ap+4);
            float av[8] = {a0.x,a0.y,a0.z,a0.w,a1.x,a1.y,a1.z,a1.w};
            ush8 vh, vl;
            #pragma unroll
            for (int i = 0; i < 8; i++){
                unsigned short h = f2bf(av[i]);
                vh[i] = h;
                vl[i] = f2bf(av[i] - bf2f(h));
            }
            *reinterpret_cast<ush8*>(&AHI[sidx]) = vh;
            *reinterpret_cast<ush8*>(&ALO[sidx]) = vl;
            size_t bo = (size_t)(n0+sm)*Kd + k0 + sk;
            *reinterpret_cast<ush8*>(&BHI[sidx]) = *reinterpret_cast<const ush8*>(BtHi + bo);
            *reinterpret_cast<ush8*>(&BLO[sidx]) = *reinterpret_cast<const ush8*>(BtLo + bo);
        }
        __syncthreads();
        sh8 ah[2], al[2], bh[2], bl[2];
        #pragma unroll
        for (int mi = 0; mi < 2; mi++){
            int gm = wm*2 + mi;
            ah[mi] = *reinterpret_cast<sh8*>(&AHI[(gm*64 + lane)*8]);
            al[mi] = *reinterpret_cast<sh8*>(&ALO[(gm*64 + lane)*8]);
        }
        #pragma unroll
        for (int ni = 0; ni < 2; ni++){
            int gn = wn*2 + ni;
            bh[ni] = *reinterpret_cast<sh8*>(&BHI[(gn*64 + lane)*8]);
            bl[ni] = *reinterpret_cast<sh8*>(&BLO[(gn*64 + lane)*8]);
        }
        #pragma unroll
        for (int mi = 0; mi < 2; mi++)
            #pragma unroll
            for (int ni = 0; ni < 2; ni++)
                MFMA3(acc[mi][ni], ah[mi], al[mi], bh[ni], bl[ni]);
    }
    #pragma unroll
    for (int mi = 0; mi < 2; mi++)
        #pragma unroll
        for (int ni = 0; ni < 2; ni++){
            int cc = n0 + wn*32 + ni*16 + (lane & 15);
            int rb = m0 + wm*32 + mi*16 + ((lane >> 4) << 2);
            #pragma unroll
            for (int j = 0; j < 4; j++){
                float v = acc[mi][ni][j];
                if (MODE == 1) v = tanhf(v);
                else if (MODE == 2) v = v / (1.f + expf(-v));
                else if (MODE == 3) v += bias[cc];
                C[(size_t)(rb+j)*N + cc] = v;
            }
        }
}

// ---------------- 5-way low-rank mix ----------------
__global__ void k_mix5(const float* __restrict__ x, const float* __restrict__ dxprev,
                       const float* __restrict__ m,
                       const float* __restrict__ tmw, const float* __restrict__ tmk,
                       const float* __restrict__ tmv, const float* __restrict__ tmr,
                       const float* __restrict__ tmg, const float* __restrict__ w2,
                       float* __restrict__ xw, float* __restrict__ xk, float* __restrict__ xv,
                       float* __restrict__ xr, float* __restrict__ xg){
    __shared__ float ms[160];
    int i = blockIdx.y;
    int j = blockIdx.x*256 + threadIdx.x;
    if (threadIdx.x < 160) ms[threadIdx.x] = m[(size_t)i*160 + threadIdx.x];
    __syncthreads();
    float xc = x[(size_t)i*CD + j], dx = dxprev[(size_t)i*CD + j];
    const float* tms[5] = {tmw, tmk, tmv, tmr, tmg};
    float* outs[5] = {xw, xk, xv, xr, xg};
    #pragma unroll
    for (int c = 0; c < 5; c++){
        float s = tms[c][j];
        const float* w2c = w2 + (size_t)c*32*CD + j;
        #pragma unroll
        for (int dm = 0; dm < 32; dm++) s += ms[c*32+dm] * w2c[(size_t)dm*CD];
        outs[c][(size_t)i*CD + j] = xc + dx*s;
    }
}

// ---------------- normalize k, stage v into X (head layout) ----------------
__global__ void k_knvx(const float* __restrict__ k, const float* __restrict__ v,
                       float* __restrict__ kn, float* __restrict__ X){
    int gw = (blockIdx.x*256 + threadIdx.x) >> 6;
    int lane = threadIdx.x & 63;
    if (gw >= CB*CH*CT) return;
    int t = gw % CT; int bh = gw / CT; int h = bh % CH; int b = bh / CH;
    size_t src = ((size_t)(b*CT + t))*CD + h*64 + lane;
    float kv = k[src];
    float ss = kv*kv;
    #pragma unroll
    for (int off = 32; off; off >>= 1) ss += __shfl_xor(ss, off);
    float nrm = fmaxf(sqrtf(ss), 1e-12f);
    size_t dst = ((size_t)bh*CT + t)*64 + lane;
    kn[dst] = kv / nrm;
    X[dst]  = v[src];
}

// ---------------- decay scan, fully coalesced ----------------
__global__ __launch_bounds__(256) void k_scan2(const float* __restrict__ r, const float* __restrict__ k,
                        const float* __restrict__ w,
                        float* __restrict__ rf, float* __restrict__ kf,
                        float* __restrict__ rb, float* __restrict__ kb){
    __shared__ float parts[16][4][64];
    __shared__ float carr[16][64];
    __shared__ float refs[2][64];
    int bh = blockIdx.x; int h = bh % CH; int b = bh / CH;
    int tid = threadIdx.x; int wid = tid >> 6; int ch = tid & 63;
    const float* wb = w + (size_t)b*CT*CD + h*64;
    for (int tc = 0; tc < 16; tc++){
        float sum = 0.f;
        int tb = tc*64 + wid*16;
        for (int s = 0; s < 16; s++)
            sum -= expf(wb[(size_t)(tb+s)*CD + ch]);
        parts[tc][wid][ch] = sum;
    }
    __syncthreads();
    if (tid < 64){
        float run = 0.f;
        for (int tc = 0; tc < 16; tc++){
            carr[tc][tid] = run;
            run += parts[tc][0][tid] + parts[tc][1][tid] + parts[tc][2][tid] + parts[tc][3][tid];
        }
        float wv512 = -expf(wb[(size_t)512*CD + tid]);
        refs[0][tid] = carr[8][tid] + wv512;
        refs[1][tid] = carr[8][tid];
    }
    __syncthreads();
    const float* rbp = r + (size_t)b*CT*CD + h*64;
    const float* kbp = k + (size_t)b*CT*CD + h*64;
    size_t ob = (size_t)bh*CT*64;
    float ref_f = refs[0][ch], ref_b = refs[1][ch];
    for (int tc = 0; tc < 16; tc++){
        float run = carr[tc][ch];
        if (wid > 0) run += parts[tc][0][ch];
        if (wid > 1) run += parts[tc][1][ch];
        if (wid > 2) run += parts[tc][2][ch];
        int tb = tc*64 + wid*16;
        for (int s = 0; s < 16; s++){
            int t = tb + s;
            float wv = -expf(wb[(size_t)t*CD + ch]);
            run += wv;
            float csf = fminf(fmaxf(run - ref_f, -60.f), 60.f);
            float csb = fminf(fmaxf((run - wv) - ref_b, -60.f), 60.f);
            float rv = rbp[(size_t)t*CD + ch], kv = kbp[(size_t)t*CD + ch];
            rf[ob + (size_t)t*64 + ch] = rv * expf(csf);
            kf[ob + (size_t)t*64 + ch] = kv * expf(-csf);
            rb[ob + (size_t)t*64 + ch] = rv * expf(-csb);
            kb[ob + (size_t)t*64 + ch] = kv * expf(csb);
        }
    }
}

// ---------------- P(lower, packed tiles) = I + exp(clip(temp * kn knT)) ----------------
__global__ void k_gram(const float* __restrict__ kn, const float* __restrict__ lucid_temp,
                       float* __restrict__ P, int bh0){
    int ti = blockIdx.y, tj = blockIdx.x;
    if (ti < tj) return;
    int t0 = ti*64, s0 = tj*64;
    __shared__ float tA[64][65];
    __shared__ float tB[64][65];
    int lbh = blockIdx.z; int gbh = bh0 + lbh; int h = gbh % CH;
    int tid = threadIdx.x;
    LOAD_TILE(tA, kn + ((size_t)gbh*CT + t0)*64, 64);
    LOAD_TILE(tB, kn + ((size_t)gbh*CT + s0)*64, 64);
    __syncthreads();
    float tv = lucid_temp[h];
    tv = (tv > 20.f) ? tv : log1pf(expf(tv));
    int ty = (tid >> 4)*4, tx = (tid & 15)*4;
    float acc[4][4] = {};
    #pragma unroll
    for (int kk = 0; kk < 64; kk++){
        float a0[4], b0[4];
        #pragma unroll
        for (int i = 0; i < 4; i++){ a0[i] = tA[ty+i][kk]; b0[i] = tB[tx+i][kk]; }
        #pragma unroll
        for (int i = 0; i < 4; i++)
            #pragma unroll
            for (int j = 0; j < 4; j++) acc[i][j] += a0[i]*b0[j];
    }
    float* Pt = P + (size_t)lbh*PBF + PTILE(ti,tj);
    #pragma unroll
    for (int i = 0; i < 4; i++){
        int tt = t0+ty+i;
        float4 v;
        float g0 = fminf(fmaxf(tv*acc[i][0], -20.f), 20.f);
        float g1 = fminf(fmaxf(tv*acc[i][1], -20.f), 20.f);
        float g2 = fminf(fmaxf(tv*acc[i][2], -20.f), 20.f);
        float g3 = fminf(fmaxf(tv*acc[i][3], -20.f), 20.f);
        v.x = expf(g0) + ((tt == s0+tx+0) ? 1.f : 0.f);
        v.y = expf(g1) + ((tt == s0+tx+1) ? 1.f : 0.f);
        v.z = expf(g2) + ((tt == s0+tx+2) ? 1.f : 0.f);
        v.w = expf(g3) + ((tt == s0+tx+3) ? 1.f : 0.f);
        *(float4*)(Pt + (size_t)(ty+i)*64 + tx) = v;
    }
}

// ---------------- in-LDS 64x64 Cholesky + triangular inverse ----------------
__device__ __forceinline__ void potrf_inv(float (&s)[64][65], float (&inv)[64][65], int tid){
    for (int j = 0; j < 63; j++){
        __syncthreads();
        float invd = 1.f / fmaxf(s[j][j], 1e-20f);
        int n = 63 - j;
        for (int e = tid; e < n*n; e += 256){
            int ii = j+1 + e / n, cc = j+1 + e % n;
            s[ii][cc] -= s[ii][j]*s[cc][j]*invd;
        }
    }
    __syncthreads();
    for (int e = tid; e < 64*64; e += 256){
        int i2 = e >> 6, j2 = e & 63;
        if (i2 > j2) s[i2][j2] *= rsqrtf(fmaxf(s[j2][j2], 1e-20f));
    }
    __syncthreads();
    if (tid < 64) s[tid][tid] = sqrtf(fmaxf(s[tid][tid], 1e-20f));
    __syncthreads();
    if (tid < 64){
        int c = tid;
        for (int j = 0; j < c; j++) inv[j][c] = 0.f;
        for (int j = c; j < 64; j++){
            float sum = (j == c) ? 1.f : 0.f;
            for (int kk = c; kk < j; kk++) sum -= s[j][kk]*inv[kk][c];
            inv[j][c] = sum / s[j][j];
        }
    }
    __syncthreads();
}

// write L (lower of s) into packed diag tile (stride 64) + inv into invL
__device__ __forceinline__ void potrf_writeout(float (&s)[64][65], float (&inv)[64][65], int tid,
                                               float* __restrict__ Pd, float* __restrict__ invp){
    for (int e = tid; e < 4096; e += 256){
        int r2 = e >> 6, c2 = e & 63;
        if (c2 <= r2) Pd[(size_t)r2*64 + c2] = s[r2][c2];
    }
    #pragma unroll
    for (int i_ = 0; i_ < 4; i_++){
        int rr_ = (tid>>4) + i_*16, cc_ = (tid&15)*4;
        float4 v_ = make_float4(inv[rr_][cc_], inv[rr_][cc_+1], inv[rr_][cc_+2], inv[rr_][cc_+3]);
        *(float4*)(invp + rr_*64 + cc_) = v_;
    }
}

__global__ void k_potrf0(float* __restrict__ P, float* __restrict__ invL){
    __shared__ float s[64][65], inv[64][65];
    int bh = blockIdx.x; int tid = threadIdx.x;
    float* Pt = P + (size_t)bh*PBF;   // tile (0,0)
    LOAD_TILE(s, Pt, 64);
    __syncthreads();
    potrf_inv(s, inv, tid);
    potrf_writeout(s, inv, tid, Pt, invL + (size_t)bh*16*4096);
}

// ---------------- TRSM: panel tile = A(rt,jb) @ invL(jb)^T ----------------
__global__ void k_trsm(float* __restrict__ P, const float* __restrict__ invL, int jb){
    __shared__ float a[64][65];
    __shared__ float iv[64][65];
    int bh = blockIdx.y;
    int rt = jb + 1 + blockIdx.x;
    int tid = threadIdx.x;
    float* Pt = P + (size_t)bh*PBF + PTILE(rt,jb);
    const float* invp = invL + ((size_t)bh*16 + jb)*4096;
    LOAD_TILE(a, Pt, 64);
    LOAD_TILE(iv, invp, 64);
    __syncthreads();
    int ty = (tid >> 4)*4, tx = (tid & 15)*4;
    float acc[4][4] = {};
    #pragma unroll
    for (int kk = 0; kk < 64; kk++){
        float a0[4], b0[4];
        #pragma unroll
        for (int i = 0; i < 4; i++){ a0[i] = a[ty+i][kk]; b0[i] = iv[tx+i][kk]; }
        #pragma unroll
        for (int i = 0; i < 4; i++)
            #pragma unroll
            for (int j = 0; j < 4; j++) acc[i][j] += a0[i]*b0[j];
    }
    #pragma unroll
    for (int i = 0; i < 4; i++)
        *(float4*)(Pt + (size_t)(ty+i)*64 + tx) =
            make_float4(acc[i][0], acc[i][1], acc[i][2], acc[i][3]);
}

// ---------------- fused SYRK + inline next-potrf + forward-solve column ----------------
// grid (nt+1, nt, Gc): tj<=ti -> syrk tile; tj==nt -> fwd solve for ib=jb+1+ti
__global__ void k_syrkf(float* __restrict__ P, float* __restrict__ invL,
                        float* __restrict__ X, float* __restrict__ Yb, int bh0, int jb){
    __shared__ float sA[64][65], sB[64][65], sC[64][65];
    int tj = blockIdx.x, ti = blockIdx.y, lbh = blockIdx.z;
    int tid = threadIdx.x;
    int ty = (tid >> 4)*4, tx = (tid & 15)*4;
    float* Pb = P + (size_t)lbh*PBF;
    if (tj == gridDim.x - 1){
        // forward-solve role: Y = invL[jb] @ X[jb]; X[ib] -= L[ib][jb] @ Y
        int ib = jb + 1 + ti;
        const float* invp = invL + ((size_t)lbh*16 + jb)*4096;
        const float* Xj = X + ((size_t)(bh0+lbh)*CT + jb*64)*64;
        LOAD_TILE(sA, invp, 64);
        LOAD_TILE(sB, Xj, 64);
        __syncthreads();
        float c4[4][4] = {};
        #pragma unroll
        for (int kk = 0; kk < 64; kk++){
            float a0[4], b0[4];
            #pragma unroll
            for (int i = 0; i < 4; i++){ a0[i] = sA[ty+i][kk]; b0[i] = sB[kk][tx+i]; }
            #pragma unroll
            for (int i = 0; i < 4; i++)
                #pragma unroll
                for (int j = 0; j < 4; j++) c4[i][j] += a0[i]*b0[j];
        }
        if (ti == 0){
            float* yd = Yb + ((size_t)(bh0+lbh)*CT + jb*64)*64;
            #pragma unroll
            for (int i = 0; i < 4; i++)
                *(float4*)(yd + (size_t)(ty+i)*64 + tx) =
                    make_float4(c4[i][0], c4[i][1], c4[i][2], c4[i][3]);
        }
        #pragma unroll
        for (int i = 0; i < 4; i++)
            #pragma unroll
            for (int j = 0; j < 4; j++) sC[ty+i][tx+j] = c4[i][j];
        __syncthreads();
        LOAD_TILE(sA, Pb + PTILE(ib,jb), 64);
        __syncthreads();
        float u4[4][4] = {};
        #pragma unroll
        for (int kk = 0; kk < 64; kk++){
            float a0[4], b0[4];
            #pragma unroll
            for (int i = 0; i < 4; i++){ a0[i] = sA[ty+i][kk]; b0[i] = sC[kk][tx+i]; }
            #pragma unroll
            for (int i = 0; i < 4; i++)
                #pragma unroll
                for (int j = 0; j < 4; j++) u4[i][j] += a0[i]*b0[j];
        }
        float* dst = X + ((size_t)(bh0+lbh)*CT + ib*64)*64;
        #pragma unroll
        for (int i = 0; i < 4; i++){
            float4* p4 = (float4*)(dst + (size_t)(ty+i)*64 + tx);
            float4 v = *p4;
            v.x -= u4[i][0]; v.y -= u4[i][1]; v.z -= u4[i][2]; v.w -= u4[i][3];
            *p4 = v;
        }
        return;
    }
    if (tj > ti) return;
    // SYRK role: tiles (ibr, ibc) -= L(ibr,jb) @ L(ibc,jb)^T
    int ibr = jb + 1 + ti, ibc = jb + 1 + tj;
    LOAD_TILE(sA, Pb + PTILE(ibr,jb), 64);
    LOAD_TILE(sB, Pb + PTILE(ibc,jb), 64);
    __syncthreads();
    float acc[4][4] = {};
    #pragma unroll
    for (int kk = 0; kk < 64; kk++){
        float a0[4], b0[4];
        #pragma unroll
        for (int i = 0; i < 4; i++){ a0[i] = sA[ty+i][kk]; b0[i] = sB[tx+i][kk]; }
        #pragma unroll
        for (int i = 0; i < 4; i++)
            #pragma unroll
            for (int j = 0; j < 4; j++) acc[i][j] += a0[i]*b0[j];
    }
    if (!(ti == 0 && tj == 0)){
        float* Pt = Pb + PTILE(ibr,ibc);
        #pragma unroll
        for (int i = 0; i < 4; i++){
            float4* p4 = (float4*)(Pt + (size_t)(ty+i)*64 + tx);
            float4 v = *p4;
            v.x -= acc[i][0]; v.y -= acc[i][1]; v.z -= acc[i][2]; v.w -= acc[i][3];
            *p4 = v;
        }
    } else {
        float* Pt = Pb + PTILE(ibr,ibr);
        __syncthreads();
        #pragma unroll
        for (int i = 0; i < 4; i++){
            float4 v = *(const float4*)(Pt + (size_t)(ty+i)*64 + tx);
            sA[ty+i][tx+0] = v.x - acc[i][0];
            sA[ty+i][tx+1] = v.y - acc[i][1];
            sA[ty+i][tx+2] = v.z - acc[i][2];
            sA[ty+i][tx+3] = v.w - acc[i][3];
        }
        __syncthreads();
        potrf_inv(sA, sB, tid);
        potrf_writeout(sA, sB, tid, Pt, invL + ((size_t)lbh*16 + jb+1)*4096);
    }
}

// ---------------- fused block substitution (fwd tail + backward sweep) ----------------
template<int TRANS>
__global__ void k_solve(const float* __restrict__ P, const float* __restrict__ invL,
                        float* __restrict__ Xc, float* __restrict__ Yb, int bh0, int jb){
    __shared__ float A[64][65], B[64][65], C[64][65];
    int bh = blockIdx.y, tid = threadIdx.x;
    int ib = TRANS ? blockIdx.x : (jb + blockIdx.x);
    const float* invp = invL + ((size_t)bh*16 + jb)*4096;
    const float* src = (TRANS ? Yb : Xc) + ((size_t)(bh0+bh)*CT + jb*64)*64;
    LOAD_TILE(A, invp, 64);
    LOAD_TILE(B, src, 64);
    __syncthreads();
    int ty = (tid >> 4)*4, tx = (tid & 15)*4;
    float c4[4][4] = {};
    #pragma unroll
    for (int kk = 0; kk < 64; kk++){
        float a0[4], b0[4];
        #pragma unroll
        for (int i = 0; i < 4; i++){
            a0[i] = TRANS ? A[kk][ty+i] : A[ty+i][kk];
            b0[i] = B[kk][tx+i];
        }
        #pragma unroll
        for (int i = 0; i < 4; i++)
            #pragma unroll
            for (int j = 0; j < 4; j++) c4[i][j] += a0[i]*b0[j];
    }
    if (ib == jb){
        float* dst = (TRANS ? Xc : Yb) + ((size_t)(bh0+bh)*CT + jb*64)*64;
        #pragma unroll
        for (int i = 0; i < 4; i++)
            *(float4*)(dst + (size_t)(ty+i)*64 + tx) =
                make_float4(c4[i][0], c4[i][1], c4[i][2], c4[i][3]);
        return;
    }
    #pragma unroll
    for (int i = 0; i < 4; i++)
        #pragma unroll
        for (int j = 0; j < 4; j++) C[ty+i][tx+j] = c4[i][j];
    __syncthreads();
    // fwd: tile (ib,jb); bwd: tile (jb,ib) read transposed
    const float* Lp = P + (size_t)bh*PBF + (TRANS ? PTILE(jb,ib) : PTILE(ib,jb));
    LOAD_TILE(A, Lp, 64);
    __syncthreads();
    float u4[4][4] = {};
    #pragma unroll
    for (int kk = 0; kk < 64; kk++){
        float a0[4], b0[4];
        #pragma unroll
        for (int i = 0; i < 4; i++){
            a0[i] = TRANS ? A[kk][ty+i] : A[ty+i][kk];
            b0[i] = C[kk][tx+i];
        }
        #pragma unroll
        for (int i = 0; i < 4; i++)
            #pragma unroll
            for (int j = 0; j < 4; j++) u4[i][j] += a0[i]*b0[j];
    }
    float* dst = (TRANS ? Yb : Xc) + ((size_t)(bh0+bh)*CT + ib*64)*64;
    #pragma unroll
    for (int i = 0; i < 4; i++){
        float4* p4 = (float4*)(dst + (size_t)(ty+i)*64 + tx);
        float4 v = *p4;
        v.x -= u4[i][0]; v.y -= u4[i][1]; v.z -= u4[i][2]; v.w -= u4[i][3];
        *p4 = v;
    }
}

// ---------------- per-chunk outer products ----------------
__global__ void k_outer(const float* __restrict__ kf, const float* __restrict__ kb,
                        const float* __restrict__ X,
                        float* __restrict__ Sf, float* __restrict__ Sb){
    __shared__ float kfs[64][65], kbs[64][65], pvs[64][65];
    int c = blockIdx.x, bh = blockIdx.y, tid = threadIdx.x;
    size_t hb = (size_t)bh*CT*64 + (size_t)c*64*64;
    LOAD_TILE(kfs, kf + hb, 64);
    LOAD_TILE(kbs, kb + hb, 64);
    LOAD_TILE(pvs, X + hb, 64);
    __syncthreads();
    int ty = (tid >> 4)*4, tx = (tid & 15)*4;
    float af[4][4] = {}, ab[4][4] = {};
    #pragma unroll
    for (int kk = 0; kk < 64; kk++){
        float f0[4], g0[4], b0[4];
        #pragma unroll
        for (int i = 0; i < 4; i++){
            f0[i] = kfs[kk][ty+i];
            g0[i] = kbs[kk][ty+i];
            b0[i] = pvs[kk][tx+i];
        }
        #pragma unroll
        for (int i = 0; i < 4; i++)
            #pragma unroll
            for (int j = 0; j < 4; j++){
                af[i][j] += f0[i]*b0[j];
                ab[i][j] += g0[i]*b0[j];
            }
    }
    size_t sb = ((size_t)bh*16 + c)*4096;
    #pragma unroll
    for (int i = 0; i < 4; i++){
        *(float4*)(Sf + sb + (size_t)(ty+i)*64 + tx) = make_float4(af[i][0], af[i][1], af[i][2], af[i][3]);
        *(float4*)(Sb + sb + (size_t)(ty+i)*64 + tx) = make_float4(ab[i][0], ab[i][1], ab[i][2], ab[i][3]);
    }
}

// ---------------- in-place chunk-state cumsum ----------------
__global__ void k_cumsum(float* __restrict__ Sf, float* __restrict__ Sb){
    int bh = blockIdx.x, tid = threadIdx.x;
    size_t base = (size_t)bh*16*4096;
    #pragma unroll
    for (int i = 0; i < 16; i++){
        int e = tid + i*256;
        float run = 0.f;
        for (int c = 0; c < 16; c++){
            float* p = Sf + base + (size_t)c*4096 + e;
            float t = *p; *p = run; run += t;
        }
        run = 0.f;
        for (int c = 15; c >= 0; c--){
            float* p = Sb + base + (size_t)c*4096 + e;
            float t = *p; *p = run; run += t;
        }
    }
}

// ---------------- per-chunk y: masked diag + state GEMMs ----------------
__global__ void k_apv2(const float* __restrict__ rf, const float* __restrict__ kf,
                       const float* __restrict__ rb, const float* __restrict__ kb,
                       const float* __restrict__ X,
                       const float* __restrict__ Sf, const float* __restrict__ Sb,
                       float* __restrict__ y){
    __shared__ float rs[64][65], ks[64][65], at[64][65];
    int c = blockIdx.x, bh = blockIdx.y, tid = threadIdx.x;
    size_t hb = (size_t)bh*CT*64 + (size_t)c*64*64;
    size_t sb = ((size_t)bh*16 + c)*4096;
    int ty = (tid >> 4)*4, tx = (tid & 15)*4;
    LOAD_TILE(rs, rf + hb, 64);
    LOAD_TILE(ks, kf + hb, 64);
    __syncthreads();
    float a4[4][4] = {};
    #pragma unroll
    for (int kk = 0; kk < 64; kk++){
        float a0[4], b0[4];
        #pragma unroll
        for (int i = 0; i < 4; i++){ a0[i] = rs[ty+i][kk]; b0[i] = ks[tx+i][kk]; }
        #pragma unroll
        for (int i = 0; i < 4; i++)
            #pragma unroll
            for (int j = 0; j < 4; j++) a4[i][j] += a0[i]*b0[j];
    }
    __syncthreads();
    LOAD_TILE(rs, rb + hb, 64);
    LOAD_TILE(ks, kb + hb, 64);
    __syncthreads();
    float b4[4][4] = {};
    #pragma unroll
    for (int kk = 0; kk < 64; kk++){
        float a0[4], b0[4];
        #pragma unroll
        for (int i = 0; i < 4; i++){ a0[i] = rs[ty+i][kk]; b0[i] = ks[tx+i][kk]; }
        #pragma unroll
        for (int i = 0; i < 4; i++)
            #pragma unroll
            for (int j = 0; j < 4; j++) b4[i][j] += a0[i]*b0[j];
    }
    #pragma unroll
    for (int i = 0; i < 4; i++)
        #pragma unroll
        for (int j = 0; j < 4; j++)
            at[ty+i][tx+j] = ((ty+i) >= (tx+j)) ? a4[i][j] : b4[i][j];
    __syncthreads();
    LOAD_TILE(rs, X + hb, 64);
    __syncthreads();
    float yacc[4][4] = {};
    #pragma unroll 8
    for (int s = 0; s < 64; s++){
        float a0[4], b0[4];
        #pragma unroll
        for (int i = 0; i < 4; i++){ a0[i] = at[ty+i][s]; b0[i] = rs[s][tx+i]; }
        #pragma unroll
        for (int i = 0; i < 4; i++)
            #pragma unroll
            for (int j = 0; j < 4; j++) yacc[i][j] += a0[i]*b0[j];
    }
    __syncthreads();
    LOAD_TILE(rs, Sf + sb, 64);
    LOAD_TILE(ks, rf + hb, 64);
    __syncthreads();
    #pragma unroll 8
    for (int kk = 0; kk < 64; kk++){
        float a0[4], b0[4];
        #pragma unroll
        for (int i = 0; i < 4; i++){ a0[i] = ks[ty+i][kk]; b0[i] = rs[kk][tx+i]; }
        #pragma unroll
        for (int i = 0; i < 4; i++)
            #pragma unroll
            for (int j = 0; j < 4; j++) yacc[i][j] += a0[i]*b0[j];
    }
    __syncthreads();
    LOAD_TILE(rs, Sb + sb, 64);
    LOAD_TILE(ks, rb + hb, 64);
    __syncthreads();
    #pragma unroll 8
    for (int kk = 0; kk < 64; kk++){
        float a0[4], b0[4];
        #pragma unroll
        for (int i = 0; i < 4; i++){ a0[i] = ks[ty+i][kk]; b0[i] = rs[kk][tx+i]; }
        #pragma unroll
        for (int i = 0; i < 4; i++)
            #pragma unroll
            for (int j = 0; j < 4; j++) yacc[i][j] += a0[i]*b0[j];
    }
    #pragma unroll
    for (int i = 0; i < 4; i++)
        *(float4*)(y + hb + (size_t)(ty+i)*64 + tx) =
            make_float4(yacc[i][0], yacc[i][1], yacc[i][2], yacc[i][3]);
}

// ---------------- GroupNorm + gate ----------------
__global__ void k_gn(const float* __restrict__ y, const float* __restrict__ g,
                     const float* __restrict__ lnw, const float* __restrict__ lnb,
                     float* __restrict__ z){
    int gw = (blockIdx.x*256 + threadIdx.x) >> 6;
    int lane = threadIdx.x & 63;
    if (gw >= CB*CT*CH) return;
    int h = gw % CH; int bt = gw / CH;
    int b = bt / CT, t = bt % CT;
    int bh = b*CH + h;
    float yv = y[((size_t)bh*CT + t)*64 + lane];
    float s1 = yv, s2 = yv*yv;
    #pragma unroll
    for (int off = 32; off; off >>= 1){ s1 += __shfl_xor(s1, off); s2 += __shfl_xor(s2, off); }
    float mu = s1 * (1.f/64.f);
    float var = s2 * (1.f/64.f) - mu*mu;
    float inv = rsqrtf(var + 6.4e-4f);
    int d = h*64 + lane;
    float yn = (yv - mu)*inv*lnw[d] + lnb[d];
    z[(size_t)bt*CD + d] = yn * g[(size_t)bt*CD + d];
}

extern "C" void kernel_launch(void* const* d_in, const int* in_sizes, int n_in,
                              void* d_out, int out_size, void* d_ws, size_t ws_size,
                              hipStream_t stream){
    const float* x          = (const float*)d_in[0];
    const float* tmx        = (const float*)d_in[1];
    const float* tmw        = (const float*)d_in[2];
    const float* tmk        = (const float*)d_in[3];
    const float* tmv        = (const float*)d_in[4];
    const float* tmr        = (const float*)d_in[5];
    const float* tmg        = (const float*)d_in[6];
    const float* maa_w1     = (const float*)d_in[7];
    const float* maa_w2     = (const float*)d_in[8];
    const float* time_decay = (const float*)d_in[9];
    const float* decay_w1   = (const float*)d_in[10];
    const float* decay_w2   = (const float*)d_in[11];
    const float* lucid_temp = (const float*)d_in[12];
    const float* Wr         = (const float*)d_in[13];
    const float* Wk         = (const float*)d_in[14];
    const float* Wv         = (const float*)d_in[15];
    const float* Wg         = (const float*)d_in[16];
    const float* Wo         = (const float*)d_in[17];
    const float* lnw        = (const float*)d_in[18];
    const float* lnb        = (const float*)d_in[19];
    float* out = (float*)d_out;
    float* ws  = (float*)d_ws;

    const size_t S = (size_t)CB*CT*CD;
    float* b0 = ws;          // dxprev -> wbuf -> Yb -> Sb
    float* b1 = ws + 1*S;    // xxx -> xw -> rf
    float* b2 = ws + 2*S;    // xk -> kf
    float* b3 = ws + 3*S;    // xv -> rb
    float* b4 = ws + 4*S;    // xr -> kn -> Sf
    float* b5 = ws + 5*S;    // xg -> X (v -> Pv)
    float* b6 = ws + 6*S;    // rbuf -> y
    float* b7 = ws + 7*S;    // kbuf -> z
    float* b8 = ws + 8*S;    // vbuf -> kb
    float* b9 = ws + 9*S;    // gbuf
    float* mbuf = ws + 10*S;
    const size_t MB_F = 4096*160;
    size_t base_f = 10*S + MB_F;

    const size_t per_bh = PBF + 16*4096;   // packed P + invL
    size_t avail = ws_size / sizeof(float);
    int G = 1;
    if (avail > base_f + per_bh){
        size_t g = (avail - base_f) / per_bh;
        G = (g >= CBH) ? CBH : (int)g;
        if (G < 1) G = 1;
    }
    float* P    = ws + base_f;
    float* invL = P + (size_t)G*PBF;

    // weight split scratch: needs 589,824 floats; P+invL region has G*622,592 >= 622,592
    unsigned short* BtHi = (unsigned short*)P;
    unsigned short* BtLo = BtHi + (size_t)CD*CD;

    float* dxprev = b0; float* xxx = b1;
    float* xw = b1; float* xk = b2; float* xv = b3; float* xr = b4; float* xg = b5;
    float* rbuf = b6; float* kbuf = b7; float* vbuf = b8; float* gbuf = b9; float* wbuf = b0;
    float* kn = b4; float* X = b5;
    float* rf = b1; float* kf = b2; float* rb = b3; float* kb = b8;
    float* Yb = b0;
    float* Sf = b4; float* Sb = b0;
    float* ybuf = b6; float* zbuf = b7;

    dim3 mg(CD/64, (CB*CT)/64);
    dim3 tg(CD/64, CD/64);

    k_shift<<<dim3((CB*CT*CD + 255)/256), 256, 0, stream>>>(x, tmx, dxprev, xxx);
    k_gemm<1><<<dim3(3, 32), 256, 0, stream>>>(xxx, maa_w1, nullptr, mbuf, 4096, 160, 768);
    k_mix5<<<dim3(3, 4096), 256, 0, stream>>>(x, dxprev, mbuf, tmw, tmk, tmv, tmr, tmg,
                                              maa_w2, xw, xk, xv, xr, xg);
    k_splitT<<<tg, 256, 0, stream>>>(Wr, BtHi, BtLo, CD, CD);
    k_mgemm<0><<<mg, 256, 0, stream>>>(xr, BtHi, BtLo, nullptr, rbuf, 4096, CD, CD);
    k_splitT<<<tg, 256, 0, stream>>>(Wk, BtHi, BtLo, CD, CD);
    k_mgemm<0><<<mg, 256, 0, stream>>>(xk, BtHi, BtLo, nullptr, kbuf, 4096, CD, CD);
    k_splitT<<<tg, 256, 0, stream>>>(Wv, BtHi, BtLo, CD, CD);
    k_mgemm<0><<<mg, 256, 0, stream>>>(xv, BtHi, BtLo, nullptr, vbuf, 4096, CD, CD);
    k_splitT<<<tg, 256, 0, stream>>>(Wg, BtHi, BtLo, CD, CD);
    k_mgemm<2><<<mg, 256, 0, stream>>>(xg, BtHi, BtLo, nullptr, gbuf, 4096, CD, CD);
    // decay: mbuf = tanh(xw @ decay_w1); wbuf = mbuf @ decay_w2 + time_decay
    k_splitT<<<dim3(1, 12), 256, 0, stream>>>(decay_w1, BtHi, BtLo, CD, 64);
    k_mgemm<1><<<dim3(1, 64), 256, 0, stream>>>(xw, BtHi, BtLo, nullptr, mbuf, 4096, 64, CD);
    k_splitT<<<dim3(12, 1), 256, 0, stream>>>(decay_w2, BtHi, BtLo, 64, CD);
    k_mgemm<3><<<dim3(12, 64), 256, 0, stream>>>(mbuf, BtHi, BtLo, time_decay, wbuf, 4096, CD, 64);

    k_knvx<<<dim3((CB*CH*CT*64)/256), 256, 0, stream>>>(kbuf, vbuf, kn, X);
    k_scan2<<<dim3(CBH), 256, 0, stream>>>(rbuf, kbuf, wbuf, rf, kf, rb, kb);

    for (int bh0 = 0; bh0 < CBH; bh0 += G){
        int Gc = (CBH - bh0 < G) ? (CBH - bh0) : G;
        k_gram<<<dim3(16, 16, Gc), 256, 0, stream>>>(kn, lucid_temp, P, bh0);
        k_potrf0<<<dim3(Gc), 256, 0, stream>>>(P, invL);
        for (int jb = 0; jb < 15; jb++){
            int nt = 15 - jb;
            k_trsm<<<dim3(nt, Gc), 256, 0, stream>>>(P, invL, jb);
            k_syrkf<<<dim3(nt+1, nt, Gc), 256, 0, stream>>>(P, invL, X, Yb, bh0, jb);
        }
        k_solve<0><<<dim3(1, Gc), 256, 0, stream>>>(P, invL, X, Yb, bh0, 15);  // fwd tail (diag 15)
        for (int jb = 15; jb >= 0; jb--)
            k_solve<1><<<dim3(jb+1, Gc), 256, 0, stream>>>(P, invL, X, Yb, bh0, jb);
    }

    k_outer<<<dim3(16, CBH), 256, 0, stream>>>(kf, kb, X, Sf, Sb);
    k_cumsum<<<dim3(CBH), 256, 0, stream>>>(Sf, Sb);
    k_apv2<<<dim3(16, CBH), 256, 0, stream>>>(rf, kf, rb, kb, X, Sf, Sb, ybuf);
    k_gn<<<dim3((CB*CT*CH*64)/256), 256, 0, stream>>>(ybuf, gbuf, lnw, lnb, zbuf);
    k_splitT<<<tg, 256, 0, stream>>>(Wo, BtHi, BtLo, CD, CD);
    k_mgemm<0><<<mg, 256, 0, stream>>>(zbuf, BtHi, BtLo, nullptr, out, 4096, CD, CD);
}

// Round 14
// 3329.305 us; speedup vs baseline: 1.4440x; 1.0002x over previous
//
#include <hip/hip_runtime.h>
#include <hip/hip_cooperative_groups.h>
#include <math.h>

namespace cg = cooperative_groups;

#define CB 4
#define CT 1024
#define CD 768
#define CH 12
#define CK 64
#define CBH (CB*CH)
#define NB 64

// packed lower-triangular tile storage for P: tile (i,j), i>=j, dense 64x64 row-major
#define PTILE(i,j) ((size_t)(((i)*((i)+1))/2 + (j))*4096)
#define PBF ((size_t)136*4096)   // floats per (b,h): 136 tiles

typedef __attribute__((ext_vector_type(8))) short sh8;
typedef __attribute__((ext_vector_type(8))) unsigned short ush8;
typedef __attribute__((ext_vector_type(4))) unsigned short ush4;
typedef __attribute__((ext_vector_type(4))) float fl4;

__device__ __forceinline__ unsigned short f2bf(float f){
    unsigned u = __builtin_bit_cast(unsigned, f);
    unsigned r = (u + 0x7fff + ((u >> 16) & 1)) >> 16;
    return (unsigned short)r;
}
__device__ __forceinline__ float bf2f(unsigned short u){
    return __builtin_bit_cast(float, (unsigned)u << 16);
}
#define MFMA3(acc, ah, al, bh_, bl_) { \
    acc = __builtin_amdgcn_mfma_f32_16x16x32_bf16(al, bh_, acc, 0, 0, 0); \
    acc = __builtin_amdgcn_mfma_f32_16x16x32_bf16(ah, bl_, acc, 0, 0, 0); \
    acc = __builtin_amdgcn_mfma_f32_16x16x32_bf16(ah, bh_, acc, 0, 0, 0); }

// cooperative 64x64 tile load: global (row-major, given stride) -> LDS [64][65]
#define LOAD_TILE(dst, src, stride) { \
    _Pragma("unroll") \
    for (int i_ = 0; i_ < 4; i_++){ \
        int rr_ = (tid>>4) + i_*16, cc_ = (tid&15)*4; \
        float4 v_ = *(const float4*)((src) + (size_t)rr_*(stride) + cc_); \
        dst[rr_][cc_+0]=v_.x; dst[rr_][cc_+1]=v_.y; dst[rr_][cc_+2]=v_.z; dst[rr_][cc_+3]=v_.w; \
    } }

// ---------------- elementwise: token shift + xxx ----------------
__global__ void k_shift(const float* __restrict__ x, const float* __restrict__ tmx,
                        float* __restrict__ dxprev, float* __restrict__ xxx){
    int idx = blockIdx.x*256 + threadIdx.x;
    if (idx >= CB*CT*CD) return;
    int d = idx % CD;
    int bt = idx / CD;
    int t = bt % CT;
    float xc = x[idx];
    float xl = (t > 0)      ? x[idx - CD] : 0.f;
    float xr = (t < CT-1)   ? x[idx + CD] : 0.f;
    float dx = 0.5f*(xl + xr) - xc;
    dxprev[idx] = dx;
    xxx[idx] = xc + dx * tmx[d];
}

// ---------------- generic tiled fp32 GEMM (maa_w1 only) ----------------
template<int MODE>
__global__ void k_gemm(const float* __restrict__ A, const float* __restrict__ Bm,
                       const float* __restrict__ bias, float* __restrict__ C,
                       int M, int N, int Kd){
    __shared__ float As[16][128];
    __shared__ float Bs[16][64];
    int tid = threadIdx.x;
    int m0 = blockIdx.y * 128, n0 = blockIdx.x * 64;
    int tn = (tid & 15) * 4;
    int tm = (tid >> 4) * 8;
    float acc[8][4] = {};
    for (int k0 = 0; k0 < Kd; k0 += 16){
        #pragma unroll
        for (int i = 0; i < 8; i++){
            int e = tid + i*256;
            int r = e >> 4, c = e & 15;
            As[c][r] = A[(size_t)(m0+r)*Kd + k0 + c];
        }
        #pragma unroll
        for (int i = 0; i < 4; i++){
            int e = tid + i*256;
            int r = e >> 6, c = e & 63;
            float bv = 0.f;
            if (n0 + c < N) bv = Bm[(size_t)(k0+r)*N + n0 + c];
            Bs[r][c] = bv;
        }
        __syncthreads();
        #pragma unroll
        for (int kk = 0; kk < 16; kk++){
            float a0[8], b0[4];
            #pragma unroll
            for (int i = 0; i < 8; i++) a0[i] = As[kk][tm+i];
            #pragma unroll
            for (int j = 0; j < 4; j++) b0[j] = Bs[kk][tn+j];
            #pragma unroll
            for (int i = 0; i < 8; i++)
                #pragma unroll
                for (int j = 0; j < 4; j++) acc[i][j] += a0[i]*b0[j];
        }
        __syncthreads();
    }
    #pragma unroll
    for (int i = 0; i < 8; i++)
        #pragma unroll
        for (int j = 0; j < 4; j++){
            int mm = m0 + tm + i, nn = n0 + tn + j;
            if (nn < N){
                float v = acc[i][j];
                if (MODE == 1) v = tanhf(v);
                else if (MODE == 2) v = v / (1.f + expf(-v));
                else if (MODE == 3) v += bias[nn];
                C[(size_t)mm*N + nn] = v;
            }
        }
}

// ---------------- weight transpose + split: B[K][N] -> Bt{Hi,Lo}[N][K] ----------------
__global__ void k_splitT(const float* __restrict__ B, unsigned short* __restrict__ hi,
                         unsigned short* __restrict__ lo, int Kd, int N){
    __shared__ float ts[64][65];
    int tid = threadIdx.x;
    int n0 = blockIdx.x*64, k0 = blockIdx.y*64;
    #pragma unroll
    for (int i = 0; i < 4; i++){
        int rr = (tid>>4) + i*16, cc = (tid&15)*4;
        float4 v = *(const float4*)(B + (size_t)(k0+rr)*N + n0 + cc);
        ts[rr][cc+0]=v.x; ts[rr][cc+1]=v.y; ts[rr][cc+2]=v.z; ts[rr][cc+3]=v.w;
    }
    __syncthreads();
    #pragma unroll
    for (int i = 0; i < 4; i++){
        int nl = (tid>>4) + i*16, k4 = (tid&15)*4;
        ush4 vh, vl;
        #pragma unroll
        for (int j = 0; j < 4; j++){
            float f = ts[k4+j][nl];
            unsigned short h = f2bf(f);
            vh[j] = h;
            vl[j] = f2bf(f - bf2f(h));
        }
        size_t o = (size_t)(n0+nl)*Kd + k0 + k4;
        *reinterpret_cast<ush4*>(hi + o) = vh;
        *reinterpret_cast<ush4*>(lo + o) = vl;
    }
}

// ---------------- MFMA split-bf16 GEMM: C[M,N] = A[M,K] @ Bt[N,K]^T ----------------
template<int MODE>
__global__ __launch_bounds__(256) void k_mgemm(const float* __restrict__ A,
        const unsigned short* __restrict__ BtHi, const unsigned short* __restrict__ BtLo,
        const float* __restrict__ bias, float* __restrict__ C, int M, int N, int Kd){
    __shared__ unsigned short AHI[2048], ALO[2048], BHI[2048], BLO[2048];
    int tid = threadIdx.x;
    int n0 = blockIdx.x*64, m0 = blockIdx.y*64;
    int w = tid >> 6, lane = tid & 63;
    int wm = w >> 1, wn = w & 1;
    fl4 acc[2][2];
    #pragma unroll
    for (int mi = 0; mi < 2; mi++)
        #pragma unroll
        for (int ni = 0; ni < 2; ni++) acc[mi][ni] = (fl4){0.f, 0.f, 0.f, 0.f};
    int sm = tid >> 2;
    int sk = (tid & 3) * 8;
    int slane = (sm & 15) + ((tid & 3) << 4);
    int sidx = (((sm >> 4)*64) + slane) * 8;
    const int nsteps = Kd >> 5;
    for (int ks = 0; ks < nsteps; ks++){
        int k0 = ks << 5;
        __syncthreads();
        {
            const float* ap = A + (size_t)(m0+sm)*Kd + k0 + sk;
            float4 a0 = *(const float4*)ap, a1 = *(const float4*)(ap+4);
            float av[8] = {a0.x,a0.y,a0.z,a0.w,a1.x,a1.y,a1.z,a1.w};
            ush8 vh, vl;
            #pragma unroll
            for (int i = 0; i < 8; i++){
                unsigned short h = f2bf(av[i]);
                vh[i] = h;
                vl[i] = f2bf(av[i] - bf2f(h));
            }
            *reinterpret_cast<ush8*>(&AHI[sidx]) = vh;
            *reinterpret_cast<ush8*>(&ALO[sidx]) = vl;
            size_t bo = (size_t)(n0+sm)*Kd + k0 + sk;
            *reinterpret_cast<ush8*>(&BHI[sidx]) = *reinterpret_cast<const ush8*>(BtHi + bo);
            *reinterpret_cast<ush8*>(&BLO[sidx]) = *reinterpret_cast<const ush8*>(BtLo + bo);
        }
        __syncthreads();
        sh8 ah[2], al[2], bh[2], bl[2];
        #pragma unroll
        for (int mi = 0; mi < 2; mi++){
            int gm = wm*2 + mi;
            ah[mi] = *reinterpret_cast<sh8*>(&AHI[(gm*64 + lane)*8]);
            al[mi] = *reinterpret_cast<sh8*>(&ALO[(gm*64 + lane)*8]);
        }
        #pragma unroll
        for (int ni = 0; ni < 2; ni++){
            int gn = wn*2 + ni;
            bh[ni] = *reinterpret_cast<sh8*>(&BHI[(gn*64 + lane)*8]);
            bl[ni] = *reinterpret_cast<sh8*>(&BLO[(gn*64 + lane)*8]);
        }
        #pragma unroll
        for (int mi = 0; mi < 2; mi++)
            #pragma unroll
            for (int ni = 0; ni < 2; ni++)
                MFMA3(acc[mi][ni], ah[mi], al[mi], bh[ni], bl[ni]);
    }
    #pragma unroll
    for (int mi = 0; mi < 2; mi++)
        #pragma unroll
        for (int ni = 0; ni < 2; ni++){
            int cc = n0 + wn*32 + ni*16 + (lane & 15);
            int rb = m0 + wm*32 + mi*16 + ((lane >> 4) << 2);
            #pragma unroll
            for (int j = 0; j < 4; j++){
                float v = acc[mi][ni][j];
                if (MODE == 1) v = tanhf(v);
                else if (MODE == 2) v = v / (1.f + expf(-v));
                else if (MODE == 3) v += bias[cc];
                C[(size_t)(rb+j)*N + cc] = v;
            }
        }
}

// ---------------- 5-way low-rank mix ----------------
__global__ void k_mix5(const float* __restrict__ x, const float* __restrict__ dxprev,
                       const float* __restrict__ m,
                       const float* __restrict__ tmw, const float* __restrict__ tmk,
                       const float* __restrict__ tmv, const float* __restrict__ tmr,
                       const float* __restrict__ tmg, const float* __restrict__ w2,
                       float* __restrict__ xw, float* __restrict__ xk, float* __restrict__ xv,
                       float* __restrict__ xr, float* __restrict__ xg){
    __shared__ float ms[160];
    int i = blockIdx.y;
    int j = blockIdx.x*256 + threadIdx.x;
    if (threadIdx.x < 160) ms[threadIdx.x] = m[(size_t)i*160 + threadIdx.x];
    __syncthreads();
    float xc = x[(size_t)i*CD + j], dx = dxprev[(size_t)i*CD + j];
    const float* tms[5] = {tmw, tmk, tmv, tmr, tmg};
    float* outs[5] = {xw, xk, xv, xr, xg};
    #pragma unroll
    for (int c = 0; c < 5; c++){
        float s = tms[c][j];
        const float* w2c = w2 + (size_t)c*32*CD + j;
        #pragma unroll
        for (int dm = 0; dm < 32; dm++) s += ms[c*32+dm] * w2c[(size_t)dm*CD];
        outs[c][(size_t)i*CD + j] = xc + dx*s;
    }
}

// ---------------- normalize k, stage v into X (head layout) ----------------
__global__ void k_knvx(const float* __restrict__ k, const float* __restrict__ v,
                       float* __restrict__ kn, float* __restrict__ X){
    int gw = (blockIdx.x*256 + threadIdx.x) >> 6;
    int lane = threadIdx.x & 63;
    if (gw >= CB*CH*CT) return;
    int t = gw % CT; int bh = gw / CT; int h = bh % CH; int b = bh / CH;
    size_t src = ((size_t)(b*CT + t))*CD + h*64 + lane;
    float kv = k[src];
    float ss = kv*kv;
    #pragma unroll
    for (int off = 32; off; off >>= 1) ss += __shfl_xor(ss, off);
    float nrm = fmaxf(sqrtf(ss), 1e-12f);
    size_t dst = ((size_t)bh*CT + t)*64 + lane;
    kn[dst] = kv / nrm;
    X[dst]  = v[src];
}

// ---------------- decay scan, fully coalesced ----------------
__global__ __launch_bounds__(256) void k_scan2(const float* __restrict__ r, const float* __restrict__ k,
                        const float* __restrict__ w,
                        float* __restrict__ rf, float* __restrict__ kf,
                        float* __restrict__ rb, float* __restrict__ kb){
    __shared__ float parts[16][4][64];
    __shared__ float carr[16][64];
    __shared__ float refs[2][64];
    int bh = blockIdx.x; int h = bh % CH; int b = bh / CH;
    int tid = threadIdx.x; int wid = tid >> 6; int ch = tid & 63;
    const float* wb = w + (size_t)b*CT*CD + h*64;
    for (int tc = 0; tc < 16; tc++){
        float sum = 0.f;
        int tb = tc*64 + wid*16;
        for (int s = 0; s < 16; s++)
            sum -= expf(wb[(size_t)(tb+s)*CD + ch]);
        parts[tc][wid][ch] = sum;
    }
    __syncthreads();
    if (tid < 64){
        float run = 0.f;
        for (int tc = 0; tc < 16; tc++){
            carr[tc][tid] = run;
            run += parts[tc][0][tid] + parts[tc][1][tid] + parts[tc][2][tid] + parts[tc][3][tid];
        }
        float wv512 = -expf(wb[(size_t)512*CD + tid]);
        refs[0][tid] = carr[8][tid] + wv512;
        refs[1][tid] = carr[8][tid];
    }
    __syncthreads();
    const float* rbp = r + (size_t)b*CT*CD + h*64;
    const float* kbp = k + (size_t)b*CT*CD + h*64;
    size_t ob = (size_t)bh*CT*64;
    float ref_f = refs[0][ch], ref_b = refs[1][ch];
    for (int tc = 0; tc < 16; tc++){
        float run = carr[tc][ch];
        if (wid > 0) run += parts[tc][0][ch];
        if (wid > 1) run += parts[tc][1][ch];
        if (wid > 2) run += parts[tc][2][ch];
        int tb = tc*64 + wid*16;
        for (int s = 0; s < 16; s++){
            int t = tb + s;
            float wv = -expf(wb[(size_t)t*CD + ch]);
            run += wv;
            float csf = fminf(fmaxf(run - ref_f, -60.f), 60.f);
            float csb = fminf(fmaxf((run - wv) - ref_b, -60.f), 60.f);
            float rv = rbp[(size_t)t*CD + ch], kv = kbp[(size_t)t*CD + ch];
            rf[ob + (size_t)t*64 + ch] = rv * expf(csf);
            kf[ob + (size_t)t*64 + ch] = kv * expf(-csf);
            rb[ob + (size_t)t*64 + ch] = rv * expf(-csb);
            kb[ob + (size_t)t*64 + ch] = kv * expf(csb);
        }
    }
}

// ---------------- P(lower, packed tiles) = I + exp(clip(temp * kn knT)) ----------------
__global__ void k_gram(const float* __restrict__ kn, const float* __restrict__ lucid_temp,
                       float* __restrict__ P, int bh0){
    int ti = blockIdx.y, tj = blockIdx.x;
    if (ti < tj) return;
    int t0 = ti*64, s0 = tj*64;
    __shared__ float tA[64][65];
    __shared__ float tB[64][65];
    int lbh = blockIdx.z; int gbh = bh0 + lbh; int h = gbh % CH;
    int tid = threadIdx.x;
    LOAD_TILE(tA, kn + ((size_t)gbh*CT + t0)*64, 64);
    LOAD_TILE(tB, kn + ((size_t)gbh*CT + s0)*64, 64);
    __syncthreads();
    float tv = lucid_temp[h];
    tv = (tv > 20.f) ? tv : log1pf(expf(tv));
    int ty = (tid >> 4)*4, tx = (tid & 15)*4;
    float acc[4][4] = {};
    #pragma unroll
    for (int kk = 0; kk < 64; kk++){
        float a0[4], b0[4];
        #pragma unroll
        for (int i = 0; i < 4; i++){ a0[i] = tA[ty+i][kk]; b0[i] = tB[tx+i][kk]; }
        #pragma unroll
        for (int i = 0; i < 4; i++)
            #pragma unroll
            for (int j = 0; j < 4; j++) acc[i][j] += a0[i]*b0[j];
    }
    float* Pt = P + (size_t)lbh*PBF + PTILE(ti,tj);
    #pragma unroll
    for (int i = 0; i < 4; i++){
        int tt = t0+ty+i;
        float4 v;
        float g0 = fminf(fmaxf(tv*acc[i][0], -20.f), 20.f);
        float g1 = fminf(fmaxf(tv*acc[i][1], -20.f), 20.f);
        float g2 = fminf(fmaxf(tv*acc[i][2], -20.f), 20.f);
        float g3 = fminf(fmaxf(tv*acc[i][3], -20.f), 20.f);
        v.x = expf(g0) + ((tt == s0+tx+0) ? 1.f : 0.f);
        v.y = expf(g1) + ((tt == s0+tx+1) ? 1.f : 0.f);
        v.z = expf(g2) + ((tt == s0+tx+2) ? 1.f : 0.f);
        v.w = expf(g3) + ((tt == s0+tx+3) ? 1.f : 0.f);
        *(float4*)(Pt + (size_t)(ty+i)*64 + tx) = v;
    }
}

// ---------------- in-LDS 64x64 Cholesky + triangular inverse ----------------
__device__ __forceinline__ void potrf_inv(float (&s)[64][65], float (&inv)[64][65], int tid){
    for (int j = 0; j < 63; j++){
        __syncthreads();
        float invd = 1.f / fmaxf(s[j][j], 1e-20f);
        int n = 63 - j;
        for (int e = tid; e < n*n; e += 256){
            int ii = j+1 + e / n, cc = j+1 + e % n;
            s[ii][cc] -= s[ii][j]*s[cc][j]*invd;
        }
    }
    __syncthreads();
    for (int e = tid; e < 64*64; e += 256){
        int i2 = e >> 6, j2 = e & 63;
        if (i2 > j2) s[i2][j2] *= rsqrtf(fmaxf(s[j2][j2], 1e-20f));
    }
    __syncthreads();
    if (tid < 64) s[tid][tid] = sqrtf(fmaxf(s[tid][tid], 1e-20f));
    __syncthreads();
    if (tid < 64){
        int c = tid;
        for (int j = 0; j < c; j++) inv[j][c] = 0.f;
        for (int j = c; j < 64; j++){
            float sum = (j == c) ? 1.f : 0.f;
            for (int kk = c; kk < j; kk++) sum -= s[j][kk]*inv[kk][c];
            inv[j][c] = sum / s[j][j];
        }
    }
    __syncthreads();
}

// write L (lower of s) into packed diag tile (stride 64) + inv into invL
__device__ __forceinline__ void potrf_writeout(float (&s)[64][65], float (&inv)[64][65], int tid,
                                               float* __restrict__ Pd, float* __restrict__ invp){
    for (int e = tid; e < 4096; e += 256){
        int r2 = e >> 6, c2 = e & 63;
        if (c2 <= r2) Pd[(size_t)r2*64 + c2] = s[r2][c2];
    }
    #pragma unroll
    for (int i_ = 0; i_ < 4; i_++){
        int rr_ = (tid>>4) + i_*16, cc_ = (tid&15)*4;
        float4 v_ = make_float4(inv[rr_][cc_], inv[rr_][cc_+1], inv[rr_][cc_+2], inv[rr_][cc_+3]);
        *(float4*)(invp + rr_*64 + cc_) = v_;
    }
}

// ================= cooperative full factorization + solves =================
__global__ __launch_bounds__(256) void k_chol(float* __restrict__ P, float* __restrict__ invL,
                                              float* __restrict__ X, float* __restrict__ Yb,
                                              int bh0, int Gc){
    cg::grid_group gg = cg::this_grid();
    __shared__ float sA[64][65], sB[64][65], sC[64][65];
    int tid = threadIdx.x;
    int ty = (tid >> 4)*4, tx = (tid & 15)*4;
    int NBK = gridDim.x, blk = blockIdx.x;

    // phase 0: potrf of tile(0,0)
    for (int t = blk; t < Gc; t += NBK){
        float* Pt = P + (size_t)t*PBF;
        LOAD_TILE(sA, Pt, 64);
        __syncthreads();
        potrf_inv(sA, sB, tid);
        potrf_writeout(sA, sB, tid, Pt, invL + (size_t)t*16*4096);
        __syncthreads();
    }
    gg.sync();

    for (int jb = 0; jb < 15; jb++){
        int nt = 15 - jb;
        // phase A: trsm column jb
        for (int t = blk; t < Gc*nt; t += NBK){
            int bh = t / nt, ti = t % nt;
            int rt = jb + 1 + ti;
            float* Pt = P + (size_t)bh*PBF + PTILE(rt,jb);
            const float* invp = invL + ((size_t)bh*16 + jb)*4096;
            LOAD_TILE(sA, Pt, 64);
            LOAD_TILE(sB, invp, 64);
            __syncthreads();
            float acc[4][4] = {};
            #pragma unroll
            for (int kk = 0; kk < 64; kk++){
                float a0[4], b0[4];
                #pragma unroll
                for (int i = 0; i < 4; i++){ a0[i] = sA[ty+i][kk]; b0[i] = sB[tx+i][kk]; }
                #pragma unroll
                for (int i = 0; i < 4; i++)
                    #pragma unroll
                    for (int j = 0; j < 4; j++) acc[i][j] += a0[i]*b0[j];
            }
            __syncthreads();
            #pragma unroll
            for (int i = 0; i < 4; i++)
                *(float4*)(Pt + (size_t)(ty+i)*64 + tx) =
                    make_float4(acc[i][0], acc[i][1], acc[i][2], acc[i][3]);
        }
        gg.sync();
        // phase B: syrk (+inline next potrf) + forward-solve column
        int Wd = nt + 1;
        for (int t = blk; t < Gc*nt*Wd; t += NBK){
            int bh = t / (nt*Wd); int r = t % (nt*Wd);
            int ti = r / Wd, tj = r % Wd;
            float* Pb = P + (size_t)bh*PBF;
            if (tj == nt){
                int ib = jb + 1 + ti;
                const float* invp = invL + ((size_t)bh*16 + jb)*4096;
                const float* Xj = X + ((size_t)(bh0+bh)*CT + jb*64)*64;
                LOAD_TILE(sA, invp, 64);
                LOAD_TILE(sB, Xj, 64);
                __syncthreads();
                float c4[4][4] = {};
                #pragma unroll
                for (int kk = 0; kk < 64; kk++){
                    float a0[4], b0[4];
                    #pragma unroll
                    for (int i = 0; i < 4; i++){ a0[i] = sA[ty+i][kk]; b0[i] = sB[kk][tx+i]; }
                    #pragma unroll
                    for (int i = 0; i < 4; i++)
                        #pragma unroll
                        for (int j = 0; j < 4; j++) c4[i][j] += a0[i]*b0[j];
                }
                if (ti == 0){
                    float* yd = Yb + ((size_t)(bh0+bh)*CT + jb*64)*64;
                    #pragma unroll
                    for (int i = 0; i < 4; i++)
                        *(float4*)(yd + (size_t)(ty+i)*64 + tx) =
                            make_float4(c4[i][0], c4[i][1], c4[i][2], c4[i][3]);
                }
                #pragma unroll
                for (int i = 0; i < 4; i++)
                    #pragma unroll
                    for (int j = 0; j < 4; j++) sC[ty+i][tx+j] = c4[i][j];
                __syncthreads();
                LOAD_TILE(sA, Pb + PTILE(ib,jb), 64);
                __syncthreads();
                float u4[4][4] = {};
                #pragma unroll
                for (int kk = 0; kk < 64; kk++){
                    float a0[4], b0[4];
                    #pragma unroll
                    for (int i = 0; i < 4; i++){ a0[i] = sA[ty+i][kk]; b0[i] = sC[kk][tx+i]; }
                    #pragma unroll
                    for (int i = 0; i < 4; i++)
                        #pragma unroll
                        for (int j = 0; j < 4; j++) u4[i][j] += a0[i]*b0[j];
                }
                float* dst = X + ((size_t)(bh0+bh)*CT + ib*64)*64;
                #pragma unroll
                for (int i = 0; i < 4; i++){
                    float4* p4 = (float4*)(dst + (size_t)(ty+i)*64 + tx);
                    float4 v = *p4;
                    v.x -= u4[i][0]; v.y -= u4[i][1]; v.z -= u4[i][2]; v.w -= u4[i][3];
                    *p4 = v;
                }
                __syncthreads();
            } else if (tj <= ti){
                int ibr = jb + 1 + ti, ibc = jb + 1 + tj;
                LOAD_TILE(sA, Pb + PTILE(ibr,jb), 64);
                LOAD_TILE(sB, Pb + PTILE(ibc,jb), 64);
                __syncthreads();
                float acc[4][4] = {};
                #pragma unroll
                for (int kk = 0; kk < 64; kk++){
                    float a0[4], b0[4];
                    #pragma unroll
                    for (int i = 0; i < 4; i++){ a0[i] = sA[ty+i][kk]; b0[i] = sB[tx+i][kk]; }
                    #pragma unroll
                    for (int i = 0; i < 4; i++)
                        #pragma unroll
                        for (int j = 0; j < 4; j++) acc[i][j] += a0[i]*b0[j];
                }
                __syncthreads();
                if (!(ti == 0 && tj == 0)){
                    float* Pt = Pb + PTILE(ibr,ibc);
                    #pragma unroll
                    for (int i = 0; i < 4; i++){
                        float4* p4 = (float4*)(Pt + (size_t)(ty+i)*64 + tx);
                        float4 v = *p4;
                        v.x -= acc[i][0]; v.y -= acc[i][1]; v.z -= acc[i][2]; v.w -= acc[i][3];
                        *p4 = v;
                    }
                } else {
                    float* Pt = Pb + PTILE(ibr,ibr);
                    #pragma unroll
                    for (int i = 0; i < 4; i++){
                        float4 v = *(const float4*)(Pt + (size_t)(ty+i)*64 + tx);
                        sA[ty+i][tx+0] = v.x - acc[i][0];
                        sA[ty+i][tx+1] = v.y - acc[i][1];
                        sA[ty+i][tx+2] = v.z - acc[i][2];
                        sA[ty+i][tx+3] = v.w - acc[i][3];
                    }
                    __syncthreads();
                    potrf_inv(sA, sB, tid);
                    potrf_writeout(sA, sB, tid, Pt, invL + ((size_t)bh*16 + jb+1)*4096);
                    __syncthreads();
                }
            }
        }
        gg.sync();
    }
    // phase: forward tail (diag jb=15): Yb(15) = inv(15) @ X(15)
    for (int t = blk; t < Gc; t += NBK){
        const float* invp = invL + ((size_t)t*16 + 15)*4096;
        const float* Xj = X + ((size_t)(bh0+t)*CT + 15*64)*64;
        LOAD_TILE(sA, invp, 64);
        LOAD_TILE(sB, Xj, 64);
        __syncthreads();
        float c4[4][4] = {};
        #pragma unroll
        for (int kk = 0; kk < 64; kk++){
            float a0[4], b0[4];
            #pragma unroll
            for (int i = 0; i < 4; i++){ a0[i] = sA[ty+i][kk]; b0[i] = sB[kk][tx+i]; }
            #pragma unroll
            for (int i = 0; i < 4; i++)
                #pragma unroll
                for (int j = 0; j < 4; j++) c4[i][j] += a0[i]*b0[j];
        }
        __syncthreads();
        float* yd = Yb + ((size_t)(bh0+t)*CT + 15*64)*64;
        #pragma unroll
        for (int i = 0; i < 4; i++)
            *(float4*)(yd + (size_t)(ty+i)*64 + tx) =
                make_float4(c4[i][0], c4[i][1], c4[i][2], c4[i][3]);
    }
    gg.sync();
    // backward solve: L^T Z = Y
    for (int jb = 15; jb >= 0; jb--){
        for (int t = blk; t < Gc*(jb+1); t += NBK){
            int bh = t / (jb+1), ib = t % (jb+1);
            const float* invp = invL + ((size_t)bh*16 + jb)*4096;
            const float* src = Yb + ((size_t)(bh0+bh)*CT + jb*64)*64;
            LOAD_TILE(sA, invp, 64);
            LOAD_TILE(sB, src, 64);
            __syncthreads();
            float c4[4][4] = {};
            #pragma unroll
            for (int kk = 0; kk < 64; kk++){
                float a0[4], b0[4];
                #pragma unroll
                for (int i = 0; i < 4; i++){ a0[i] = sA[kk][ty+i]; b0[i] = sB[kk][tx+i]; }
                #pragma unroll
                for (int i = 0; i < 4; i++)
                    #pragma unroll
                    for (int j = 0; j < 4; j++) c4[i][j] += a0[i]*b0[j];
            }
            if (ib == jb){
                float* dst = X + ((size_t)(bh0+bh)*CT + jb*64)*64;
                #pragma unroll
                for (int i = 0; i < 4; i++)
                    *(float4*)(dst + (size_t)(ty+i)*64 + tx) =
                        make_float4(c4[i][0], c4[i][1], c4[i][2], c4[i][3]);
                __syncthreads();
            } else {
                #pragma unroll
                for (int i = 0; i < 4; i++)
                    #pragma unroll
                    for (int j = 0; j < 4; j++) sC[ty+i][tx+j] = c4[i][j];
                __syncthreads();
                LOAD_TILE(sA, P + (size_t)bh*PBF + PTILE(jb,ib), 64);
                __syncthreads();
                float u4[4][4] = {};
                #pragma unroll
                for (int kk = 0; kk < 64; kk++){
                    float a0[4], b0[4];
                    #pragma unroll
                    for (int i = 0; i < 4; i++){ a0[i] = sA[kk][ty+i]; b0[i] = sC[kk][tx+i]; }
                    #pragma unroll
                    for (int i = 0; i < 4; i++)
                        #pragma unroll
                        for (int j = 0; j < 4; j++) u4[i][j] += a0[i]*b0[j];
                }
                float* dst = Yb + ((size_t)(bh0+bh)*CT + ib*64)*64;
                #pragma unroll
                for (int i = 0; i < 4; i++){
                    float4* p4 = (float4*)(dst + (size_t)(ty+i)*64 + tx);
                    float4 v = *p4;
                    v.x -= u4[i][0]; v.y -= u4[i][1]; v.z -= u4[i][2]; v.w -= u4[i][3];
                    *p4 = v;
                }
                __syncthreads();
            }
        }
        gg.sync();
    }
}

// ---------- fallback (round-13) ladder kernels ----------
__global__ void k_potrf0(float* __restrict__ P, float* __restrict__ invL){
    __shared__ float s[64][65], inv[64][65];
    int bh = blockIdx.x; int tid = threadIdx.x;
    float* Pt = P + (size_t)bh*PBF;
    LOAD_TILE(s, Pt, 64);
    __syncthreads();
    potrf_inv(s, inv, tid);
    potrf_writeout(s, inv, tid, Pt, invL + (size_t)bh*16*4096);
}

__global__ void k_trsm(float* __restrict__ P, const float* __restrict__ invL, int jb){
    __shared__ float a[64][65];
    __shared__ float iv[64][65];
    int bh = blockIdx.y;
    int rt = jb + 1 + blockIdx.x;
    int tid = threadIdx.x;
    float* Pt = P + (size_t)bh*PBF + PTILE(rt,jb);
    const float* invp = invL + ((size_t)bh*16 + jb)*4096;
    LOAD_TILE(a, Pt, 64);
    LOAD_TILE(iv, invp, 64);
    __syncthreads();
    int ty = (tid >> 4)*4, tx = (tid & 15)*4;
    float acc[4][4] = {};
    #pragma unroll
    for (int kk = 0; kk < 64; kk++){
        float a0[4], b0[4];
        #pragma unroll
        for (int i = 0; i < 4; i++){ a0[i] = a[ty+i][kk]; b0[i] = iv[tx+i][kk]; }
        #pragma unroll
        for (int i = 0; i < 4; i++)
            #pragma unroll
            for (int j = 0; j < 4; j++) acc[i][j] += a0[i]*b0[j];
    }
    #pragma unroll
    for (int i = 0; i < 4; i++)
        *(float4*)(Pt + (size_t)(ty+i)*64 + tx) =
            make_float4(acc[i][0], acc[i][1], acc[i][2], acc[i][3]);
}

__global__ void k_syrkf(float* __restrict__ P, float* __restrict__ invL,
                        float* __restrict__ X, float* __restrict__ Yb, int bh0, int jb){
    __shared__ float sA[64][65], sB[64][65], sC[64][65];
    int tj = blockIdx.x, ti = blockIdx.y, lbh = blockIdx.z;
    int tid = threadIdx.x;
    int ty = (tid >> 4)*4, tx = (tid & 15)*4;
    float* Pb = P + (size_t)lbh*PBF;
    if (tj == gridDim.x - 1){
        int ib = jb + 1 + ti;
        const float* invp = invL + ((size_t)lbh*16 + jb)*4096;
        const float* Xj = X + ((size_t)(bh0+lbh)*CT + jb*64)*64;
        LOAD_TILE(sA, invp, 64);
        LOAD_TILE(sB, Xj, 64);
        __syncthreads();
        float c4[4][4] = {};
        #pragma unroll
        for (int kk = 0; kk < 64; kk++){
            float a0[4], b0[4];
            #pragma unroll
            for (int i = 0; i < 4; i++){ a0[i] = sA[ty+i][kk]; b0[i] = sB[kk][tx+i]; }
            #pragma unroll
            for (int i = 0; i < 4; i++)
                #pragma unroll
                for (int j = 0; j < 4; j++) c4[i][j] += a0[i]*b0[j];
        }
        if (ti == 0){
            float* yd = Yb + ((size_t)(bh0+lbh)*CT + jb*64)*64;
            #pragma unroll
            for (int i = 0; i < 4; i++)
                *(float4*)(yd + (size_t)(ty+i)*64 + tx) =
                    make_float4(c4[i][0], c4[i][1], c4[i][2], c4[i][3]);
        }
        #pragma unroll
        for (int i = 0; i < 4; i++)
            #pragma unroll
            for (int j = 0; j < 4; j++) sC[ty+i][tx+j] = c4[i][j];
        __syncthreads();
        LOAD_TILE(sA, Pb + PTILE(ib,jb), 64);
        __syncthreads();
        float u4[4][4] = {};
        #pragma unroll
        for (int kk = 0; kk < 64; kk++){
            float a0[4], b0[4];
            #pragma unroll
            for (int i = 0; i < 4; i++){ a0[i] = sA[ty+i][kk]; b0[i] = sC[kk][tx+i]; }
            #pragma unroll
            for (int i = 0; i < 4; i++)
                #pragma unroll
                for (int j = 0; j < 4; j++) u4[i][j] += a0[i]*b0[j];
        }
        float* dst = X + ((size_t)(bh0+lbh)*CT + ib*64)*64;
        #pragma unroll
        for (int i = 0; i < 4; i++){
            float4* p4 = (float4*)(dst + (size_t)(ty+i)*64 + tx);
            float4 v = *p4;
            v.x -= u4[i][0]; v.y -= u4[i][1]; v.z -= u4[i][2]; v.w -= u4[i][3];
            *p4 = v;
        }
        return;
    }
    if (tj > ti) return;
    int ibr = jb + 1 + ti, ibc = jb + 1 + tj;
    LOAD_TILE(sA, Pb + PTILE(ibr,jb), 64);
    LOAD_TILE(sB, Pb + PTILE(ibc,jb), 64);
    __syncthreads();
    float acc[4][4] = {};
    #pragma unroll
    for (int kk = 0; kk < 64; kk++){
        float a0[4], b0[4];
        #pragma unroll
        for (int i = 0; i < 4; i++){ a0[i] = sA[ty+i][kk]; b0[i] = sB[tx+i][kk]; }
        #pragma unroll
        for (int i = 0; i < 4; i++)
            #pragma unroll
            for (int j = 0; j < 4; j++) acc[i][j] += a0[i]*b0[j];
    }
    if (!(ti == 0 && tj == 0)){
        float* Pt = Pb + PTILE(ibr,ibc);
        #pragma unroll
        for (int i = 0; i < 4; i++){
            float4* p4 = (float4*)(Pt + (size_t)(ty+i)*64 + tx);
            float4 v = *p4;
            v.x -= acc[i][0]; v.y -= acc[i][1]; v.z -= acc[i][2]; v.w -= acc[i][3];
            *p4 = v;
        }
    } else {
        float* Pt = Pb + PTILE(ibr,ibr);
        __syncthreads();
        #pragma unroll
        for (int i = 0; i < 4; i++){
            float4 v = *(const float4*)(Pt + (size_t)(ty+i)*64 + tx);
            sA[ty+i][tx+0] = v.x - acc[i][0];
            sA[ty+i][tx+1] = v.y - acc[i][1];
            sA[ty+i][tx+2] = v.z - acc[i][2];
            sA[ty+i][tx+3] = v.w - acc[i][3];
        }
        __syncthreads();
        potrf_inv(sA, sB, tid);
        potrf_writeout(sA, sB, tid, Pt, invL + ((size_t)lbh*16 + jb+1)*4096);
    }
}

template<int TRANS>
__global__ void k_solve(const float* __restrict__ P, const float* __restrict__ invL,
                        float* __restrict__ Xc, float* __restrict__ Yb, int bh0, int jb){
    __shared__ float A[64][65], B[64][65], C[64][65];
    int bh = blockIdx.y, tid = threadIdx.x;
    int ib = TRANS ? blockIdx.x : (jb + blockIdx.x);
    const float* invp = invL + ((size_t)bh*16 + jb)*4096;
    const float* src = (TRANS ? Yb : Xc) + ((size_t)(bh0+bh)*CT + jb*64)*64;
    LOAD_TILE(A, invp, 64);
    LOAD_TILE(B, src, 64);
    __syncthreads();
    int ty = (tid >> 4)*4, tx = (tid & 15)*4;
    float c4[4][4] = {};
    #pragma unroll
    for (int kk = 0; kk < 64; kk++){
        float a0[4], b0[4];
        #pragma unroll
        for (int i = 0; i < 4; i++){
            a0[i] = TRANS ? A[kk][ty+i] : A[ty+i][kk];
            b0[i] = B[kk][tx+i];
        }
        #pragma unroll
        for (int i = 0; i < 4; i++)
            #pragma unroll
            for (int j = 0; j < 4; j++) c4[i][j] += a0[i]*b0[j];
    }
    if (ib == jb){
        float* dst = (TRANS ? Xc : Yb) + ((size_t)(bh0+bh)*CT + jb*64)*64;
        #pragma unroll
        for (int i = 0; i < 4; i++)
            *(float4*)(dst + (size_t)(ty+i)*64 + tx) =
                make_float4(c4[i][0], c4[i][1], c4[i][2], c4[i][3]);
        return;
    }
    #pragma unroll
    for (int i = 0; i < 4; i++)
        #pragma unroll
        for (int j = 0; j < 4; j++) C[ty+i][tx+j] = c4[i][j];
    __syncthreads();
    const float* Lp = P + (size_t)bh*PBF + (TRANS ? PTILE(jb,ib) : PTILE(ib,jb));
    LOAD_TILE(A, Lp, 64);
    __syncthreads();
    float u4[4][4] = {};
    #pragma unroll
    for (int kk = 0; kk < 64; kk++){
        float a0[4], b0[4];
        #pragma unroll
        for (int i = 0; i < 4; i++){
            a0[i] = TRANS ? A[kk][ty+i] : A[ty+i][kk];
            b0[i] = C[kk][tx+i];
        }
        #pragma unroll
        for (int i = 0; i < 4; i++)
            #pragma unroll
            for (int j = 0; j < 4; j++) u4[i][j] += a0[i]*b0[j];
    }
    float* dst = (TRANS ? Yb : Xc) + ((size_t)(bh0+bh)*CT + ib*64)*64;
    #pragma unroll
    for (int i = 0; i < 4; i++){
        float4* p4 = (float4*)(dst + (size_t)(ty+i)*64 + tx);
        float4 v = *p4;
        v.x -= u4[i][0]; v.y -= u4[i][1]; v.z -= u4[i][2]; v.w -= u4[i][3];
        *p4 = v;
    }
}

// ---------------- per-chunk outer products ----------------
__global__ void k_outer(const float* __restrict__ kf, const float* __restrict__ kb,
                        const float* __restrict__ X,
                        float* __restrict__ Sf, float* __restrict__ Sb){
    __shared__ float kfs[64][65], kbs[64][65], pvs[64][65];
    int c = blockIdx.x, bh = blockIdx.y, tid = threadIdx.x;
    size_t hb = (size_t)bh*CT*64 + (size_t)c*64*64;
    LOAD_TILE(kfs, kf + hb, 64);
    LOAD_TILE(kbs, kb + hb, 64);
    LOAD_TILE(pvs, X + hb, 64);
    __syncthreads();
    int ty = (tid >> 4)*4, tx = (tid & 15)*4;
    float af[4][4] = {}, ab[4][4] = {};
    #pragma unroll
    for (int kk = 0; kk < 64; kk++){
        float f0[4], g0[4], b0[4];
        #pragma unroll
        for (int i = 0; i < 4; i++){
            f0[i] = kfs[kk][ty+i];
            g0[i] = kbs[kk][ty+i];
            b0[i] = pvs[kk][tx+i];
        }
        #pragma unroll
        for (int i = 0; i < 4; i++)
            #pragma unroll
            for (int j = 0; j < 4; j++){
                af[i][j] += f0[i]*b0[j];
                ab[i][j] += g0[i]*b0[j];
            }
    }
    size_t sb = ((size_t)bh*16 + c)*4096;
    #pragma unroll
    for (int i = 0; i < 4; i++){
        *(float4*)(Sf + sb + (size_t)(ty+i)*64 + tx) = make_float4(af[i][0], af[i][1], af[i][2], af[i][3]);
        *(float4*)(Sb + sb + (size_t)(ty+i)*64 + tx) = make_float4(ab[i][0], ab[i][1], ab[i][2], ab[i][3]);
    }
}

// ---------------- in-place chunk-state cumsum ----------------
__global__ void k_cumsum(float* __restrict__ Sf, float* __restrict__ Sb){
    int bh = blockIdx.x, tid = threadIdx.x;
    size_t base = (size_t)bh*16*4096;
    #pragma unroll
    for (int i = 0; i < 16; i++){
        int e = tid + i*256;
        float run = 0.f;
        for (int c = 0; c < 16; c++){
            float* p = Sf + base + (size_t)c*4096 + e;
            float t = *p; *p = run; run += t;
        }
        run = 0.f;
        for (int c = 15; c >= 0; c--){
            float* p = Sb + base + (size_t)c*4096 + e;
            float t = *p; *p = run; run += t;
        }
    }
}

// ---------------- per-chunk y: masked diag + state GEMMs ----------------
__global__ void k_apv2(const float* __restrict__ rf, const float* __restrict__ kf,
                       const float* __restrict__ rb, const float* __restrict__ kb,
                       const float* __restrict__ X,
                       const float* __restrict__ Sf, const float* __restrict__ Sb,
                       float* __restrict__ y){
    __shared__ float rs[64][65], ks[64][65], at[64][65];
    int c = blockIdx.x, bh = blockIdx.y, tid = threadIdx.x;
    size_t hb = (size_t)bh*CT*64 + (size_t)c*64*64;
    size_t sb = ((size_t)bh*16 + c)*4096;
    int ty = (tid >> 4)*4, tx = (tid & 15)*4;
    LOAD_TILE(rs, rf + hb, 64);
    LOAD_TILE(ks, kf + hb, 64);
    __syncthreads();
    float a4[4][4] = {};
    #pragma unroll
    for (int kk = 0; kk < 64; kk++){
        float a0[4], b0[4];
        #pragma unroll
        for (int i = 0; i < 4; i++){ a0[i] = rs[ty+i][kk]; b0[i] = ks[tx+i][kk]; }
        #pragma unroll
        for (int i = 0; i < 4; i++)
            #pragma unroll
            for (int j = 0; j < 4; j++) a4[i][j] += a0[i]*b0[j];
    }
    __syncthreads();
    LOAD_TILE(rs, rb + hb, 64);
    LOAD_TILE(ks, kb + hb, 64);
    __syncthreads();
    float b4[4][4] = {};
    #pragma unroll
    for (int kk = 0; kk < 64; kk++){
        float a0[4], b0[4];
        #pragma unroll
        for (int i = 0; i < 4; i++){ a0[i] = rs[ty+i][kk]; b0[i] = ks[tx+i][kk]; }
        #pragma unroll
        for (int i = 0; i < 4; i++)
            #pragma unroll
            for (int j = 0; j < 4; j++) b4[i][j] += a0[i]*b0[j];
    }
    #pragma unroll
    for (int i = 0; i < 4; i++)
        #pragma unroll
        for (int j = 0; j < 4; j++)
            at[ty+i][tx+j] = ((ty+i) >= (tx+j)) ? a4[i][j] : b4[i][j];
    __syncthreads();
    LOAD_TILE(rs, X + hb, 64);
    __syncthreads();
    float yacc[4][4] = {};
    #pragma unroll 8
    for (int s = 0; s < 64; s++){
        float a0[4], b0[4];
        #pragma unroll
        for (int i = 0; i < 4; i++){ a0[i] = at[ty+i][s]; b0[i] = rs[s][tx+i]; }
        #pragma unroll
        for (int i = 0; i < 4; i++)
            #pragma unroll
            for (int j = 0; j < 4; j++) yacc[i][j] += a0[i]*b0[j];
    }
    __syncthreads();
    LOAD_TILE(rs, Sf + sb, 64);
    LOAD_TILE(ks, rf + hb, 64);
    __syncthreads();
    #pragma unroll 8
    for (int kk = 0; kk < 64; kk++){
        float a0[4], b0[4];
        #pragma unroll
        for (int i = 0; i < 4; i++){ a0[i] = ks[ty+i][kk]; b0[i] = rs[kk][tx+i]; }
        #pragma unroll
        for (int i = 0; i < 4; i++)
            #pragma unroll
            for (int j = 0; j < 4; j++) yacc[i][j] += a0[i]*b0[j];
    }
    __syncthreads();
    LOAD_TILE(rs, Sb + sb, 64);
    LOAD_TILE(ks, rb + hb, 64);
    __syncthreads();
    #pragma unroll 8
    for (int kk = 0; kk < 64; kk++){
        float a0[4], b0[4];
        #pragma unroll
        for (int i = 0; i < 4; i++){ a0[i] = ks[ty+i][kk]; b0[i] = rs[kk][tx+i]; }
        #pragma unroll
        for (int i = 0; i < 4; i++)
            #pragma unroll
            for (int j = 0; j < 4; j++) yacc[i][j] += a0[i]*b0[j];
    }
    #pragma unroll
    for (int i = 0; i < 4; i++)
        *(float4*)(y + hb + (size_t)(ty+i)*64 + tx) =
            make_float4(yacc[i][0], yacc[i][1], yacc[i][2], yacc[i][3]);
}

// ---------------- GroupNorm + gate ----------------
__global__ void k_gn(const float* __restrict__ y, const float* __restrict__ g,
                     const float* __restrict__ lnw, const float* __restrict__ lnb,
                     float* __restrict__ z){
    int gw = (blockIdx.x*256 + threadIdx.x) >> 6;
    int lane = threadIdx.x & 63;
    if (gw >= CB*CT*CH) return;
    int h = gw % CH; int bt = gw / CH;
    int b = bt / CT, t = bt % CT;
    int bh = b*CH + h;
    float yv = y[((size_t)bh*CT + t)*64 + lane];
    float s1 = yv, s2 = yv*yv;
    #pragma unroll
    for (int off = 32; off; off >>= 1){ s1 += __shfl_xor(s1, off); s2 += __shfl_xor(s2, off); }
    float mu = s1 * (1.f/64.f);
    float var = s2 * (1.f/64.f) - mu*mu;
    float inv = rsqrtf(var + 6.4e-4f);
    int d = h*64 + lane;
    float yn = (yv - mu)*inv*lnw[d] + lnb[d];
    z[(size_t)bt*CD + d] = yn * g[(size_t)bt*CD + d];
}

extern "C" void kernel_launch(void* const* d_in, const int* in_sizes, int n_in,
                              void* d_out, int out_size, void* d_ws, size_t ws_size,
                              hipStream_t stream){
    const float* x          = (const float*)d_in[0];
    const float* tmx        = (const float*)d_in[1];
    const float* tmw        = (const float*)d_in[2];
    const float* tmk        = (const float*)d_in[3];
    const float* tmv        = (const float*)d_in[4];
    const float* tmr        = (const float*)d_in[5];
    const float* tmg        = (const float*)d_in[6];
    const float* maa_w1     = (const float*)d_in[7];
    const float* maa_w2     = (const float*)d_in[8];
    const float* time_decay = (const float*)d_in[9];
    const float* decay_w1   = (const float*)d_in[10];
    const float* decay_w2   = (const float*)d_in[11];
    const float* lucid_temp = (const float*)d_in[12];
    const float* Wr         = (const float*)d_in[13];
    const float* Wk         = (const float*)d_in[14];
    const float* Wv         = (const float*)d_in[15];
    const float* Wg         = (const float*)d_in[16];
    const float* Wo         = (const float*)d_in[17];
    const float* lnw        = (const float*)d_in[18];
    const float* lnb        = (const float*)d_in[19];
    float* out = (float*)d_out;
    float* ws  = (float*)d_ws;

    const size_t S = (size_t)CB*CT*CD;
    float* b0 = ws;          // dxprev -> wbuf -> Yb -> Sb
    float* b1 = ws + 1*S;    // xxx -> xw -> rf
    float* b2 = ws + 2*S;    // xk -> kf
    float* b3 = ws + 3*S;    // xv -> rb
    float* b4 = ws + 4*S;    // xr -> kn -> Sf
    float* b5 = ws + 5*S;    // xg -> X (v -> Pv)
    float* b6 = ws + 6*S;    // rbuf -> y
    float* b7 = ws + 7*S;    // kbuf -> z
    float* b8 = ws + 8*S;    // vbuf -> kb
    float* b9 = ws + 9*S;    // gbuf
    float* mbuf = ws + 10*S;
    const size_t MB_F = 4096*160;
    size_t base_f = 10*S + MB_F;

    const size_t per_bh = PBF + 16*4096;   // packed P + invL
    size_t avail = ws_size / sizeof(float);
    int G = 1;
    if (avail > base_f + per_bh){
        size_t g = (avail - base_f) / per_bh;
        G = (g >= CBH) ? CBH : (int)g;
        if (G < 1) G = 1;
    }
    float* P    = ws + base_f;
    float* invL = P + (size_t)G*PBF;

    unsigned short* BtHi = (unsigned short*)P;
    unsigned short* BtLo = BtHi + (size_t)CD*CD;

    float* dxprev = b0; float* xxx = b1;
    float* xw = b1; float* xk = b2; float* xv = b3; float* xr = b4; float* xg = b5;
    float* rbuf = b6; float* kbuf = b7; float* vbuf = b8; float* gbuf = b9; float* wbuf = b0;
    float* kn = b4; float* X = b5;
    float* rf = b1; float* kf = b2; float* rb = b3; float* kb = b8;
    float* Yb = b0;
    float* Sf = b4; float* Sb = b0;
    float* ybuf = b6; float* zbuf = b7;

    dim3 mg(CD/64, (CB*CT)/64);
    dim3 tg(CD/64, CD/64);

    k_shift<<<dim3((CB*CT*CD + 255)/256), 256, 0, stream>>>(x, tmx, dxprev, xxx);
    k_gemm<1><<<dim3(3, 32), 256, 0, stream>>>(xxx, maa_w1, nullptr, mbuf, 4096, 160, 768);
    k_mix5<<<dim3(3, 4096), 256, 0, stream>>>(x, dxprev, mbuf, tmw, tmk, tmv, tmr, tmg,
                                              maa_w2, xw, xk, xv, xr, xg);
    k_splitT<<<tg, 256, 0, stream>>>(Wr, BtHi, BtLo, CD, CD);
    k_mgemm<0><<<mg, 256, 0, stream>>>(xr, BtHi, BtLo, nullptr, rbuf, 4096, CD, CD);
    k_splitT<<<tg, 256, 0, stream>>>(Wk, BtHi, BtLo, CD, CD);
    k_mgemm<0><<<mg, 256, 0, stream>>>(xk, BtHi, BtLo, nullptr, kbuf, 4096, CD, CD);
    k_splitT<<<tg, 256, 0, stream>>>(Wv, BtHi, BtLo, CD, CD);
    k_mgemm<0><<<mg, 256, 0, stream>>>(xv, BtHi, BtLo, nullptr, vbuf, 4096, CD, CD);
    k_splitT<<<tg, 256, 0, stream>>>(Wg, BtHi, BtLo, CD, CD);
    k_mgemm<2><<<mg, 256, 0, stream>>>(xg, BtHi, BtLo, nullptr, gbuf, 4096, CD, CD);
    k_splitT<<<dim3(1, 12), 256, 0, stream>>>(decay_w1, BtHi, BtLo, CD, 64);
    k_mgemm<1><<<dim3(1, 64), 256, 0, stream>>>(xw, BtHi, BtLo, nullptr, mbuf, 4096, 64, CD);
    k_splitT<<<dim3(12, 1), 256, 0, stream>>>(decay_w2, BtHi, BtLo, 64, CD);
    k_mgemm<3><<<dim3(12, 64), 256, 0, stream>>>(mbuf, BtHi, BtLo, time_decay, wbuf, 4096, CD, 64);

    k_knvx<<<dim3((CB*CH*CT*64)/256), 256, 0, stream>>>(kbuf, vbuf, kn, X);
    k_scan2<<<dim3(CBH), 256, 0, stream>>>(rbuf, kbuf, wbuf, rf, kf, rb, kb);

    // cooperative grid sizing (host code runs once at graph capture)
    int devId = 0;
    hipGetDevice(&devId);
    hipDeviceProp_t prop;
    hipGetDeviceProperties(&prop, devId);
    int maxB = 0;
    hipError_t occErr = hipOccupancyMaxActiveBlocksPerMultiprocessor(&maxB, k_chol, 256, 0);
    int nblk = (occErr == hipSuccess && maxB > 0) ? maxB * prop.multiProcessorCount : 0;
    if (nblk > 2048) nblk = 2048;

    for (int bh0 = 0; bh0 < CBH; bh0 += G){
        int Gc = (CBH - bh0 < G) ? (CBH - bh0) : G;
        k_gram<<<dim3(16, 16, Gc), 256, 0, stream>>>(kn, lucid_temp, P, bh0);
        bool done = false;
        if (nblk >= 64){
            int bh0a = bh0, gca = Gc;
            void* args[] = {(void*)&P, (void*)&invL, (void*)&X, (void*)&Yb,
                            (void*)&bh0a, (void*)&gca};
            hipError_t e = hipLaunchCooperativeKernel((void*)k_chol, dim3(nblk), dim3(256),
                                                      args, 0, stream);
            done = (e == hipSuccess);
            if (!done) (void)hipGetLastError();
        }
        if (!done){
            k_potrf0<<<dim3(Gc), 256, 0, stream>>>(P, invL);
            for (int jb = 0; jb < 15; jb++){
                int nt = 15 - jb;
                k_trsm<<<dim3(nt, Gc), 256, 0, stream>>>(P, invL, jb);
                k_syrkf<<<dim3(nt+1, nt, Gc), 256, 0, stream>>>(P, invL, X, Yb, bh0, jb);
            }
            k_solve<0><<<dim3(1, Gc), 256, 0, stream>>>(P, invL, X, Yb, bh0, 15);
            for (int jb = 15; jb >= 0; jb--)
                k_solve<1><<<dim3(jb+1, Gc), 256, 0, stream>>>(P, invL, X, Yb, bh0, jb);
        }
    }

    k_outer<<<dim3(16, CBH), 256, 0, stream>>>(kf, kb, X, Sf, Sb);
    k_cumsum<<<dim3(CBH), 256, 0, stream>>>(Sf, Sb);
    k_apv2<<<dim3(16, CBH), 256, 0, stream>>>(rf, kf, rb, kb, X, Sf, Sb, ybuf);
    k_gn<<<dim3((CB*CT*CH*64)/256), 256, 0, stream>>>(ybuf, gbuf, lnw, lnb, zbuf);
    k_splitT<<<tg, 256, 0, stream>>>(Wo, BtHi, BtLo, CD, CD);
    k_mgemm<0><<<mg, 256, 0, stream>>>(zbuf, BtHi, BtLo, nullptr, out, 4096, CD, CD);
}